// Round 7
// baseline (71297.791 us; speedup 1.0000x reference)
//
#include <hip/hip_runtime.h>
#include <hip/hip_bf16.h>
#include <math.h>

// ---------------------------------------------------------------------------
// TrafficSeq2Seq round 7 = round 6 architecture + two fixes:
//  (a) gi (input-side gate projections) stored f32, not bf16 (round-2-proven
//      precision); ws-gated with in-loop-f32 fallback.
//  (b) decoder h0/h1 bf16 operand buffers double-buffered per step (removes
//      intra-phase read/write race in S5/S6).
// ---------------------------------------------------------------------------

#define NWG 256
#define TPB 512

typedef unsigned short u16;
typedef unsigned int   u32;
typedef short v8s __attribute__((ext_vector_type(8)));
typedef float v4f __attribute__((ext_vector_type(4)));

#define MFMA_(a,b,c) __builtin_amdgcn_mfma_f32_16x16x32_bf16((a),(b),(c),0,0,0)

__device__ __forceinline__ u16 f2bf(float f){
  u32 u = __builtin_bit_cast(u32, f);
  u32 r = u + 0x7FFFu + ((u >> 16) & 1u);
  return (u16)(r >> 16);
}
__device__ __forceinline__ float bf2f(u16 s){ u32 u = ((u32)s) << 16; return __builtin_bit_cast(float, u); }
__device__ __forceinline__ float sigm(float x){ return 1.f/(1.f+__expf(-x)); }
__device__ __forceinline__ float tanh_f(float x){
  float ax = fabsf(x); float t = __expf(-2.f*ax);
  return copysignf((1.f-t)/(1.f+t), x);
}

// cached bf16 fragment: lane holds M[(r0+(lane&15))*ld + k0 + (lane>>4)*8 ..+8)
__device__ __forceinline__ v8s ldfrag(const u16* base, size_t ld, int r0, int k0){
  int lane = threadIdx.x & 63;
  return *(const v8s*)(base + (size_t)(r0 + (lane&15))*ld + (size_t)(k0 + ((lane>>4)<<3)));
}
// fragment from f32 source with on-the-fly bf16 convert (rows 0..15)
__device__ __forceinline__ v8s ldfrag_f32(const float* base, size_t ld, int k0){
  int lane = threadIdx.x & 63;
  const float* p = base + (size_t)(lane&15)*ld + (size_t)(k0 + ((lane>>4)<<3));
  v4f f0 = *(const v4f*)p, f1 = *(const v4f*)(p+4);
  v8s o;
  #pragma unroll
  for (int j=0;j<4;j++){ o[j]=(short)f2bf(f0[j]); o[4+j]=(short)f2bf(f1[j]); }
  return o;
}
// XOR-swizzled LDS [16][C] helpers (C multiple of 8; 16B-chunk xor row&7)
__device__ __forceinline__ int swz(int r, int c){ return ((((c>>3) ^ (r&7))<<3) | (c&7)); }
__device__ __forceinline__ v8s ldfrag_lds(const u16* buf, int C, int k0){
  int lane = threadIdx.x & 63;
  int r = lane & 15;
  int ch = (k0>>3) + (lane>>4);
  return *(const v8s*)(buf + r*C + ((ch ^ (r&7))<<3));
}

struct KArgs {
  const float *x, *target, *eWih_f, *eWhh_f, *ebih, *ebhh;
  const float *dWih0_f, *dWih1_f, *dWhh_f, *dbih, *dbhh;
  const float *aWw_f, *aWb, *aCw_f, *aCb, *o1w_f, *o1b, *o2w_f, *o2b;
  float* out;
  u32 *flags, *genp;
  u16 *ebf, *ehh;                        // encoder Wih / Whh bf16 [2][1536][512]
  u16 *dWih0,*dWih0l,*dWih1,*dWih1l,*dWhh,*dWhhl;  // decoder weights hi/lo
  u16 *Wwh,*Wwhl,*Wch,*Wchl,*o1w,*o2w;   // attn/out weights (Wwh/Wch split)
  u16 *Wwxh,*Wwxl,*Wcxh,*Wcxl,*xth,*xtl; // split-bf16 for exact precompute
  float *preW, *preC;                    // xt-side attn linears, f32
  u16 *h0hist;                           // [128][256][512]
  u16 *encT;                             // [128][512][256] (enc_out transposed)
  float *h0f, *h1f;                      // decoder f32 h shadows [128][512]
  u16 *h0b, *h0c, *h1b, *h1c;            // h hi/lo bf16, DOUBLE buffered [2][128][512]
  float *gi;                             // [128][256][1536] f32 (if gipre)
  int gipre;
};

// ---- grid barrier: relaxed RMW polls, release on arrival, acquire at exit --
__device__ void gbar(u32* flags, u32* genp, u32 target){
  __syncthreads();
  int wg = blockIdx.x, tid = threadIdx.x;
  if (wg == 0){
    if (tid > 0 && tid < NWG){
      while (__hip_atomic_fetch_add(&flags[tid], 0u, __ATOMIC_RELAXED, __HIP_MEMORY_SCOPE_AGENT) < target)
        __builtin_amdgcn_s_sleep(8);
    }
    __syncthreads();
    if (tid == 0)
      __hip_atomic_fetch_add(genp, 1u, __ATOMIC_RELEASE, __HIP_MEMORY_SCOPE_AGENT);
  } else {
    if (tid == 0){
      __hip_atomic_fetch_add(&flags[wg], 1u, __ATOMIC_RELEASE, __HIP_MEMORY_SCOPE_AGENT);
      while (__hip_atomic_fetch_add(genp, 0u, __ATOMIC_RELAXED, __HIP_MEMORY_SCOPE_AGENT) < target)
        __builtin_amdgcn_s_sleep(8);
    }
  }
  __builtin_amdgcn_fence(__ATOMIC_ACQUIRE, "agent");
  __syncthreads();
}

// ---- encoder layer: h state in LDS (swizzled), weights streamed from L2 ----
__device__ void enc_layer(const KArgs& A, int layer, int b0, u16* hbA, u16* hbB){
  const int tid = threadIdx.x, w = tid>>6, lane = tid&63;
  const u16* Whh = A.ehh + (size_t)layer*1536*512;
  const u16* Wih = A.ebf + (size_t)layer*1536*512;
  const float* bih = A.ebih + layer*1536;
  const float* bhh = A.ebhh + layer*1536;
  for (int i=tid; i<16*512; i+=TPB) hbA[i] = 0;
  __syncthreads();
  u16* hp_ = hbA; u16* hn_ = hbB;
  for (int t=0; t<256; ++t){
    v4f aR[4],aZ[4],aN[4],aNI[4];
    #pragma unroll
    for (int j=0;j<4;j++){ aR[j]=(v4f){0,0,0,0}; aZ[j]=(v4f){0,0,0,0}; aN[j]=(v4f){0,0,0,0}; aNI[j]=(v4f){0,0,0,0}; }
    const int cw = w*64;
    for (int kt=0; kt<16; ++kt){
      int k0 = kt*32;
      v8s af = ldfrag_lds(hp_, 512, k0);
      #pragma unroll
      for (int j=0;j<4;j++){
        int c0 = cw + j*16;
        aR[j] = MFMA_(af, ldfrag(Whh,512,c0,k0), aR[j]);
        aZ[j] = MFMA_(af, ldfrag(Whh,512,512+c0,k0), aZ[j]);
        aN[j] = MFMA_(af, ldfrag(Whh,512,1024+c0,k0), aN[j]);
      }
    }
    if (!A.gipre){
      for (int kt=0; kt<16; ++kt){
        int k0 = kt*32;
        v8s af;
        if (layer==0) af = ldfrag_f32(A.x + (size_t)b0*131072 + (size_t)t*512, 131072, k0);
        else          af = ldfrag(A.h0hist + (size_t)b0*131072 + (size_t)t*512, 131072, 0, k0);
        #pragma unroll
        for (int j=0;j<4;j++){
          int c0 = cw + j*16;
          aR[j]  = MFMA_(af, ldfrag(Wih,512,c0,k0), aR[j]);
          aZ[j]  = MFMA_(af, ldfrag(Wih,512,512+c0,k0), aZ[j]);
          aNI[j] = MFMA_(af, ldfrag(Wih,512,1024+c0,k0), aNI[j]);
        }
      }
    }
    #pragma unroll
    for (int j=0;j<4;j++){
      int c = cw + j*16 + (lane&15);
      float bir=bih[c], biz=bih[512+c], bin=bih[1024+c];
      float bhr=bhh[c], bhz=bhh[512+c], bhn=bhh[1024+c];
      #pragma unroll
      for (int e=0;e<4;e++){
        int b = ((lane>>4)<<2)+e, gb = b0+b;
        float gr=0.f, gz=0.f, gn;
        if (A.gipre){
          const float* gp = A.gi + ((size_t)gb*256 + (size_t)t)*1536;
          gr = gp[c]; gz = gp[512+c]; gn = gp[1024+c];
        } else gn = aNI[j][e];
        float r = sigm(aR[j][e] + gr + bir + bhr);
        float z = sigm(aZ[j][e] + gz + biz + bhz);
        float n = tanh_f(gn + bin + r*(aN[j][e] + bhn));
        float hp = bf2f(hp_[b*512 + swz(b,c)]);
        float hv = (1.f-z)*n + z*hp;
        u16 h16 = f2bf(hv);
        hn_[b*512 + swz(b,c)] = h16;
        if (layer==0) A.h0hist[(size_t)gb*131072 + (size_t)t*512 + c] = h16;
        else          A.encT[(size_t)gb*131072 + (size_t)c*256 + t] = h16;
        if (t==255){
          u16 lo = f2bf(hv - bf2f(h16));
          // write slot 0 of the double-buffered decoder operand arrays
          if (layer==0){ A.h0f[(size_t)gb*512+c]=hv; A.h0b[(size_t)gb*512+c]=h16; A.h0c[(size_t)gb*512+c]=lo; }
          else         { A.h1f[(size_t)gb*512+c]=hv; A.h1b[(size_t)gb*512+c]=h16; A.h1c[(size_t)gb*512+c]=lo; }
        }
      }
    }
    __syncthreads();
    u16* tp = hp_; hp_ = hn_; hn_ = tp;
  }
}

#define DECOUT_OFF 0
#define DECHID_OFF 1228800
#define ATTN_OFF   1359872
#define HSLOT      65536            // 128*512, double-buffer slot stride

struct DecLds {
  float logits[16][256];   // 16KB
  u16   awh[16][256];      // 8KB
  u16   awl[16][256];      // 8KB
  u16   wcth[16][512];     // 16KB (swz)
  u16   wctl[16][512];     // 16KB (swz)
  u16   xch[16][320];      // 10KB (swz)
  u16   xcl[16][320];      // 10KB (swz)
  u16   o1[16][320];       // 10KB (swz)
};

__device__ void decoder(const KArgs& A, int b0, DecLds& L){
  const int tid = threadIdx.x, w = tid>>6, lane = tid&63;
  for (int i=tid; i<16*320; i+=TPB){ ((u16*)L.xch)[i]=0; ((u16*)L.xcl)[i]=0; ((u16*)L.o1)[i]=0; }
  __syncthreads();
  for (int s=0; s<32; ++s){
    const size_t rd = (size_t)(s&1)*HSLOT, wr = (size_t)((s&1)^1)*HSLOT;
    const u16* h0bR = A.h0b + rd + (size_t)b0*512;  const u16* h0cR = A.h0c + rd + (size_t)b0*512;
    u16*       h0bW = A.h0b + wr + (size_t)b0*512;  u16*       h0cW = A.h0c + wr + (size_t)b0*512;
    const u16* h1bR = A.h1b + rd + (size_t)b0*512;  const u16* h1cR = A.h1c + rd + (size_t)b0*512;
    u16*       h1bW = A.h1b + wr + (size_t)b0*512;  u16*       h1cW = A.h1c + wr + (size_t)b0*512;

    // S1: logits = preW[s] + h1 @ Wwh^T   (16 x 256), split 3-pass
    #pragma unroll
    for (int q=0;q<2;q++){
      int ct = w*2 + q;
      int c0 = ct*16;
      v4f acc = (v4f){0,0,0,0};
      for (int kt=0; kt<16; ++kt){
        v8s ah = ldfrag(h1bR, 512, 0, kt*32);
        v8s al = ldfrag(h1cR, 512, 0, kt*32);
        v8s bh = ldfrag(A.Wwh,512,c0,kt*32);
        v8s bl = ldfrag(A.Wwhl,512,c0,kt*32);
        acc = MFMA_(ah,bh,acc); acc = MFMA_(al,bh,acc); acc = MFMA_(ah,bl,acc);
      }
      int c = c0 + (lane&15);
      #pragma unroll
      for (int e=0;e<4;e++){
        int b = ((lane>>4)<<2)+e;
        L.logits[b][c] = acc[e] + A.preW[((size_t)s*128 + b0+b)*256 + c];
      }
    }
    __syncthreads();
    // S2: softmax rows (32 threads per row), aw stored split hi/lo
    {
      int r = tid>>5, ln = tid&31;
      float vals[8]; float mx = -3.4e38f;
      #pragma unroll
      for (int i=0;i<8;i++){ vals[i]=L.logits[r][ln+i*32]; mx = fmaxf(mx, vals[i]); }
      #pragma unroll
      for (int off=16; off>0; off>>=1) mx = fmaxf(mx, __shfl_xor(mx, off, 64));
      float sum=0.f;
      #pragma unroll
      for (int i=0;i<8;i++){ vals[i]=__expf(vals[i]-mx); sum += vals[i]; }
      #pragma unroll
      for (int off=16; off>0; off>>=1) sum += __shfl_xor(sum, off, 64);
      float inv = 1.f/sum;
      #pragma unroll
      for (int i=0;i<8;i++){
        float awv = vals[i]*inv; int t2 = ln+i*32;
        A.out[ATTN_OFF + ((size_t)(b0+r)*32 + s)*256 + t2] = awv;
        u16 hh = f2bf(awv);
        L.awh[r][t2] = hh; L.awl[r][t2] = f2bf(awv - bf2f(hh));
      }
    }
    __syncthreads();
    // S3: wctx via per-batch MFMA over encT, aw split 2-pass
    for (int job = w; job < 512; job += 8){
      int b = job>>5, h0 = (job&31)*16;
      const u16* eb = A.encT + (size_t)(b0+b)*131072 + (size_t)h0*256;
      v4f acc = (v4f){0,0,0,0};
      for (int kt=0; kt<8; ++kt){
        v8s a = ldfrag(eb, 256, 0, kt*32);
        v8s bh = *(const v8s*)(&L.awh[b][kt*32 + ((lane>>4)<<3)]);
        v8s bl = *(const v8s*)(&L.awl[b][kt*32 + ((lane>>4)<<3)]);
        acc = MFMA_(a, bh, acc); acc = MFMA_(a, bl, acc);
      }
      if ((lane & 15) == 0){
        #pragma unroll
        for (int e=0;e<4;e++){
          int h = h0 + ((lane>>4)<<2) + e;
          float v = acc[e];
          u16 hh = f2bf(v);
          L.wcth[b][swz(b,h)] = hh;
          L.wctl[b][swz(b,h)] = f2bf(v - bf2f(hh));
        }
      }
    }
    __syncthreads();
    // S4: xc = relu(preC[s] + wctx @ Wch^T)  (16 x 304), split 3-pass
    for (int ct = w; ct < 19; ct += 8){
      int c0 = ct*16;
      v4f acc = (v4f){0,0,0,0};
      for (int kt=0; kt<16; ++kt){
        v8s ah = ldfrag_lds(&L.wcth[0][0], 512, kt*32);
        v8s al = ldfrag_lds(&L.wctl[0][0], 512, kt*32);
        v8s bh = ldfrag(A.Wch,512,c0,kt*32);
        v8s bl = ldfrag(A.Wchl,512,c0,kt*32);
        acc = MFMA_(ah,bh,acc); acc = MFMA_(al,bh,acc); acc = MFMA_(ah,bl,acc);
      }
      int c = c0 + (lane&15);
      #pragma unroll
      for (int e=0;e<4;e++){
        int b = ((lane>>4)<<2)+e;
        float v = (c<300)? fmaxf(acc[e] + A.preC[((size_t)s*128 + b0+b)*320 + c], 0.f) : 0.f;
        u16 hh = f2bf(v);
        L.xch[b][swz(b,c)] = hh;
        L.xcl[b][swz(b,c)] = f2bf(v - bf2f(hh));
      }
    }
    __syncthreads();
    // S5: GRU layer 0 — reads h0 slot rd, writes slot wr (no in-place race)
    for (int jt = w; jt < 32; jt += 8){
      int c0 = jt*16;
      v4f ar=(v4f){0,0,0,0}, az=ar, an=ar, nh=ar;
      for (int kt=0; kt<10; ++kt){
        v8s ah = ldfrag_lds(&L.xch[0][0], 320, kt*32);
        v8s al = ldfrag_lds(&L.xcl[0][0], 320, kt*32);
        v8s br = ldfrag(A.dWih0,320,c0,kt*32),      brl = ldfrag(A.dWih0l,320,c0,kt*32);
        v8s bz = ldfrag(A.dWih0,320,512+c0,kt*32),  bzl = ldfrag(A.dWih0l,320,512+c0,kt*32);
        v8s bn = ldfrag(A.dWih0,320,1024+c0,kt*32), bnl = ldfrag(A.dWih0l,320,1024+c0,kt*32);
        ar = MFMA_(ah,br,ar); ar = MFMA_(al,br,ar); ar = MFMA_(ah,brl,ar);
        az = MFMA_(ah,bz,az); az = MFMA_(al,bz,az); az = MFMA_(ah,bzl,az);
        an = MFMA_(ah,bn,an); an = MFMA_(al,bn,an); an = MFMA_(ah,bnl,an);
      }
      for (int kt=0; kt<16; ++kt){
        v8s ah = ldfrag(h0bR, 512, 0, kt*32);
        v8s al = ldfrag(h0cR, 512, 0, kt*32);
        v8s br = ldfrag(A.dWhh,512,c0,kt*32),      brl = ldfrag(A.dWhhl,512,c0,kt*32);
        v8s bz = ldfrag(A.dWhh,512,512+c0,kt*32),  bzl = ldfrag(A.dWhhl,512,512+c0,kt*32);
        v8s bn = ldfrag(A.dWhh,512,1024+c0,kt*32), bnl = ldfrag(A.dWhhl,512,1024+c0,kt*32);
        ar = MFMA_(ah,br,ar); ar = MFMA_(al,br,ar); ar = MFMA_(ah,brl,ar);
        az = MFMA_(ah,bz,az); az = MFMA_(al,bz,az); az = MFMA_(ah,bzl,az);
        nh = MFMA_(ah,bn,nh); nh = MFMA_(al,bn,nh); nh = MFMA_(ah,bnl,nh);
      }
      int c = c0 + (lane&15);
      float bir=A.dbih[c], biz=A.dbih[512+c], bin=A.dbih[1024+c];
      float bhr=A.dbhh[c], bhz=A.dbhh[512+c], bhn=A.dbhh[1024+c];
      #pragma unroll
      for (int e=0;e<4;e++){
        int b = ((lane>>4)<<2)+e, gb = b0+b;
        float r = sigm(ar[e] + bir + bhr);
        float z = sigm(az[e] + biz + bhz);
        float n = tanh_f(an[e] + bin + r*(nh[e] + bhn));
        float hv = (1.f-z)*n + z*A.h0f[(size_t)gb*512+c];
        A.h0f[(size_t)gb*512+c] = hv;
        u16 hh = f2bf(hv);
        h0bW[(size_t)b*512+c] = hh;
        h0cW[(size_t)b*512+c] = f2bf(hv - bf2f(hh));
      }
    }
    __syncthreads();
    // S6: GRU layer 1 — ih input = NEW h0 (slot wr); h1 reads rd, writes wr
    for (int jt = w; jt < 32; jt += 8){
      int c0 = jt*16;
      v4f ar=(v4f){0,0,0,0}, az=ar, an=ar, nh=ar;
      const u16* Whh1  = A.dWhh  + (size_t)1536*512;
      const u16* Whh1l = A.dWhhl + (size_t)1536*512;
      for (int kt=0; kt<16; ++kt){
        v8s ah = ldfrag(h0bW, 512, 0, kt*32);
        v8s al = ldfrag(h0cW, 512, 0, kt*32);
        v8s br = ldfrag(A.dWih1,512,c0,kt*32),      brl = ldfrag(A.dWih1l,512,c0,kt*32);
        v8s bz = ldfrag(A.dWih1,512,512+c0,kt*32),  bzl = ldfrag(A.dWih1l,512,512+c0,kt*32);
        v8s bn = ldfrag(A.dWih1,512,1024+c0,kt*32), bnl = ldfrag(A.dWih1l,512,1024+c0,kt*32);
        ar = MFMA_(ah,br,ar); ar = MFMA_(al,br,ar); ar = MFMA_(ah,brl,ar);
        az = MFMA_(ah,bz,az); az = MFMA_(al,bz,az); az = MFMA_(ah,bzl,az);
        an = MFMA_(ah,bn,an); an = MFMA_(al,bn,an); an = MFMA_(ah,bnl,an);
      }
      for (int kt=0; kt<16; ++kt){
        v8s ah = ldfrag(h1bR, 512, 0, kt*32);
        v8s al = ldfrag(h1cR, 512, 0, kt*32);
        v8s br = ldfrag(Whh1,512,c0,kt*32),      brl = ldfrag(Whh1l,512,c0,kt*32);
        v8s bz = ldfrag(Whh1,512,512+c0,kt*32),  bzl = ldfrag(Whh1l,512,512+c0,kt*32);
        v8s bn = ldfrag(Whh1,512,1024+c0,kt*32), bnl = ldfrag(Whh1l,512,1024+c0,kt*32);
        ar = MFMA_(ah,br,ar); ar = MFMA_(al,br,ar); ar = MFMA_(ah,brl,ar);
        az = MFMA_(ah,bz,az); az = MFMA_(al,bz,az); az = MFMA_(ah,bzl,az);
        nh = MFMA_(ah,bn,nh); nh = MFMA_(al,bn,nh); nh = MFMA_(ah,bnl,nh);
      }
      int c = c0 + (lane&15);
      float bir=A.dbih[1536+c], biz=A.dbih[1536+512+c], bin=A.dbih[1536+1024+c];
      float bhr=A.dbhh[1536+c], bhz=A.dbhh[1536+512+c], bhn=A.dbhh[1536+1024+c];
      #pragma unroll
      for (int e=0;e<4;e++){
        int b = ((lane>>4)<<2)+e, gb = b0+b;
        float r = sigm(ar[e] + bir + bhr);
        float z = sigm(az[e] + biz + bhz);
        float n = tanh_f(an[e] + bin + r*(nh[e] + bhn));
        float hv = (1.f-z)*n + z*A.h1f[(size_t)gb*512+c];
        A.h1f[(size_t)gb*512+c] = hv;
        u16 hh = f2bf(hv);
        h1bW[(size_t)b*512+c] = hh;
        h1cW[(size_t)b*512+c] = f2bf(hv - bf2f(hh));
      }
    }
    __syncthreads();
    // S7: o1 = h1' @ o1w^T + b  (16 x 304), NEW h1 (slot wr), split 2-pass
    for (int ct = w; ct < 19; ct += 8){
      int c0 = ct*16;
      v4f acc = (v4f){0,0,0,0};
      for (int kt=0; kt<16; ++kt){
        v8s ah = ldfrag(h1bW, 512, 0, kt*32);
        v8s al = ldfrag(h1cW, 512, 0, kt*32);
        v8s bb = ldfrag(A.o1w,512,c0,kt*32);
        acc = MFMA_(ah, bb, acc); acc = MFMA_(al, bb, acc);
      }
      int c = c0 + (lane&15);
      #pragma unroll
      for (int e=0;e<4;e++){
        int b = ((lane>>4)<<2)+e;
        float v = (c<300)? (acc[e] + A.o1b[c]) : 0.f;
        L.o1[b][swz(b,c)] = f2bf(v);
      }
    }
    __syncthreads();
    // S8: dec_out[:,s,:] = o1 @ o2w^T + b
    for (int ct = w; ct < 19; ct += 8){
      int c0 = ct*16;
      v4f acc = (v4f){0,0,0,0};
      for (int kt=0; kt<10; ++kt){
        v8s a = ldfrag_lds(&L.o1[0][0], 320, kt*32);
        acc = MFMA_(a, ldfrag(A.o2w,320,c0,kt*32), acc);
      }
      int c = c0 + (lane&15);
      #pragma unroll
      for (int e=0;e<4;e++){
        int b = ((lane>>4)<<2)+e;
        if (c < 300)
          A.out[DECOUT_OFF + ((size_t)(b0+b)*32 + s)*300 + c] = acc[e] + A.o2b[c];
      }
    }
    __syncthreads();
  }
  // dec_hidden outputs (f32 shadows hold exact final h)
  for (int i=tid; i<16*512; i+=TPB){
    int b = i>>9, c = i&511;
    A.out[DECHID_OFF + (size_t)(b0+b)*512 + c]         = A.h0f[(size_t)(b0+b)*512 + c];
    A.out[DECHID_OFF + 65536 + (size_t)(b0+b)*512 + c] = A.h1f[(size_t)(b0+b)*512 + c];
  }
}

__global__ void __launch_bounds__(TPB, 1) traffic_kernel(KArgs A){
  __shared__ union {
    u16 hb[2][16][512];   // encoder (32KB)
    DecLds d;             // decoder (94KB)
  } U;
  const int tid = threadIdx.x;
  const int wg  = blockIdx.x;
  const int w   = tid >> 6;
  const size_t gtid = (size_t)wg*TPB + tid;
  const size_t P = (size_t)NWG*TPB;
  u32 bt = 0;

  // ===== P0: weight conversions (plain stores; visibility via B1) ==========
  auto spl = [](u16* ph, u16* pl, float v){ u16 h=f2bf(v); ph[0]=h; pl[0]=f2bf(v-bf2f(h)); };
  for (size_t i=gtid; i<2UL*1536*512; i+=P){ A.ebf[i]=f2bf(A.eWih_f[i]); A.ehh[i]=f2bf(A.eWhh_f[i]); }
  for (size_t i=gtid; i<1536UL*320; i+=P){ size_t r=i/320,c=i%320; float v=(c<300)? A.dWih0_f[r*300+c]:0.f; spl(&A.dWih0[i],&A.dWih0l[i],v); }
  for (size_t i=gtid; i<1536UL*512; i+=P) spl(&A.dWih1[i],&A.dWih1l[i],A.dWih1_f[i]);
  for (size_t i=gtid; i<2UL*1536*512; i+=P) spl(&A.dWhh[i],&A.dWhhl[i],A.dWhh_f[i]);
  for (size_t i=gtid; i<256UL*512; i+=P){ size_t r=i>>9,c=i&511; spl(&A.Wwh[i],&A.Wwhl[i],A.aWw_f[r*812+300+c]); }
  for (size_t i=gtid; i<304UL*512; i+=P){ size_t r=i>>9,c=i&511; float v=(r<300)? A.aCw_f[r*812+300+c]:0.f; spl(&A.Wch[i],&A.Wchl[i],v); }
  for (size_t i=gtid; i<304UL*512; i+=P){ size_t r=i>>9,c=i&511; A.o1w[i]=(r<300)? f2bf(A.o1w_f[r*512+c]) : (u16)0; }
  for (size_t i=gtid; i<304UL*320; i+=P){ size_t r=i/320,c=i%320; A.o2w[i]=(r<300&&c<300)? f2bf(A.o2w_f[r*300+c]) : (u16)0; }
  for (size_t i=gtid; i<256UL*320; i+=P){ size_t r=i/320,c=i%320; float v=(c<300)? A.aWw_f[r*812+c]:0.f; spl(&A.Wwxh[i],&A.Wwxl[i],v); }
  for (size_t i=gtid; i<304UL*320; i+=P){ size_t r=i/320,c=i%320; float v=(r<300&&c<300)? A.aCw_f[r*812+c]:0.f; spl(&A.Wcxh[i],&A.Wcxl[i],v); }
  for (size_t i=gtid; i<4096UL*320; i+=P){
    size_t rr=i/320, c=i%320, s=rr>>7, b=rr&127;
    float v = (c<300)? A.target[(b*33+s)*300 + c] : 0.f;
    spl(&A.xth[i],&A.xtl[i],v);
  }
  gbar(A.flags, A.genp, ++bt);   // B1

  // ===== P1: preW/preC (split-bf16 exact) + gi0 GEMM (f32 out) =============
  {
    const int lane = tid & 63;
    int gw = wg*8 + w;   // 0..2047
    for (int tl = gw; tl < 4096; tl += 2048){   // preW: 256 rt x 16 ct
      int rt = tl>>4, ct = tl&15;
      v4f acc = (v4f){0,0,0,0};
      for (int kt=0; kt<10; ++kt){
        int k0 = kt*32;
        v8s ah = ldfrag(A.xth,320,rt*16,k0), al = ldfrag(A.xtl,320,rt*16,k0);
        v8s bh = ldfrag(A.Wwxh,320,ct*16,k0), bl = ldfrag(A.Wwxl,320,ct*16,k0);
        acc = MFMA_(ah,bh,acc); acc = MFMA_(al,bh,acc); acc = MFMA_(ah,bl,acc);
      }
      int c = ct*16 + (lane&15);
      #pragma unroll
      for (int e=0;e<4;e++){
        int r = rt*16 + ((lane>>4)<<2) + e;
        A.preW[(size_t)r*256 + c] = acc[e] + A.aWb[c];
      }
    }
    for (int tl = gw; tl < 4864; tl += 2048){   // preC: 256 rt x 19 ct
      int rt = tl/19, ct = tl%19;
      v4f acc = (v4f){0,0,0,0};
      for (int kt=0; kt<10; ++kt){
        int k0 = kt*32;
        v8s ah = ldfrag(A.xth,320,rt*16,k0), al = ldfrag(A.xtl,320,rt*16,k0);
        v8s bh = ldfrag(A.Wcxh,320,ct*16,k0), bl = ldfrag(A.Wcxl,320,ct*16,k0);
        acc = MFMA_(ah,bh,acc); acc = MFMA_(al,bh,acc); acc = MFMA_(ah,bl,acc);
      }
      int c = ct*16 + (lane&15);
      #pragma unroll
      for (int e=0;e<4;e++){
        int r = rt*16 + ((lane>>4)<<2) + e;
        A.preC[(size_t)r*320 + c] = (c<300)? (acc[e] + A.aCb[c]) : 0.f;
      }
    }
    if (A.gipre){   // gi0 = x @ eWih0^T  -> f32
      int rt = gw;
      int b = (rt*16) >> 8, t0 = (rt*16) & 255;
      const float* xb = A.x + (size_t)b*131072 + (size_t)t0*512;
      for (int ct=0; ct<96; ++ct){
        v4f acc = (v4f){0,0,0,0};
        for (int kt=0; kt<16; ++kt)
          acc = MFMA_(ldfrag_f32(xb, 512, kt*32), ldfrag(A.ebf,512,ct*16,kt*32), acc);
        int n = ct*16 + (lane&15);
        #pragma unroll
        for (int e=0;e<4;e++){
          int t = t0 + ((lane>>4)<<2) + e;
          A.gi[((size_t)b*256 + t)*1536 + n] = acc[e];
        }
      }
    }
  }
  gbar(A.flags, A.genp, ++bt);   // B2

  // ===== encoder layer 0 (workers only) ====================================
  if (wg < 8) enc_layer(A, 0, wg*16, &U.hb[0][0][0], &U.hb[1][0][0]);
  gbar(A.flags, A.genp, ++bt);   // B3 (h0hist visible to all)

  // ===== gi1 = h0hist @ eWih1^T  -> f32 ====================================
  if (A.gipre){
    const int lane = tid & 63;
    int rt = wg*8 + w;
    int b = (rt*16) >> 8, t0 = (rt*16) & 255;
    const u16* hb = A.h0hist + (size_t)b*131072 + (size_t)t0*512;
    const u16* W1 = A.ebf + (size_t)1536*512;
    for (int ct=0; ct<96; ++ct){
      v4f acc = (v4f){0,0,0,0};
      for (int kt=0; kt<16; ++kt)
        acc = MFMA_(ldfrag(hb,512,0,kt*32), ldfrag(W1,512,ct*16,kt*32), acc);
      int n = ct*16 + (lane&15);
      #pragma unroll
      for (int e=0;e<4;e++){
        int t = t0 + ((lane>>4)<<2) + e;
        A.gi[((size_t)b*256 + t)*1536 + n] = acc[e];
      }
    }
  }
  gbar(A.flags, A.genp, ++bt);   // B4
  if (wg >= 8) return;

  // ===== encoder layer 1 + decoder (workers, WG-private from here) =========
  enc_layer(A, 1, wg*16, &U.hb[0][0][0], &U.hb[1][0][0]);
  decoder(A, wg*16, U.d);
}

// ===========================================================================
extern "C" void kernel_launch(void* const* d_in, const int* in_sizes, int n_in,
                              void* d_out, int out_size, void* d_ws, size_t ws_size,
                              hipStream_t stream){
  (void)in_sizes; (void)n_in; (void)out_size;
  KArgs A;
  A.x       = (const float*)d_in[0];  A.target = (const float*)d_in[1];
  A.eWih_f  = (const float*)d_in[2];  A.eWhh_f = (const float*)d_in[3];
  A.ebih    = (const float*)d_in[4];  A.ebhh   = (const float*)d_in[5];
  A.dWih0_f = (const float*)d_in[6];  A.dWih1_f= (const float*)d_in[7];
  A.dWhh_f  = (const float*)d_in[8];  A.dbih   = (const float*)d_in[9];
  A.dbhh    = (const float*)d_in[10];
  A.aWw_f   = (const float*)d_in[11]; A.aWb    = (const float*)d_in[12];
  A.aCw_f   = (const float*)d_in[13]; A.aCb    = (const float*)d_in[14];
  A.o1w_f   = (const float*)d_in[15]; A.o1b    = (const float*)d_in[16];
  A.o2w_f   = (const float*)d_in[17]; A.o2b    = (const float*)d_in[18];
  A.out = (float*)d_out;

  char* wsp = (char*)d_ws;
  size_t off = 0;
  auto alloc = [&](size_t bytes)->char*{
    char* p = wsp + off; off += (bytes + 255) & ~(size_t)255; return p;
  };
  char* barp = alloc(4096);
  A.flags = (u32*)barp;
  A.genp  = (u32*)(barp + 2048);
  A.ebf    = (u16*)alloc(2UL*1536*512*2);
  A.ehh    = (u16*)alloc(2UL*1536*512*2);
  A.dWih0  = (u16*)alloc(1536UL*320*2);  A.dWih0l = (u16*)alloc(1536UL*320*2);
  A.dWih1  = (u16*)alloc(1536UL*512*2);  A.dWih1l = (u16*)alloc(1536UL*512*2);
  A.dWhh   = (u16*)alloc(2UL*1536*512*2);A.dWhhl  = (u16*)alloc(2UL*1536*512*2);
  A.Wwh    = (u16*)alloc(256UL*512*2);   A.Wwhl   = (u16*)alloc(256UL*512*2);
  A.Wch    = (u16*)alloc(304UL*512*2);   A.Wchl   = (u16*)alloc(304UL*512*2);
  A.o1w    = (u16*)alloc(304UL*512*2);
  A.o2w    = (u16*)alloc(304UL*320*2);
  A.Wwxh   = (u16*)alloc(256UL*320*2);   A.Wwxl = (u16*)alloc(256UL*320*2);
  A.Wcxh   = (u16*)alloc(304UL*320*2);   A.Wcxl = (u16*)alloc(304UL*320*2);
  A.xth    = (u16*)alloc(4096UL*320*2);  A.xtl  = (u16*)alloc(4096UL*320*2);
  A.preW   = (float*)alloc(32UL*128*256*4);
  A.preC   = (float*)alloc(32UL*128*320*4);
  A.h0hist = (u16*)alloc(128UL*256*512*2);
  A.encT   = (u16*)alloc(128UL*512*256*2);
  A.h0f    = (float*)alloc(128UL*512*4);
  A.h1f    = (float*)alloc(128UL*512*4);
  A.h0b    = (u16*)alloc(2UL*65536*2);  A.h0c = (u16*)alloc(2UL*65536*2);   // double-buffered
  A.h1b    = (u16*)alloc(2UL*65536*2);  A.h1c = (u16*)alloc(2UL*65536*2);
  size_t gi_need = ((128UL*256*1536*4 + 255) & ~(size_t)255);   // f32 now
  A.gipre = (off + gi_need <= ws_size) ? 1 : 0;
  A.gi = (float*)(wsp + off);
  if (A.gipre) off += gi_need;

  hipMemsetAsync(d_ws, 0, 4096, stream);   // reset barrier flags/gen
  traffic_kernel<<<dim3(NWG), dim3(TPB), 0, stream>>>(A);
}

// Round 8
// 17550.467 us; speedup vs baseline: 4.0624x; 4.0624x over previous
//
#include <hip/hip_runtime.h>
#include <hip/hip_bf16.h>
#include <math.h>

// ---------------------------------------------------------------------------
// TrafficSeq2Seq round 8 = round-2 proven kernel (64 WGs collaborate on every
// step, fully-fenced grid barrier each step) + round-3 LDS-pinned encoder
// weight slices (98KB/WG, staged from f32 once per layer; immune to the
// barrier's cache invalidation). Decoder/numerics byte-identical to round 2.
// ---------------------------------------------------------------------------

#define NWG 64
#define TPB 256

typedef unsigned short u16;
typedef short v8s __attribute__((ext_vector_type(8)));
typedef float v4f __attribute__((ext_vector_type(4)));

#define MFMA_(a,b,c) __builtin_amdgcn_mfma_f32_16x16x32_bf16((a),(b),(c),0,0,0)

__device__ __forceinline__ u16 f2bf(float f){
  unsigned u = __builtin_bit_cast(unsigned, f);
  unsigned r = u + 0x7FFFu + ((u >> 16) & 1u);
  return (u16)(r >> 16);
}
__device__ __forceinline__ float bf2f(u16 s){
  unsigned u = ((unsigned)s) << 16;
  return __builtin_bit_cast(float, u);
}
__device__ __forceinline__ void splitstore(u16* ph, u16* pl, float v){
  u16 h = f2bf(v); ph[0] = h; pl[0] = f2bf(v - bf2f(h));
}
__device__ __forceinline__ float sigm(float x){ return 1.f / (1.f + __expf(-x)); }
__device__ __forceinline__ float tanh_f(float x){
  float ax = fabsf(x);
  float t = __expf(-2.f * ax);
  float r = (1.f - t) / (1.f + t);
  return copysignf(r, x);
}

// fragment load: lane holds M[(r0+(lane&15))*ld + k0 + (lane>>4)*8 .. +8)
__device__ __forceinline__ v8s ldfrag(const u16* base, size_t ld, int r0, int k0){
  int lane = threadIdx.x & 63;
  const u16* p = base + (size_t)(r0 + (lane & 15)) * ld + (size_t)(k0 + ((lane >> 4) << 3));
  return *(const v8s*)p;
}

// ---- LDS weight slice: [3 gates][16 rows][64 chunks of 8], chunk ^= (row&7)
__device__ __forceinline__ v8s ldfrag_w(const u16* wlds, int gate, int ks){
  int lane = threadIdx.x & 63;
  int rr = lane & 15;
  int ch = (ks*4 + (lane >> 4)) ^ (rr & 7);
  return *(const v8s*)(wlds + (size_t)((gate*16 + rr)*64 + ch) * 8);
}
__device__ void stage_wslice(const float* Wf, u16* wlds, int col0){
  for (int idx = threadIdx.x; idx < 3*16*64; idx += TPB){
    int ch = idx & 63, rr = (idx >> 6) & 15, g = idx >> 10;
    const float* src = Wf + ((size_t)(g*512 + col0 + rr))*512 + ch*8;
    v4f f0 = *(const v4f*)src, f1 = *(const v4f*)(src + 4);
    v8s o;
    #pragma unroll
    for (int j=0;j<4;j++){ o[j] = (short)f2bf(f0[j]); o[4+j] = (short)f2bf(f1[j]); }
    *(v8s*)(wlds + (size_t)((g*16 + rr)*64 + (ch ^ (rr & 7))) * 8) = o;
  }
}

struct KArgs {
  // inputs (f32)
  const float *x, *target, *eWih_f, *eWhh_f, *ebih, *ebhh;
  const float *dWih0_f, *dWih1_f, *dWhh_f, *dbih, *dbhh;
  const float *aWw_f, *aWb, *aCw_f, *aCb, *o1w_f, *o1b, *o2w_f, *o2b;
  float* out;
  // barrier
  unsigned *flags, *genp;
  // bf16 weights / activations in ws
  u16 *xhi, *h0hi, *h1hi, *encout;
  u16 *dWih0h,*dWih0l,*dWih1h,*dWih1l,*dWhhh,*dWhhl;
  u16 *Wwhh,*Wwhl,*Wwxh,*Wwxl,*Wchh,*Wchl,*Wcxh,*Wcxl,*o1wh,*o1wl,*o2wh,*o2wl;
  u16 *xth,*xtl;
  float *preW,*preC;
  u16 *dh0h,*dh0l,*dh1h,*dh1l;
  float *logits,*aw;
  u16 *wcth,*wctl,*xch,*xcl,*o1h,*o1l;
};

// ---- grid barrier: round-2 proven protocol (full fences both sides) -------
__device__ void gbar(unsigned* flags, unsigned* genp, unsigned target){
  __syncthreads();
  __threadfence();
  int wg = blockIdx.x, tid = threadIdx.x;
  if (wg == 0){
    if (tid > 0 && tid < NWG){
      while (__hip_atomic_load(&flags[tid], __ATOMIC_ACQUIRE, __HIP_MEMORY_SCOPE_AGENT) < target)
        __builtin_amdgcn_s_sleep(2);
    }
    __syncthreads();
    if (tid == 0)
      __hip_atomic_store(genp, target, __ATOMIC_RELEASE, __HIP_MEMORY_SCOPE_AGENT);
  } else {
    if (tid == 0){
      __hip_atomic_store(&flags[wg], target, __ATOMIC_RELEASE, __HIP_MEMORY_SCOPE_AGENT);
      while (__hip_atomic_load(genp, __ATOMIC_ACQUIRE, __HIP_MEMORY_SCOPE_AGENT) < target)
        __builtin_amdgcn_s_sleep(2);
    }
  }
  __threadfence();
  __syncthreads();
}

// ---- generic 64x16 tile of  C = A @ B^T  (split-bf16 3-pass) --------------
__device__ __forceinline__ v4f tile_xwT(const u16* Ah, const u16* Al, size_t lda, int nks,
                                        const u16* Bh, const u16* Bl, size_t ldb,
                                        int row0, int brow0, v4f* red){
  int tid = threadIdx.x, w = tid >> 6, lane = tid & 63;
  v4f acc[4];
  #pragma unroll
  for (int i=0;i<4;i++) acc[i] = (v4f){0.f,0.f,0.f,0.f};
  for (int ks = w; ks < nks; ks += 4){
    int k0 = ks * 32;
    v8s bh = ldfrag(Bh, ldb, brow0, k0);
    v8s bl = ldfrag(Bl, ldb, brow0, k0);
    #pragma unroll
    for (int rt=0; rt<4; rt++){
      v8s a  = ldfrag(Ah, lda, row0 + rt*16, k0);
      v8s al = ldfrag(Al, lda, row0 + rt*16, k0);
      acc[rt] = MFMA_(a,  bh, acc[rt]);
      acc[rt] = MFMA_(al, bh, acc[rt]);
      acc[rt] = MFMA_(a,  bl, acc[rt]);
    }
  }
  __syncthreads();
  red[(0*4+w)*64+lane]=acc[0]; red[(1*4+w)*64+lane]=acc[1];
  red[(2*4+w)*64+lane]=acc[2]; red[(3*4+w)*64+lane]=acc[3];
  __syncthreads();
  v4f g = red[(w*4+0)*64+lane];
  g += red[(w*4+1)*64+lane]; g += red[(w*4+2)*64+lane]; g += red[(w*4+3)*64+lane];
  return g;
}

// ---- decoder GRU gate tile: acc types {0:r, 1:z, 2:n_i, 3:n_h} ------------
template<bool PAIR>
__device__ __forceinline__ void gru_tile(const u16* Axh, const u16* Axl, size_t ldx, int nkx,
                                         const u16* Ahh, const u16* Ahl, size_t ldh, int nkh,
                                         const u16* Wi,  const u16* Wil, size_t ldwi,
                                         const u16* Wh,  const u16* Whl, size_t ldwh,
                                         int row0, int col0, v4f* red, v4f* gate){
  int tid = threadIdx.x, w = tid >> 6, lane = tid & 63;
  v4f acc[4][4];
  #pragma unroll
  for (int i=0;i<4;i++){
    #pragma unroll
    for (int j=0;j<4;j++) acc[i][j] = (v4f){0.f,0.f,0.f,0.f};
  }
  for (int ks = w; ks < nkx; ks += 4){
    int k0 = ks * 32;
    v8s br = ldfrag(Wi, ldwi,        col0, k0);
    v8s bz = ldfrag(Wi, ldwi,  512 + col0, k0);
    v8s bn = ldfrag(Wi, ldwi, 1024 + col0, k0);
    v8s brl, bzl, bnl;
    if (PAIR){ brl = ldfrag(Wil, ldwi, col0, k0); bzl = ldfrag(Wil, ldwi, 512+col0, k0); bnl = ldfrag(Wil, ldwi, 1024+col0, k0); }
    #pragma unroll
    for (int rt=0; rt<4; rt++){
      v8s a = ldfrag(Axh, ldx, row0 + rt*16, k0);
      acc[rt][0] = MFMA_(a, br, acc[rt][0]);
      acc[rt][1] = MFMA_(a, bz, acc[rt][1]);
      acc[rt][2] = MFMA_(a, bn, acc[rt][2]);
      if (PAIR){
        v8s al = ldfrag(Axl, ldx, row0 + rt*16, k0);
        acc[rt][0] = MFMA_(al, br, acc[rt][0]); acc[rt][0] = MFMA_(a, brl, acc[rt][0]);
        acc[rt][1] = MFMA_(al, bz, acc[rt][1]); acc[rt][1] = MFMA_(a, bzl, acc[rt][1]);
        acc[rt][2] = MFMA_(al, bn, acc[rt][2]); acc[rt][2] = MFMA_(a, bnl, acc[rt][2]);
      }
    }
  }
  for (int ks = w; ks < nkh; ks += 4){
    int k0 = ks * 32;
    v8s br = ldfrag(Wh, ldwh,        col0, k0);
    v8s bz = ldfrag(Wh, ldwh,  512 + col0, k0);
    v8s bn = ldfrag(Wh, ldwh, 1024 + col0, k0);
    v8s brl, bzl, bnl;
    if (PAIR){ brl = ldfrag(Whl, ldwh, col0, k0); bzl = ldfrag(Whl, ldwh, 512+col0, k0); bnl = ldfrag(Whl, ldwh, 1024+col0, k0); }
    #pragma unroll
    for (int rt=0; rt<4; rt++){
      v8s a = ldfrag(Ahh, ldh, row0 + rt*16, k0);
      acc[rt][0] = MFMA_(a, br, acc[rt][0]);
      acc[rt][1] = MFMA_(a, bz, acc[rt][1]);
      acc[rt][3] = MFMA_(a, bn, acc[rt][3]);
      if (PAIR){
        v8s al = ldfrag(Ahl, ldh, row0 + rt*16, k0);
        acc[rt][0] = MFMA_(al, br, acc[rt][0]); acc[rt][0] = MFMA_(a, brl, acc[rt][0]);
        acc[rt][1] = MFMA_(al, bz, acc[rt][1]); acc[rt][1] = MFMA_(a, bzl, acc[rt][1]);
        acc[rt][3] = MFMA_(al, bn, acc[rt][3]); acc[rt][3] = MFMA_(a, bnl, acc[rt][3]);
      }
    }
  }
  #pragma unroll
  for (int ty=0; ty<4; ty++){
    __syncthreads();
    red[(0*4+w)*64+lane]=acc[0][ty]; red[(1*4+w)*64+lane]=acc[1][ty];
    red[(2*4+w)*64+lane]=acc[2][ty]; red[(3*4+w)*64+lane]=acc[3][ty];
    __syncthreads();
    v4f g = red[(w*4+0)*64+lane];
    g += red[(w*4+1)*64+lane]; g += red[(w*4+2)*64+lane]; g += red[(w*4+3)*64+lane];
    gate[ty] = g;
  }
}

__device__ __forceinline__ void gru_combine(const v4f* gate, const float* bih, const float* bhh,
                                            const u16* Hph, const u16* Hpl,
                                            u16* Hnh, u16* Hnl, u16* encw, int t,
                                            int row0, int col0){
  int tid = threadIdx.x, w = tid >> 6, lane = tid & 63;
  int col  = col0 + (lane & 15);
  int rowb = row0 + w*16 + ((lane >> 4) << 2);
  float bir = bih[col], biz = bih[512+col], bin = bih[1024+col];
  float bhr = bhh[col], bhz = bhh[512+col], bhn = bhh[1024+col];
  #pragma unroll
  for (int e=0; e<4; e++){
    int row = rowb + e;
    float r = sigm(gate[0][e] + bir + bhr);
    float z = sigm(gate[1][e] + biz + bhz);
    float n = tanh_f(gate[2][e] + bin + r * (gate[3][e] + bhn));
    float hp = bf2f(Hph[(size_t)row*512 + col]);
    if (Hpl) hp += bf2f(Hpl[(size_t)row*512 + col]);
    float hv = (1.f - z) * n + z * hp;
    if (Hnl) splitstore(&Hnh[(size_t)row*512+col], &Hnl[(size_t)row*512+col], hv);
    else Hnh[(size_t)row*512+col] = f2bf(hv);
    if (encw) encw[((size_t)row*256 + t)*512 + col] = f2bf(hv);
  }
}

// ---- encoder step: A (x / h) from global, BOTH weights from LDS ------------
__device__ void enc_step(const u16* Xb, size_t ldX, const u16* Hp, u16* Hn,
                         u16* encw, int t, const u16* wI, const u16* wH,
                         const float* bih, const float* bhh,
                         int row0, int col0, v4f* red){
  const int tid = threadIdx.x, w = tid>>6, lane = tid&63;
  v4f acc[4][4];
  #pragma unroll
  for (int i=0;i<4;i++)
    #pragma unroll
    for (int j=0;j<4;j++) acc[i][j] = (v4f){0.f,0.f,0.f,0.f};
  for (int ks = w; ks < 16; ks += 4){
    int k0 = ks*32;
    v8s bi0=ldfrag_w(wI,0,ks), bi1=ldfrag_w(wI,1,ks), bi2=ldfrag_w(wI,2,ks);
    v8s bh0=ldfrag_w(wH,0,ks), bh1=ldfrag_w(wH,1,ks), bh2=ldfrag_w(wH,2,ks);
    #pragma unroll
    for (int rt=0; rt<4; rt++){
      v8s ax = ldfrag(Xb, ldX, row0 + rt*16, k0);
      v8s ah = ldfrag(Hp, 512, row0 + rt*16, k0);
      acc[rt][0] = MFMA_(ax, bi0, acc[rt][0]);
      acc[rt][1] = MFMA_(ax, bi1, acc[rt][1]);
      acc[rt][2] = MFMA_(ax, bi2, acc[rt][2]);
      acc[rt][0] = MFMA_(ah, bh0, acc[rt][0]);
      acc[rt][1] = MFMA_(ah, bh1, acc[rt][1]);
      acc[rt][3] = MFMA_(ah, bh2, acc[rt][3]);
    }
  }
  v4f gate[4];
  #pragma unroll
  for (int ty=0; ty<4; ty++){
    __syncthreads();
    red[(0*4+w)*64+lane]=acc[0][ty]; red[(1*4+w)*64+lane]=acc[1][ty];
    red[(2*4+w)*64+lane]=acc[2][ty]; red[(3*4+w)*64+lane]=acc[3][ty];
    __syncthreads();
    v4f g = red[(w*4+0)*64+lane];
    g += red[(w*4+1)*64+lane]; g += red[(w*4+2)*64+lane]; g += red[(w*4+3)*64+lane];
    gate[ty] = g;
  }
  int col  = col0 + (lane & 15);
  int rowb = row0 + w*16 + ((lane >> 4) << 2);
  float bir=bih[col], biz=bih[512+col], bin=bih[1024+col];
  float bhr=bhh[col], bhz=bhh[512+col], bhn=bhh[1024+col];
  #pragma unroll
  for (int e=0; e<4; e++){
    int row = rowb + e;
    float r = sigm(gate[0][e] + bir + bhr);
    float z = sigm(gate[1][e] + biz + bhz);
    float n = tanh_f(gate[2][e] + bin + r * (gate[3][e] + bhn));
    float hp = bf2f(Hp[(size_t)row*512 + col]);
    float hv = (1.f - z) * n + z * hp;
    Hn[(size_t)row*512 + col] = f2bf(hv);
    if (encw) encw[((size_t)row*256 + t)*512 + col] = f2bf(hv);
  }
}

__device__ __forceinline__ float blk_max(float v, float* sred){
  #pragma unroll
  for (int off=32; off>0; off>>=1) v = fmaxf(v, __shfl_xor(v, off, 64));
  __syncthreads();
  if ((threadIdx.x & 63) == 0) sred[threadIdx.x >> 6] = v;
  __syncthreads();
  return fmaxf(fmaxf(sred[0], sred[1]), fmaxf(sred[2], sred[3]));
}
__device__ __forceinline__ float blk_sum(float v, float* sred){
  #pragma unroll
  for (int off=32; off>0; off>>=1) v += __shfl_xor(v, off, 64);
  __syncthreads();
  if ((threadIdx.x & 63) == 0) sred[threadIdx.x >> 6] = v;
  __syncthreads();
  return sred[0] + sred[1] + sred[2] + sred[3];
}

#define DECOUT_OFF 0
#define DECHID_OFF 1228800      // 128*32*300
#define ATTN_OFF   1359872      // + 2*128*512

__global__ void __launch_bounds__(TPB, 1) traffic_kernel(KArgs A){
  __shared__ union {
    struct { u16 wI[3*16*64*8]; u16 wH[3*16*64*8]; } enc;   // 48KB + 48KB
    struct { float awl[2][256]; } dec;
  } U;
  __shared__ v4f red[4*4*64];   // 16KB reduce scratch
  __shared__ float sred[4];
  const int tid = threadIdx.x;
  const int wg  = blockIdx.x;
  const size_t gtid = (size_t)wg * TPB + tid;
  const size_t P = (size_t)NWG * TPB;
  unsigned bt = 0;

  // ================= Phase 0: conversion / padding / zeroing ===============
  for (size_t i=gtid; i<128UL*256*512; i+=P) A.xhi[i] = f2bf(A.x[i]);
  for (size_t i=gtid; i<1536UL*320; i+=P){
    size_t r=i/320, c=i%320;
    float v = (c<300)? A.dWih0_f[r*300+c] : 0.f;
    splitstore(&A.dWih0h[i], &A.dWih0l[i], v);
  }
  for (size_t i=gtid; i<1536UL*512; i+=P) splitstore(&A.dWih1h[i], &A.dWih1l[i], A.dWih1_f[i]);
  for (size_t i=gtid; i<2UL*1536*512; i+=P) splitstore(&A.dWhhh[i], &A.dWhhl[i], A.dWhh_f[i]);
  for (size_t i=gtid; i<256UL*512; i+=P){ size_t r=i>>9, c=i&511; splitstore(&A.Wwhh[i], &A.Wwhl[i], A.aWw_f[r*812+300+c]); }
  for (size_t i=gtid; i<256UL*320; i+=P){ size_t r=i/320, c=i%320; float v=(c<300)? A.aWw_f[r*812+c]:0.f; splitstore(&A.Wwxh[i], &A.Wwxl[i], v); }
  for (size_t i=gtid; i<304UL*512; i+=P){ size_t r=i>>9, c=i&511; float v=(r<300)? A.aCw_f[r*812+300+c]:0.f; splitstore(&A.Wchh[i], &A.Wchl[i], v); }
  for (size_t i=gtid; i<304UL*320; i+=P){ size_t r=i/320, c=i%320; float v=(r<300&&c<300)? A.aCw_f[r*812+c]:0.f; splitstore(&A.Wcxh[i], &A.Wcxl[i], v); }
  for (size_t i=gtid; i<304UL*512; i+=P){ size_t r=i>>9, c=i&511; float v=(r<300)? A.o1w_f[r*512+c]:0.f; splitstore(&A.o1wh[i], &A.o1wl[i], v); }
  for (size_t i=gtid; i<304UL*320; i+=P){ size_t r=i/320, c=i%320; float v=(r<300&&c<300)? A.o2w_f[r*300+c]:0.f; splitstore(&A.o2wh[i], &A.o2wl[i], v); }
  for (size_t i=gtid; i<32UL*128*320; i+=P){
    size_t sb=i/320, c=i%320, s2=sb>>7, b=sb&127;
    float v = (c<300)? A.target[(b*33+s2)*300 + c] : 0.f;
    splitstore(&A.xth[i], &A.xtl[i], v);
  }
  for (size_t i=gtid; i<65536; i+=P){ A.h0hi[i]=0; A.h1hi[i]=0; }
  for (size_t i=gtid; i<128UL*320; i+=P){ A.xch[i]=0; A.xcl[i]=0; A.o1h[i]=0; A.o1l[i]=0; }
  gbar(A.flags, A.genp, ++bt);

  // ================= Phase 0b: precompute xt-side attn linears =============
  for (int tl = wg; tl < 1024; tl += NWG){        // preW: (32*128) x 256
    int rb = tl >> 4, cb = tl & 15;
    int row0 = rb*64, col0 = cb*16;
    v4f g = tile_xwT(A.xth, A.xtl, 320, 10, A.Wwxh, A.Wwxl, 320, row0, col0, red);
    int w = tid>>6, lane = tid&63;
    int col = col0 + (lane&15), rowb = row0 + w*16 + ((lane>>4)<<2);
    #pragma unroll
    for (int e=0;e<4;e++){ int row=rowb+e; A.preW[(size_t)row*256+col] = g[e] + A.aWb[col]; }
  }
  for (int tl = wg; tl < 1216; tl += NWG){        // preC: (32*128) x 304
    int rb = tl / 19, cb = tl % 19;
    int row0 = rb*64, col0 = cb*16;
    v4f g = tile_xwT(A.xth, A.xtl, 320, 10, A.Wcxh, A.Wcxl, 320, row0, col0, red);
    int w = tid>>6, lane = tid&63;
    int col = col0 + (lane&15), rowb = row0 + w*16 + ((lane>>4)<<2);
    #pragma unroll
    for (int e=0;e<4;e++){
      int row=rowb+e;
      float v = (col<300)? (g[e] + A.aCb[col]) : 0.f;
      A.preC[(size_t)row*320+col] = v;
    }
  }
  gbar(A.flags, A.genp, ++bt);

  // ================= Encoder: weights LDS-pinned, barrier per step =========
  {
    int rb = wg >> 5, cb = wg & 31;
    int row0 = rb*64, col0 = cb*16;
    for (int l=0; l<2; l++){
      stage_wslice(A.eWih_f + (size_t)l*1536*512, U.enc.wI, col0);
      stage_wslice(A.eWhh_f + (size_t)l*1536*512, U.enc.wH, col0);
      __syncthreads();
      const float* bih = A.ebih + l*1536;
      const float* bhh = A.ebhh + l*1536;
      for (int t=0; t<256; t++){
        const u16* Xb; size_t ldX; const u16* Hp; u16* Hn; u16* encw;
        if (l==0){ Xb = A.xhi + (size_t)t*512; ldX = 256*512;
                   Hp = A.h0hi + (size_t)t*65536; Hn = A.h0hi + (size_t)(t+1)*65536; encw = nullptr; }
        else     { Xb = A.h0hi + (size_t)(t+1)*65536; ldX = 512;
                   Hp = A.h1hi + (size_t)(t&1)*65536; Hn = A.h1hi + (size_t)((t+1)&1)*65536; encw = A.encout; }
        enc_step(Xb, ldX, Hp, Hn, encw, t, U.enc.wI, U.enc.wH, bih, bhh, row0, col0, red);
        gbar(A.flags, A.genp, ++bt);
      }
    }
  }

  // ================= Decoder init: h = enc_hidden ==========================
  for (size_t i=gtid; i<65536; i+=P){
    A.dh0h[i] = A.h0hi[(size_t)256*65536 + i]; A.dh0l[i] = 0;
    A.dh1h[i] = A.h1hi[i];                     A.dh1l[i] = 0;   // layer1 final in buf 0
  }
  gbar(A.flags, A.genp, ++bt);

  // ================= Decoder: 32 steps (round-2 verbatim) ==================
  for (int s=0; s<32; s++){
    const u16* h0ph = A.dh0h + (size_t)(s&1)*65536;
    const u16* h0pl = A.dh0l + (size_t)(s&1)*65536;
    u16* h0nh = A.dh0h + (size_t)((s+1)&1)*65536;
    u16* h0nl = A.dh0l + (size_t)((s+1)&1)*65536;
    const u16* h1ph = A.dh1h + (size_t)(s&1)*65536;
    const u16* h1pl = A.dh1l + (size_t)(s&1)*65536;
    u16* h1nh = A.dh1h + (size_t)((s+1)&1)*65536;
    u16* h1nl = A.dh1l + (size_t)((s+1)&1)*65536;

    // S1: logits = preW[s] + h1 @ Wwh^T      (128 x 256)
    if (wg < 32){
      int rb = wg >> 4, cb = wg & 15;
      int row0 = rb*64, col0 = cb*16;
      v4f g = tile_xwT(h1ph, h1pl, 512, 16, A.Wwhh, A.Wwhl, 512, row0, col0, red);
      const float* pre = A.preW + (size_t)s*128*256;
      int w = tid>>6, lane = tid&63;
      int col = col0 + (lane&15), rowb = row0 + w*16 + ((lane>>4)<<2);
      #pragma unroll
      for (int e=0;e<4;e++){ int row=rowb+e; A.logits[(size_t)row*256+col] = g[e] + pre[(size_t)row*256+col]; }
    }
    gbar(A.flags, A.genp, ++bt);

    // S2: softmax rows -> aw, attn output
    {
      #pragma unroll
      for (int bi=0; bi<2; bi++){
        int b = wg*2 + bi;
        float v = A.logits[(size_t)b*256 + tid];
        float m = blk_max(v, sred);
        float e = __expf(v - m);
        float ssum = blk_sum(e, sred);
        float awv = e / ssum;
        A.aw[(size_t)b*256 + tid] = awv;
        A.out[ATTN_OFF + ((size_t)b*32 + s)*256 + tid] = awv;
      }
    }
    gbar(A.flags, A.genp, ++bt);

    // S3: wctx[b,h] = sum_t aw[b,t] * enc_out[b,t,h]
    {
      int b0 = wg*2, b1 = b0+1;
      float a00=0.f,a01=0.f,a10=0.f,a11=0.f;
      const float* aw0 = A.aw + (size_t)b0*256;
      const float* aw1 = A.aw + (size_t)b1*256;
      const u16* e0 = A.encout + (size_t)b0*256*512;
      const u16* e1 = A.encout + (size_t)b1*256*512;
      for (int t2=0; t2<256; t2++){
        float w0 = aw0[t2], w1 = aw1[t2];
        a00 += w0 * bf2f(e0[(size_t)t2*512 + tid]);
        a01 += w0 * bf2f(e0[(size_t)t2*512 + 256 + tid]);
        a10 += w1 * bf2f(e1[(size_t)t2*512 + tid]);
        a11 += w1 * bf2f(e1[(size_t)t2*512 + 256 + tid]);
      }
      splitstore(&A.wcth[(size_t)b0*512+tid],     &A.wctl[(size_t)b0*512+tid],     a00);
      splitstore(&A.wcth[(size_t)b0*512+256+tid], &A.wctl[(size_t)b0*512+256+tid], a01);
      splitstore(&A.wcth[(size_t)b1*512+tid],     &A.wctl[(size_t)b1*512+tid],     a10);
      splitstore(&A.wcth[(size_t)b1*512+256+tid], &A.wctl[(size_t)b1*512+256+tid], a11);
    }
    gbar(A.flags, A.genp, ++bt);

    // S4: xc = relu(preC[s] + wctx @ Wch^T)   (128 x 304, pads stay 0)
    if (wg < 38){
      int rb = wg / 19, cb = wg % 19;
      int row0 = rb*64, col0 = cb*16;
      v4f g = tile_xwT(A.wcth, A.wctl, 512, 16, A.Wchh, A.Wchl, 512, row0, col0, red);
      const float* pre = A.preC + (size_t)s*128*320;
      int w = tid>>6, lane = tid&63;
      int col = col0 + (lane&15), rowb = row0 + w*16 + ((lane>>4)<<2);
      #pragma unroll
      for (int e=0;e<4;e++){
        int row = rowb+e;
        float v = (col<300)? fmaxf(g[e] + pre[(size_t)row*320+col], 0.f) : 0.f;
        splitstore(&A.xch[(size_t)row*320+col], &A.xcl[(size_t)row*320+col], v);
      }
    }
    gbar(A.flags, A.genp, ++bt);

    // S5: GRU layer 0: h0' = gru(xc, h0)
    {
      int rb = wg >> 5, cb = wg & 31;
      int row0 = rb*64, col0 = cb*16;
      v4f gate[4];
      gru_tile<true>(A.xch, A.xcl, 320, 10, h0ph, h0pl, 512, 16,
                     A.dWih0h, A.dWih0l, 320, A.dWhhh, A.dWhhl, 512, row0, col0, red, gate);
      gru_combine(gate, A.dbih, A.dbhh, h0ph, h0pl, h0nh, h0nl, nullptr, 0, row0, col0);
    }
    gbar(A.flags, A.genp, ++bt);

    // S6: GRU layer 1: h1' = gru(h0', h1)
    {
      int rb = wg >> 5, cb = wg & 31;
      int row0 = rb*64, col0 = cb*16;
      v4f gate[4];
      gru_tile<true>(h0nh, h0nl, 512, 16, h1ph, h1pl, 512, 16,
                     A.dWih1h, A.dWih1l, 512,
                     A.dWhhh + (size_t)1536*512, A.dWhhl + (size_t)1536*512, 512,
                     row0, col0, red, gate);
      gru_combine(gate, A.dbih + 1536, A.dbhh + 1536, h1ph, h1pl, h1nh, h1nl, nullptr, 0, row0, col0);
    }
    gbar(A.flags, A.genp, ++bt);

    // S7: o1 = h1' @ out1^T + b1   (128 x 304)
    if (wg < 38){
      int rb = wg / 19, cb = wg % 19;
      int row0 = rb*64, col0 = cb*16;
      v4f g = tile_xwT(h1nh, h1nl, 512, 16, A.o1wh, A.o1wl, 512, row0, col0, red);
      int w = tid>>6, lane = tid&63;
      int col = col0 + (lane&15), rowb = row0 + w*16 + ((lane>>4)<<2);
      #pragma unroll
      for (int e=0;e<4;e++){
        int row = rowb+e;
        float v = (col<300)? (g[e] + A.o1b[col]) : 0.f;
        splitstore(&A.o1h[(size_t)row*320+col], &A.o1l[(size_t)row*320+col], v);
      }
    }
    gbar(A.flags, A.genp, ++bt);

    // S8: dec_out[:,s,:] = o1 @ out2^T + b2
    if (wg < 38){
      int rb = wg / 19, cb = wg % 19;
      int row0 = rb*64, col0 = cb*16;
      v4f g = tile_xwT(A.o1h, A.o1l, 320, 10, A.o2wh, A.o2wl, 320, row0, col0, red);
      int w = tid>>6, lane = tid&63;
      int col = col0 + (lane&15), rowb = row0 + w*16 + ((lane>>4)<<2);
      #pragma unroll
      for (int e=0;e<4;e++){
        int row = rowb+e;
        if (col < 300) A.out[DECOUT_OFF + ((size_t)row*32 + s)*300 + col] = g[e] + A.o2b[col];
      }
    }
    // no barrier needed before next step's S1 (h1' was barred after S6)
  }

  // ================= dec_hidden output (final h in buffer 0) ===============
  for (size_t i=gtid; i<65536; i+=P){
    A.out[DECHID_OFF + i]         = bf2f(A.dh0h[i]) + bf2f(A.dh0l[i]);
    A.out[DECHID_OFF + 65536 + i] = bf2f(A.dh1h[i]) + bf2f(A.dh1l[i]);
  }
}

// ===========================================================================
extern "C" void kernel_launch(void* const* d_in, const int* in_sizes, int n_in,
                              void* d_out, int out_size, void* d_ws, size_t ws_size,
                              hipStream_t stream){
  (void)in_sizes; (void)n_in; (void)out_size; (void)ws_size;
  KArgs A;
  A.x       = (const float*)d_in[0];  A.target = (const float*)d_in[1];
  A.eWih_f  = (const float*)d_in[2];  A.eWhh_f = (const float*)d_in[3];
  A.ebih    = (const float*)d_in[4];  A.ebhh   = (const float*)d_in[5];
  A.dWih0_f = (const float*)d_in[6];  A.dWih1_f= (const float*)d_in[7];
  A.dWhh_f  = (const float*)d_in[8];  A.dbih   = (const float*)d_in[9];
  A.dbhh    = (const float*)d_in[10];
  A.aWw_f   = (const float*)d_in[11]; A.aWb    = (const float*)d_in[12];
  A.aCw_f   = (const float*)d_in[13]; A.aCb    = (const float*)d_in[14];
  A.o1w_f   = (const float*)d_in[15]; A.o1b    = (const float*)d_in[16];
  A.o2w_f   = (const float*)d_in[17]; A.o2b    = (const float*)d_in[18];
  A.out = (float*)d_out;

  char* w = (char*)d_ws;
  size_t off = 0;
  auto alloc = [&](size_t bytes)->char*{
    char* p = w + off; off += (bytes + 255) & ~(size_t)255; return p;
  };
  char* barp = alloc(4096);
  A.flags = (unsigned*)barp;
  A.genp  = (unsigned*)(barp + 2048);
  A.xhi    = (u16*)alloc(128UL*256*512*2);
  A.h0hi   = (u16*)alloc(257UL*128*512*2);
  A.h1hi   = (u16*)alloc(2UL*128*512*2);
  A.encout = A.xhi;   // alias: xhi read only in encoder layer 0; encout written in layer 1
  A.dWih0h = (u16*)alloc(1536UL*320*2); A.dWih0l = (u16*)alloc(1536UL*320*2);
  A.dWih1h = (u16*)alloc(1536UL*512*2); A.dWih1l = (u16*)alloc(1536UL*512*2);
  A.dWhhh  = (u16*)alloc(2UL*1536*512*2); A.dWhhl = (u16*)alloc(2UL*1536*512*2);
  A.Wwhh   = (u16*)alloc(256UL*512*2);  A.Wwhl   = (u16*)alloc(256UL*512*2);
  A.Wwxh   = (u16*)alloc(256UL*320*2);  A.Wwxl   = (u16*)alloc(256UL*320*2);
  A.Wchh   = (u16*)alloc(304UL*512*2);  A.Wchl   = (u16*)alloc(304UL*512*2);
  A.Wcxh   = (u16*)alloc(304UL*320*2);  A.Wcxl   = (u16*)alloc(304UL*320*2);
  A.o1wh   = (u16*)alloc(304UL*512*2);  A.o1wl   = (u16*)alloc(304UL*512*2);
  A.o2wh   = (u16*)alloc(304UL*320*2);  A.o2wl   = (u16*)alloc(304UL*320*2);
  A.xth    = (u16*)alloc(32UL*128*320*2); A.xtl  = (u16*)alloc(32UL*128*320*2);
  A.preW   = (float*)alloc(32UL*128*256*4);
  A.preC   = (float*)alloc(32UL*128*320*4);
  A.dh0h   = (u16*)alloc(2UL*65536*2); A.dh0l = (u16*)alloc(2UL*65536*2);
  A.dh1h   = (u16*)alloc(2UL*65536*2); A.dh1l = (u16*)alloc(2UL*65536*2);
  A.logits = (float*)alloc(128UL*256*4);
  A.aw     = (float*)alloc(128UL*256*4);
  A.wcth   = (u16*)alloc(128UL*512*2); A.wctl = (u16*)alloc(128UL*512*2);
  A.xch    = (u16*)alloc(128UL*320*2); A.xcl  = (u16*)alloc(128UL*320*2);
  A.o1h    = (u16*)alloc(128UL*320*2); A.o1l  = (u16*)alloc(128UL*320*2);

  hipMemsetAsync(d_ws, 0, 4096, stream);   // reset barrier flags/gen each launch
  traffic_kernel<<<dim3(NWG), dim3(TPB), 0, stream>>>(A);
}

// Round 9
// 11863.027 us; speedup vs baseline: 6.0101x; 1.4794x over previous
//
#include <hip/hip_runtime.h>
#include <hip/hip_bf16.h>
#include <math.h>

// ---------------------------------------------------------------------------
// TrafficSeq2Seq round 9 = round-8 (proven, 17.8ms) with:
//  1. round-7-proven relaxed-RMW grid barrier (1 wb+inv per barrier, not per
//     poll iteration)
//  2. encoder layers pipelined: WGs 0-31 = layer0 step k, WGs 32-63 = layer1
//     step k-1 (both weight slices in LDS; 512 -> 257 encoder barriers; waves
//     own row-tiles x full K, so no cross-wave reduce)
//  3. decoder S2+S3 fused via LDS aw (-32 barriers)
// ---------------------------------------------------------------------------

#define NWG 64
#define TPB 256

typedef unsigned short u16;
typedef unsigned int   u32;
typedef short v8s __attribute__((ext_vector_type(8)));
typedef float v4f __attribute__((ext_vector_type(4)));

#define MFMA_(a,b,c) __builtin_amdgcn_mfma_f32_16x16x32_bf16((a),(b),(c),0,0,0)

__device__ __forceinline__ u16 f2bf(float f){
  unsigned u = __builtin_bit_cast(unsigned, f);
  unsigned r = u + 0x7FFFu + ((u >> 16) & 1u);
  return (u16)(r >> 16);
}
__device__ __forceinline__ float bf2f(u16 s){
  unsigned u = ((unsigned)s) << 16;
  return __builtin_bit_cast(float, u);
}
__device__ __forceinline__ void splitstore(u16* ph, u16* pl, float v){
  u16 h = f2bf(v); ph[0] = h; pl[0] = f2bf(v - bf2f(h));
}
__device__ __forceinline__ float sigm(float x){ return 1.f / (1.f + __expf(-x)); }
__device__ __forceinline__ float tanh_f(float x){
  float ax = fabsf(x);
  float t = __expf(-2.f * ax);
  float r = (1.f - t) / (1.f + t);
  return copysignf(r, x);
}

// fragment load: lane holds M[(r0+(lane&15))*ld + k0 + (lane>>4)*8 .. +8)
__device__ __forceinline__ v8s ldfrag(const u16* base, size_t ld, int r0, int k0){
  int lane = threadIdx.x & 63;
  const u16* p = base + (size_t)(r0 + (lane & 15)) * ld + (size_t)(k0 + ((lane >> 4) << 3));
  return *(const v8s*)p;
}

// ---- LDS weight slice: [3 gates][16 rows][64 chunks of 8], chunk ^= (row&7)
__device__ __forceinline__ v8s ldfrag_w(const u16* wlds, int gate, int kt){
  int lane = threadIdx.x & 63;
  int rr = lane & 15;
  int ch = (kt*4 + (lane >> 4)) ^ (rr & 7);
  return *(const v8s*)(wlds + (size_t)((gate*16 + rr)*64 + ch) * 8);
}
__device__ void stage_wslice(const float* Wf, u16* wlds, int col0){
  for (int idx = threadIdx.x; idx < 3*16*64; idx += TPB){
    int ch = idx & 63, rr = (idx >> 6) & 15, g = idx >> 10;
    const float* src = Wf + ((size_t)(g*512 + col0 + rr))*512 + ch*8;
    v4f f0 = *(const v4f*)src, f1 = *(const v4f*)(src + 4);
    v8s o;
    #pragma unroll
    for (int j=0;j<4;j++){ o[j] = (short)f2bf(f0[j]); o[4+j] = (short)f2bf(f1[j]); }
    *(v8s*)(wlds + (size_t)((g*16 + rr)*64 + (ch ^ (rr & 7))) * 8) = o;
  }
}

struct KArgs {
  // inputs (f32)
  const float *x, *target, *eWih_f, *eWhh_f, *ebih, *ebhh;
  const float *dWih0_f, *dWih1_f, *dWhh_f, *dbih, *dbhh;
  const float *aWw_f, *aWb, *aCw_f, *aCb, *o1w_f, *o1b, *o2w_f, *o2b;
  float* out;
  // barrier
  u32 *flags, *genp;
  // bf16 weights / activations in ws
  u16 *xhi, *h0hi, *h1hi, *encout;
  u16 *dWih0h,*dWih0l,*dWih1h,*dWih1l,*dWhhh,*dWhhl;
  u16 *Wwhh,*Wwhl,*Wwxh,*Wwxl,*Wchh,*Wchl,*Wcxh,*Wcxl,*o1wh,*o1wl,*o2wh,*o2wl;
  u16 *xth,*xtl;
  float *preW,*preC;
  u16 *dh0h,*dh0l,*dh1h,*dh1l;
  float *logits;
  u16 *wcth,*wctl,*xch,*xcl,*o1h,*o1l;
};

// ---- grid barrier: round-7-proven relaxed-RMW protocol --------------------
// arrival = RELEASE RMW (orders prior writes, 1 wb); polls = RELAXED RMW
// (coherence-point read, no cache maintenance); exit = 1 ACQUIRE fence (inv).
__device__ void gbar(u32* flags, u32* genp, u32 target){
  __syncthreads();
  int wg = blockIdx.x, tid = threadIdx.x;
  if (wg == 0){
    if (tid > 0 && tid < NWG){
      while (__hip_atomic_fetch_add(&flags[tid], 0u, __ATOMIC_RELAXED, __HIP_MEMORY_SCOPE_AGENT) < target)
        __builtin_amdgcn_s_sleep(2);
    }
    __syncthreads();
    if (tid == 0)
      __hip_atomic_fetch_add(genp, 1u, __ATOMIC_RELEASE, __HIP_MEMORY_SCOPE_AGENT);
  } else {
    if (tid == 0){
      __hip_atomic_fetch_add(&flags[wg], 1u, __ATOMIC_RELEASE, __HIP_MEMORY_SCOPE_AGENT);
      while (__hip_atomic_fetch_add(genp, 0u, __ATOMIC_RELAXED, __HIP_MEMORY_SCOPE_AGENT) < target)
        __builtin_amdgcn_s_sleep(2);
    }
  }
  __builtin_amdgcn_fence(__ATOMIC_ACQUIRE, "agent");
  __syncthreads();
}

// ---- generic 64x16 tile of  C = A @ B^T  (split-bf16 3-pass) --------------
__device__ __forceinline__ v4f tile_xwT(const u16* Ah, const u16* Al, size_t lda, int nks,
                                        const u16* Bh, const u16* Bl, size_t ldb,
                                        int row0, int brow0, v4f* red){
  int tid = threadIdx.x, w = tid >> 6, lane = tid & 63;
  v4f acc[4];
  #pragma unroll
  for (int i=0;i<4;i++) acc[i] = (v4f){0.f,0.f,0.f,0.f};
  for (int ks = w; ks < nks; ks += 4){
    int k0 = ks * 32;
    v8s bh = ldfrag(Bh, ldb, brow0, k0);
    v8s bl = ldfrag(Bl, ldb, brow0, k0);
    #pragma unroll
    for (int rt=0; rt<4; rt++){
      v8s a  = ldfrag(Ah, lda, row0 + rt*16, k0);
      v8s al = ldfrag(Al, lda, row0 + rt*16, k0);
      acc[rt] = MFMA_(a,  bh, acc[rt]);
      acc[rt] = MFMA_(al, bh, acc[rt]);
      acc[rt] = MFMA_(a,  bl, acc[rt]);
    }
  }
  __syncthreads();
  red[(0*4+w)*64+lane]=acc[0]; red[(1*4+w)*64+lane]=acc[1];
  red[(2*4+w)*64+lane]=acc[2]; red[(3*4+w)*64+lane]=acc[3];
  __syncthreads();
  v4f g = red[(w*4+0)*64+lane];
  g += red[(w*4+1)*64+lane]; g += red[(w*4+2)*64+lane]; g += red[(w*4+3)*64+lane];
  return g;
}

// ---- decoder GRU gate tile: acc types {0:r, 1:z, 2:n_i, 3:n_h} ------------
template<bool PAIR>
__device__ __forceinline__ void gru_tile(const u16* Axh, const u16* Axl, size_t ldx, int nkx,
                                         const u16* Ahh, const u16* Ahl, size_t ldh, int nkh,
                                         const u16* Wi,  const u16* Wil, size_t ldwi,
                                         const u16* Wh,  const u16* Whl, size_t ldwh,
                                         int row0, int col0, v4f* red, v4f* gate){
  int tid = threadIdx.x, w = tid >> 6, lane = tid & 63;
  v4f acc[4][4];
  #pragma unroll
  for (int i=0;i<4;i++){
    #pragma unroll
    for (int j=0;j<4;j++) acc[i][j] = (v4f){0.f,0.f,0.f,0.f};
  }
  for (int ks = w; ks < nkx; ks += 4){
    int k0 = ks * 32;
    v8s br = ldfrag(Wi, ldwi,        col0, k0);
    v8s bz = ldfrag(Wi, ldwi,  512 + col0, k0);
    v8s bn = ldfrag(Wi, ldwi, 1024 + col0, k0);
    v8s brl, bzl, bnl;
    if (PAIR){ brl = ldfrag(Wil, ldwi, col0, k0); bzl = ldfrag(Wil, ldwi, 512+col0, k0); bnl = ldfrag(Wil, ldwi, 1024+col0, k0); }
    #pragma unroll
    for (int rt=0; rt<4; rt++){
      v8s a = ldfrag(Axh, ldx, row0 + rt*16, k0);
      acc[rt][0] = MFMA_(a, br, acc[rt][0]);
      acc[rt][1] = MFMA_(a, bz, acc[rt][1]);
      acc[rt][2] = MFMA_(a, bn, acc[rt][2]);
      if (PAIR){
        v8s al = ldfrag(Axl, ldx, row0 + rt*16, k0);
        acc[rt][0] = MFMA_(al, br, acc[rt][0]); acc[rt][0] = MFMA_(a, brl, acc[rt][0]);
        acc[rt][1] = MFMA_(al, bz, acc[rt][1]); acc[rt][1] = MFMA_(a, bzl, acc[rt][1]);
        acc[rt][2] = MFMA_(al, bn, acc[rt][2]); acc[rt][2] = MFMA_(a, bnl, acc[rt][2]);
      }
    }
  }
  for (int ks = w; ks < nkh; ks += 4){
    int k0 = ks * 32;
    v8s br = ldfrag(Wh, ldwh,        col0, k0);
    v8s bz = ldfrag(Wh, ldwh,  512 + col0, k0);
    v8s bn = ldfrag(Wh, ldwh, 1024 + col0, k0);
    v8s brl, bzl, bnl;
    if (PAIR){ brl = ldfrag(Whl, ldwh, col0, k0); bzl = ldfrag(Whl, ldwh, 512+col0, k0); bnl = ldfrag(Whl, ldwh, 1024+col0, k0); }
    #pragma unroll
    for (int rt=0; rt<4; rt++){
      v8s a = ldfrag(Ahh, ldh, row0 + rt*16, k0);
      acc[rt][0] = MFMA_(a, br, acc[rt][0]);
      acc[rt][1] = MFMA_(a, bz, acc[rt][1]);
      acc[rt][3] = MFMA_(a, bn, acc[rt][3]);
      if (PAIR){
        v8s al = ldfrag(Ahl, ldh, row0 + rt*16, k0);
        acc[rt][0] = MFMA_(al, br, acc[rt][0]); acc[rt][0] = MFMA_(a, brl, acc[rt][0]);
        acc[rt][1] = MFMA_(al, bz, acc[rt][1]); acc[rt][1] = MFMA_(a, bzl, acc[rt][1]);
        acc[rt][3] = MFMA_(al, bn, acc[rt][3]); acc[rt][3] = MFMA_(a, bnl, acc[rt][3]);
      }
    }
  }
  #pragma unroll
  for (int ty=0; ty<4; ty++){
    __syncthreads();
    red[(0*4+w)*64+lane]=acc[0][ty]; red[(1*4+w)*64+lane]=acc[1][ty];
    red[(2*4+w)*64+lane]=acc[2][ty]; red[(3*4+w)*64+lane]=acc[3][ty];
    __syncthreads();
    v4f g = red[(w*4+0)*64+lane];
    g += red[(w*4+1)*64+lane]; g += red[(w*4+2)*64+lane]; g += red[(w*4+3)*64+lane];
    gate[ty] = g;
  }
}

__device__ __forceinline__ void gru_combine(const v4f* gate, const float* bih, const float* bhh,
                                            const u16* Hph, const u16* Hpl,
                                            u16* Hnh, u16* Hnl,
                                            int row0, int col0){
  int tid = threadIdx.x, w = tid >> 6, lane = tid & 63;
  int col  = col0 + (lane & 15);
  int rowb = row0 + w*16 + ((lane >> 4) << 2);
  float bir = bih[col], biz = bih[512+col], bin = bih[1024+col];
  float bhr = bhh[col], bhz = bhh[512+col], bhn = bhh[1024+col];
  #pragma unroll
  for (int e=0; e<4; e++){
    int row = rowb + e;
    float r = sigm(gate[0][e] + bir + bhr);
    float z = sigm(gate[1][e] + biz + bhz);
    float n = tanh_f(gate[2][e] + bin + r * (gate[3][e] + bhn));
    float hp = bf2f(Hph[(size_t)row*512 + col]) + bf2f(Hpl[(size_t)row*512 + col]);
    float hv = (1.f - z) * n + z * hp;
    splitstore(&Hnh[(size_t)row*512+col], &Hnl[(size_t)row*512+col], hv);
  }
}

// ---- pipelined encoder step: waves own 2 row-tiles x full K; no reduce -----
__device__ void enc_step2(const u16* Xb, size_t ldX, const u16* Hp, u16* Hn,
                          u16* encw, int t, const u16* wI, const u16* wH,
                          const float* bih, const float* bhh, int col0){
  const int tid = threadIdx.x, w = tid>>6, lane = tid&63;
  v4f aR[2], aZ[2], aNI[2], aNH[2];
  #pragma unroll
  for (int j=0;j<2;j++){ aR[j]=(v4f){0,0,0,0}; aZ[j]=(v4f){0,0,0,0}; aNI[j]=(v4f){0,0,0,0}; aNH[j]=(v4f){0,0,0,0}; }
  for (int kt=0; kt<16; ++kt){
    int k0 = kt*32;
    v8s bi0=ldfrag_w(wI,0,kt), bi1=ldfrag_w(wI,1,kt), bi2=ldfrag_w(wI,2,kt);
    v8s bh0=ldfrag_w(wH,0,kt), bh1=ldfrag_w(wH,1,kt), bh2=ldfrag_w(wH,2,kt);
    #pragma unroll
    for (int j=0;j<2;j++){
      int r0 = (w*2+j)*16;
      v8s ax = ldfrag(Xb, ldX, r0, k0);
      v8s ah = ldfrag(Hp, 512, r0, k0);
      aR[j]=MFMA_(ax,bi0,aR[j]); aZ[j]=MFMA_(ax,bi1,aZ[j]); aNI[j]=MFMA_(ax,bi2,aNI[j]);
      aR[j]=MFMA_(ah,bh0,aR[j]); aZ[j]=MFMA_(ah,bh1,aZ[j]); aNH[j]=MFMA_(ah,bh2,aNH[j]);
    }
  }
  int col = col0 + (lane&15);
  float bir=bih[col], biz=bih[512+col], bin=bih[1024+col];
  float bhr=bhh[col], bhz=bhh[512+col], bhn=bhh[1024+col];
  #pragma unroll
  for (int j=0;j<2;j++){
    int rowb = (w*2+j)*16 + ((lane>>4)<<2);
    #pragma unroll
    for (int e=0;e<4;e++){
      int row = rowb + e;
      float r = sigm(aR[j][e] + bir + bhr);
      float z = sigm(aZ[j][e] + biz + bhz);
      float n = tanh_f(aNI[j][e] + bin + r*(aNH[j][e] + bhn));
      float hp = bf2f(Hp[(size_t)row*512 + col]);
      float hv = (1.f-z)*n + z*hp;
      u16 h16 = f2bf(hv);
      Hn[(size_t)row*512 + col] = h16;
      if (encw) encw[((size_t)row*256 + t)*512 + col] = h16;
    }
  }
}

__device__ __forceinline__ float blk_max(float v, float* sred){
  #pragma unroll
  for (int off=32; off>0; off>>=1) v = fmaxf(v, __shfl_xor(v, off, 64));
  __syncthreads();
  if ((threadIdx.x & 63) == 0) sred[threadIdx.x >> 6] = v;
  __syncthreads();
  return fmaxf(fmaxf(sred[0], sred[1]), fmaxf(sred[2], sred[3]));
}
__device__ __forceinline__ float blk_sum(float v, float* sred){
  #pragma unroll
  for (int off=32; off>0; off>>=1) v += __shfl_xor(v, off, 64);
  __syncthreads();
  if ((threadIdx.x & 63) == 0) sred[threadIdx.x >> 6] = v;
  __syncthreads();
  return sred[0] + sred[1] + sred[2] + sred[3];
}

#define DECOUT_OFF 0
#define DECHID_OFF 1228800      // 128*32*300
#define ATTN_OFF   1359872      // + 2*128*512

__global__ void __launch_bounds__(TPB, 1) traffic_kernel(KArgs A){
  __shared__ union {
    struct { u16 wI[3*16*64*8]; u16 wH[3*16*64*8]; } enc;   // 48KB + 48KB
    struct { float awl[2][256]; } dec;
  } U;
  __shared__ v4f red[4*4*64];   // 16KB reduce scratch
  __shared__ float sred[4];
  const int tid = threadIdx.x;
  const int wg  = blockIdx.x;
  const size_t gtid = (size_t)wg * TPB + tid;
  const size_t P = (size_t)NWG * TPB;
  u32 bt = 0;

  // ================= Phase 0: conversion / padding / zeroing ===============
  for (size_t i=gtid; i<128UL*256*512; i+=P) A.xhi[i] = f2bf(A.x[i]);
  for (size_t i=gtid; i<1536UL*320; i+=P){
    size_t r=i/320, c=i%320;
    float v = (c<300)? A.dWih0_f[r*300+c] : 0.f;
    splitstore(&A.dWih0h[i], &A.dWih0l[i], v);
  }
  for (size_t i=gtid; i<1536UL*512; i+=P) splitstore(&A.dWih1h[i], &A.dWih1l[i], A.dWih1_f[i]);
  for (size_t i=gtid; i<2UL*1536*512; i+=P) splitstore(&A.dWhhh[i], &A.dWhhl[i], A.dWhh_f[i]);
  for (size_t i=gtid; i<256UL*512; i+=P){ size_t r=i>>9, c=i&511; splitstore(&A.Wwhh[i], &A.Wwhl[i], A.aWw_f[r*812+300+c]); }
  for (size_t i=gtid; i<256UL*320; i+=P){ size_t r=i/320, c=i%320; float v=(c<300)? A.aWw_f[r*812+c]:0.f; splitstore(&A.Wwxh[i], &A.Wwxl[i], v); }
  for (size_t i=gtid; i<304UL*512; i+=P){ size_t r=i>>9, c=i&511; float v=(r<300)? A.aCw_f[r*812+300+c]:0.f; splitstore(&A.Wchh[i], &A.Wchl[i], v); }
  for (size_t i=gtid; i<304UL*320; i+=P){ size_t r=i/320, c=i%320; float v=(r<300&&c<300)? A.aCw_f[r*812+c]:0.f; splitstore(&A.Wcxh[i], &A.Wcxl[i], v); }
  for (size_t i=gtid; i<304UL*512; i+=P){ size_t r=i>>9, c=i&511; float v=(r<300)? A.o1w_f[r*512+c]:0.f; splitstore(&A.o1wh[i], &A.o1wl[i], v); }
  for (size_t i=gtid; i<304UL*320; i+=P){ size_t r=i/320, c=i%320; float v=(r<300&&c<300)? A.o2w_f[r*300+c]:0.f; splitstore(&A.o2wh[i], &A.o2wl[i], v); }
  for (size_t i=gtid; i<32UL*128*320; i+=P){
    size_t sb=i/320, c=i%320, s2=sb>>7, b=sb&127;
    float v = (c<300)? A.target[(b*33+s2)*300 + c] : 0.f;
    splitstore(&A.xth[i], &A.xtl[i], v);
  }
  for (size_t i=gtid; i<65536; i+=P){ A.h0hi[i]=0; A.h1hi[i]=0; }
  for (size_t i=gtid; i<128UL*320; i+=P){ A.xch[i]=0; A.xcl[i]=0; A.o1h[i]=0; A.o1l[i]=0; }
  gbar(A.flags, A.genp, ++bt);

  // ================= Phase 0b: precompute xt-side attn linears =============
  for (int tl = wg; tl < 1024; tl += NWG){        // preW: (32*128) x 256
    int rb = tl >> 4, cb = tl & 15;
    int row0 = rb*64, col0 = cb*16;
    v4f g = tile_xwT(A.xth, A.xtl, 320, 10, A.Wwxh, A.Wwxl, 320, row0, col0, red);
    int w = tid>>6, lane = tid&63;
    int col = col0 + (lane&15), rowb = row0 + w*16 + ((lane>>4)<<2);
    #pragma unroll
    for (int e=0;e<4;e++){ int row=rowb+e; A.preW[(size_t)row*256+col] = g[e] + A.aWb[col]; }
  }
  for (int tl = wg; tl < 1216; tl += NWG){        // preC: (32*128) x 304
    int rb = tl / 19, cb = tl % 19;
    int row0 = rb*64, col0 = cb*16;
    v4f g = tile_xwT(A.xth, A.xtl, 320, 10, A.Wcxh, A.Wcxl, 320, row0, col0, red);
    int w = tid>>6, lane = tid&63;
    int col = col0 + (lane&15), rowb = row0 + w*16 + ((lane>>4)<<2);
    #pragma unroll
    for (int e=0;e<4;e++){
      int row=rowb+e;
      float v = (col<300)? (g[e] + A.aCb[col]) : 0.f;
      A.preC[(size_t)row*320+col] = v;
    }
  }
  gbar(A.flags, A.genp, ++bt);

  // ================= Encoder: 2 layers PIPELINED, 257 barriers =============
  {
    const int grp  = wg >> 5;            // 0: layer0 (WGs 0-31), 1: layer1
    const int col0 = (wg & 31) * 16;
    stage_wslice(A.eWih_f + (size_t)grp*1536*512, U.enc.wI, col0);
    stage_wslice(A.eWhh_f + (size_t)grp*1536*512, U.enc.wH, col0);
    __syncthreads();
    const float* bih = A.ebih + grp*1536;
    const float* bhh = A.ebhh + grp*1536;
    for (int k=0; k<=256; ++k){
      if (grp == 0){
        if (k < 256)
          enc_step2(A.xhi + (size_t)k*512, (size_t)256*512,
                    A.h0hi + (size_t)k*65536, A.h0hi + (size_t)(k+1)*65536,
                    nullptr, 0, U.enc.wI, U.enc.wH, bih, bhh, col0);
      } else {
        if (k >= 1){
          int t = k-1;
          // layer1 input at time t = layer0 output at t = h0hi[t+1] = h0hi[k]
          enc_step2(A.h0hi + (size_t)k*65536, 512,
                    A.h1hi + (size_t)(t&1)*65536, A.h1hi + (size_t)((t+1)&1)*65536,
                    A.encout, t, U.enc.wI, U.enc.wH, bih, bhh, col0);
        }
      }
      gbar(A.flags, A.genp, ++bt);
    }
  }

  // ================= Decoder init: h = enc_hidden ==========================
  for (size_t i=gtid; i<65536; i+=P){
    A.dh0h[i] = A.h0hi[(size_t)256*65536 + i]; A.dh0l[i] = 0;
    A.dh1h[i] = A.h1hi[i];                     A.dh1l[i] = 0;   // layer1 final in buf 0
  }
  gbar(A.flags, A.genp, ++bt);

  // ================= Decoder: 32 steps, 6 barriers/step ====================
  for (int s=0; s<32; s++){
    const u16* h0ph = A.dh0h + (size_t)(s&1)*65536;
    const u16* h0pl = A.dh0l + (size_t)(s&1)*65536;
    u16* h0nh = A.dh0h + (size_t)((s+1)&1)*65536;
    u16* h0nl = A.dh0l + (size_t)((s+1)&1)*65536;
    const u16* h1ph = A.dh1h + (size_t)(s&1)*65536;
    const u16* h1pl = A.dh1l + (size_t)(s&1)*65536;
    u16* h1nh = A.dh1h + (size_t)((s+1)&1)*65536;
    u16* h1nl = A.dh1l + (size_t)((s+1)&1)*65536;

    // S1: logits = preW[s] + h1 @ Wwh^T      (128 x 256)
    if (wg < 32){
      int rb = wg >> 4, cb = wg & 15;
      int row0 = rb*64, col0 = cb*16;
      v4f g = tile_xwT(h1ph, h1pl, 512, 16, A.Wwhh, A.Wwhl, 512, row0, col0, red);
      const float* pre = A.preW + (size_t)s*128*256;
      int w = tid>>6, lane = tid&63;
      int col = col0 + (lane&15), rowb = row0 + w*16 + ((lane>>4)<<2);
      #pragma unroll
      for (int e=0;e<4;e++){ int row=rowb+e; A.logits[(size_t)row*256+col] = g[e] + pre[(size_t)row*256+col]; }
    }
    gbar(A.flags, A.genp, ++bt);

    // S2+S3 fused: softmax (aw in LDS) + weighted context
    {
      int b0 = wg*2, b1 = b0+1;
      #pragma unroll
      for (int bi=0; bi<2; bi++){
        int b = wg*2 + bi;
        float v = A.logits[(size_t)b*256 + tid];
        float m = blk_max(v, sred);
        float e = __expf(v - m);
        float ssum = blk_sum(e, sred);
        float awv = e / ssum;
        U.dec.awl[bi][tid] = awv;
        A.out[ATTN_OFF + ((size_t)b*32 + s)*256 + tid] = awv;
      }
      __syncthreads();
      float a00=0.f,a01=0.f,a10=0.f,a11=0.f;
      const u16* e0 = A.encout + (size_t)b0*256*512;
      const u16* e1 = A.encout + (size_t)b1*256*512;
      for (int t2=0; t2<256; t2++){
        float w0 = U.dec.awl[0][t2], w1 = U.dec.awl[1][t2];
        a00 += w0 * bf2f(e0[(size_t)t2*512 + tid]);
        a01 += w0 * bf2f(e0[(size_t)t2*512 + 256 + tid]);
        a10 += w1 * bf2f(e1[(size_t)t2*512 + tid]);
        a11 += w1 * bf2f(e1[(size_t)t2*512 + 256 + tid]);
      }
      splitstore(&A.wcth[(size_t)b0*512+tid],     &A.wctl[(size_t)b0*512+tid],     a00);
      splitstore(&A.wcth[(size_t)b0*512+256+tid], &A.wctl[(size_t)b0*512+256+tid], a01);
      splitstore(&A.wcth[(size_t)b1*512+tid],     &A.wctl[(size_t)b1*512+tid],     a10);
      splitstore(&A.wcth[(size_t)b1*512+256+tid], &A.wctl[(size_t)b1*512+256+tid], a11);
    }
    gbar(A.flags, A.genp, ++bt);

    // S4: xc = relu(preC[s] + wctx @ Wch^T)   (128 x 304, pads stay 0)
    if (wg < 38){
      int rb = wg / 19, cb = wg % 19;
      int row0 = rb*64, col0 = cb*16;
      v4f g = tile_xwT(A.wcth, A.wctl, 512, 16, A.Wchh, A.Wchl, 512, row0, col0, red);
      const float* pre = A.preC + (size_t)s*128*320;
      int w = tid>>6, lane = tid&63;
      int col = col0 + (lane&15), rowb = row0 + w*16 + ((lane>>4)<<2);
      #pragma unroll
      for (int e=0;e<4;e++){
        int row = rowb+e;
        float v = (col<300)? fmaxf(g[e] + pre[(size_t)row*320+col], 0.f) : 0.f;
        splitstore(&A.xch[(size_t)row*320+col], &A.xcl[(size_t)row*320+col], v);
      }
    }
    gbar(A.flags, A.genp, ++bt);

    // S5: GRU layer 0: h0' = gru(xc, h0)
    {
      int rb = wg >> 5, cb = wg & 31;
      int row0 = rb*64, col0 = cb*16;
      v4f gate[4];
      gru_tile<true>(A.xch, A.xcl, 320, 10, h0ph, h0pl, 512, 16,
                     A.dWih0h, A.dWih0l, 320, A.dWhhh, A.dWhhl, 512, row0, col0, red, gate);
      gru_combine(gate, A.dbih, A.dbhh, h0ph, h0pl, h0nh, h0nl, row0, col0);
    }
    gbar(A.flags, A.genp, ++bt);

    // S6: GRU layer 1: h1' = gru(h0', h1)
    {
      int rb = wg >> 5, cb = wg & 31;
      int row0 = rb*64, col0 = cb*16;
      v4f gate[4];
      gru_tile<true>(h0nh, h0nl, 512, 16, h1ph, h1pl, 512, 16,
                     A.dWih1h, A.dWih1l, 512,
                     A.dWhhh + (size_t)1536*512, A.dWhhl + (size_t)1536*512, 512,
                     row0, col0, red, gate);
      gru_combine(gate, A.dbih + 1536, A.dbhh + 1536, h1ph, h1pl, h1nh, h1nl, row0, col0);
    }
    gbar(A.flags, A.genp, ++bt);

    // S7: o1 = h1' @ out1^T + b1   (128 x 304)
    if (wg < 38){
      int rb = wg / 19, cb = wg % 19;
      int row0 = rb*64, col0 = cb*16;
      v4f g = tile_xwT(h1nh, h1nl, 512, 16, A.o1wh, A.o1wl, 512, row0, col0, red);
      int w = tid>>6, lane = tid&63;
      int col = col0 + (lane&15), rowb = row0 + w*16 + ((lane>>4)<<2);
      #pragma unroll
      for (int e=0;e<4;e++){
        int row = rowb+e;
        float v = (col<300)? (g[e] + A.o1b[col]) : 0.f;
        splitstore(&A.o1h[(size_t)row*320+col], &A.o1l[(size_t)row*320+col], v);
      }
    }
    gbar(A.flags, A.genp, ++bt);

    // S8: dec_out[:,s,:] = o1 @ out2^T + b2
    if (wg < 38){
      int rb = wg / 19, cb = wg % 19;
      int row0 = rb*64, col0 = cb*16;
      v4f g = tile_xwT(A.o1h, A.o1l, 320, 10, A.o2wh, A.o2wl, 320, row0, col0, red);
      int w = tid>>6, lane = tid&63;
      int col = col0 + (lane&15), rowb = row0 + w*16 + ((lane>>4)<<2);
      #pragma unroll
      for (int e=0;e<4;e++){
        int row = rowb+e;
        if (col < 300) A.out[DECOUT_OFF + ((size_t)row*32 + s)*300 + col] = g[e] + A.o2b[col];
      }
    }
    // no barrier needed before next step's S1 (h1' was barred after S6)
  }

  // ================= dec_hidden output (final h in buffer 0) ===============
  for (size_t i=gtid; i<65536; i+=P){
    A.out[DECHID_OFF + i]         = bf2f(A.dh0h[i]) + bf2f(A.dh0l[i]);
    A.out[DECHID_OFF + 65536 + i] = bf2f(A.dh1h[i]) + bf2f(A.dh1l[i]);
  }
}

// ===========================================================================
extern "C" void kernel_launch(void* const* d_in, const int* in_sizes, int n_in,
                              void* d_out, int out_size, void* d_ws, size_t ws_size,
                              hipStream_t stream){
  (void)in_sizes; (void)n_in; (void)out_size; (void)ws_size;
  KArgs A;
  A.x       = (const float*)d_in[0];  A.target = (const float*)d_in[1];
  A.eWih_f  = (const float*)d_in[2];  A.eWhh_f = (const float*)d_in[3];
  A.ebih    = (const float*)d_in[4];  A.ebhh   = (const float*)d_in[5];
  A.dWih0_f = (const float*)d_in[6];  A.dWih1_f= (const float*)d_in[7];
  A.dWhh_f  = (const float*)d_in[8];  A.dbih   = (const float*)d_in[9];
  A.dbhh    = (const float*)d_in[10];
  A.aWw_f   = (const float*)d_in[11]; A.aWb    = (const float*)d_in[12];
  A.aCw_f   = (const float*)d_in[13]; A.aCb    = (const float*)d_in[14];
  A.o1w_f   = (const float*)d_in[15]; A.o1b    = (const float*)d_in[16];
  A.o2w_f   = (const float*)d_in[17]; A.o2b    = (const float*)d_in[18];
  A.out = (float*)d_out;

  char* w = (char*)d_ws;
  size_t off = 0;
  auto alloc = [&](size_t bytes)->char*{
    char* p = w + off; off += (bytes + 255) & ~(size_t)255; return p;
  };
  char* barp = alloc(4096);
  A.flags = (u32*)barp;
  A.genp  = (u32*)(barp + 2048);
  A.xhi    = (u16*)alloc(128UL*256*512*2);
  A.h0hi   = (u16*)alloc(257UL*128*512*2);
  A.h1hi   = (u16*)alloc(2UL*128*512*2);
  A.encout = A.xhi;   // alias: layer0 reads xhi[t=k] while layer1 writes
                      // encout[t=k-1] -- trailing by one t-slice, disjoint
  A.dWih0h = (u16*)alloc(1536UL*320*2); A.dWih0l = (u16*)alloc(1536UL*320*2);
  A.dWih1h = (u16*)alloc(1536UL*512*2); A.dWih1l = (u16*)alloc(1536UL*512*2);
  A.dWhhh  = (u16*)alloc(2UL*1536*512*2); A.dWhhl = (u16*)alloc(2UL*1536*512*2);
  A.Wwhh   = (u16*)alloc(256UL*512*2);  A.Wwhl   = (u16*)alloc(256UL*512*2);
  A.Wwxh   = (u16*)alloc(256UL*320*2);  A.Wwxl   = (u16*)alloc(256UL*320*2);
  A.Wchh   = (u16*)alloc(304UL*512*2);  A.Wchl   = (u16*)alloc(304UL*512*2);
  A.Wcxh   = (u16*)alloc(304UL*320*2);  A.Wcxl   = (u16*)alloc(304UL*320*2);
  A.o1wh   = (u16*)alloc(304UL*512*2);  A.o1wl   = (u16*)alloc(304UL*512*2);
  A.o2wh   = (u16*)alloc(304UL*320*2);  A.o2wl   = (u16*)alloc(304UL*320*2);
  A.xth    = (u16*)alloc(32UL*128*320*2); A.xtl  = (u16*)alloc(32UL*128*320*2);
  A.preW   = (float*)alloc(32UL*128*256*4);
  A.preC   = (float*)alloc(32UL*128*320*4);
  A.dh0h   = (u16*)alloc(2UL*65536*2); A.dh0l = (u16*)alloc(2UL*65536*2);
  A.dh1h   = (u16*)alloc(2UL*65536*2); A.dh1l = (u16*)alloc(2UL*65536*2);
  A.logits = (float*)alloc(128UL*256*4);
  A.wcth   = (u16*)alloc(128UL*512*2); A.wctl = (u16*)alloc(128UL*512*2);
  A.xch    = (u16*)alloc(128UL*320*2); A.xcl  = (u16*)alloc(128UL*320*2);
  A.o1h    = (u16*)alloc(128UL*320*2); A.o1l  = (u16*)alloc(128UL*320*2);

  hipMemsetAsync(d_ws, 0, 4096, stream);   // reset barrier flags/gen each launch
  traffic_kernel<<<dim3(NWG), dim3(TPB), 0, stream>>>(A);
}

// Round 10
// 11451.178 us; speedup vs baseline: 6.2262x; 1.0360x over previous
//
#include <hip/hip_runtime.h>
#include <hip/hip_bf16.h>
#include <math.h>

// ---------------------------------------------------------------------------
// TrafficSeq2Seq round 10 = round-9 (proven, 11.9ms) with:
//  1. two-level grid barrier: per-XCD leader does the single RELEASE (wbl2)
//     for its die (64 -> ~8 wbl2 per phase); everyone keeps the proven
//     agent ACQUIRE fence on exit. XCD id via s_getreg(HW_REG_XCC_ID).
//  2. S7+S8 fused via exact composite W' = o2w@o1w (f32 precompute, split
//     GEMM) and b' = o2w@o1b + o2b: 1 fewer phase/decoder-step (-32 phases).
// ---------------------------------------------------------------------------

#define NWG 64
#define TPB 256

typedef unsigned short u16;
typedef unsigned int   u32;
typedef short v8s __attribute__((ext_vector_type(8)));
typedef float v4f __attribute__((ext_vector_type(4)));

#define MFMA_(a,b,c) __builtin_amdgcn_mfma_f32_16x16x32_bf16((a),(b),(c),0,0,0)

__device__ __forceinline__ u16 f2bf(float f){
  unsigned u = __builtin_bit_cast(unsigned, f);
  unsigned r = u + 0x7FFFu + ((u >> 16) & 1u);
  return (u16)(r >> 16);
}
__device__ __forceinline__ float bf2f(u16 s){
  unsigned u = ((unsigned)s) << 16;
  return __builtin_bit_cast(float, u);
}
__device__ __forceinline__ void splitstore(u16* ph, u16* pl, float v){
  u16 h = f2bf(v); ph[0] = h; pl[0] = f2bf(v - bf2f(h));
}
__device__ __forceinline__ float sigm(float x){ return 1.f / (1.f + __expf(-x)); }
__device__ __forceinline__ float tanh_f(float x){
  float ax = fabsf(x);
  float t = __expf(-2.f * ax);
  float r = (1.f - t) / (1.f + t);
  return copysignf(r, x);
}

// fragment load: lane holds M[(r0+(lane&15))*ld + k0 + (lane>>4)*8 .. +8)
__device__ __forceinline__ v8s ldfrag(const u16* base, size_t ld, int r0, int k0){
  int lane = threadIdx.x & 63;
  const u16* p = base + (size_t)(r0 + (lane & 15)) * ld + (size_t)(k0 + ((lane >> 4) << 3));
  return *(const v8s*)p;
}

// ---- LDS weight slice: [3 gates][16 rows][64 chunks of 8], chunk ^= (row&7)
__device__ __forceinline__ v8s ldfrag_w(const u16* wlds, int gate, int kt){
  int lane = threadIdx.x & 63;
  int rr = lane & 15;
  int ch = (kt*4 + (lane >> 4)) ^ (rr & 7);
  return *(const v8s*)(wlds + (size_t)((gate*16 + rr)*64 + ch) * 8);
}
__device__ void stage_wslice(const float* Wf, u16* wlds, int col0){
  for (int idx = threadIdx.x; idx < 3*16*64; idx += TPB){
    int ch = idx & 63, rr = (idx >> 6) & 15, g = idx >> 10;
    const float* src = Wf + ((size_t)(g*512 + col0 + rr))*512 + ch*8;
    v4f f0 = *(const v4f*)src, f1 = *(const v4f*)(src + 4);
    v8s o;
    #pragma unroll
    for (int j=0;j<4;j++){ o[j] = (short)f2bf(f0[j]); o[4+j] = (short)f2bf(f1[j]); }
    *(v8s*)(wlds + (size_t)((g*16 + rr)*64 + (ch ^ (rr & 7))) * 8) = o;
  }
}

struct KArgs {
  // inputs (f32)
  const float *x, *target, *eWih_f, *eWhh_f, *ebih, *ebhh;
  const float *dWih0_f, *dWih1_f, *dWhh_f, *dbih, *dbhh;
  const float *aWw_f, *aWb, *aCw_f, *aCb, *o1w_f, *o1b, *o2w_f, *o2b;
  float* out;
  // barrier page
  u32 *flags, *genp, *larr, *lflags, *ecnt, *enldr;
  // bf16 weights / activations in ws
  u16 *xhi, *h0hi, *h1hi, *encout;
  u16 *dWih0h,*dWih0l,*dWih1h,*dWih1l,*dWhhh,*dWhhl;
  u16 *Wwhh,*Wwhl,*Wwxh,*Wwxl,*Wchh,*Wchl,*Wcxh,*Wcxl;
  u16 *o2wh,*o2wl,*o1Th,*o1Tl,*Wph,*Wpl;
  float *bpr;
  u16 *xth,*xtl;
  float *preW,*preC;
  u16 *dh0h,*dh0l,*dh1h,*dh1l;
  float *logits;
  u16 *wcth,*wctl,*xch,*xcl;
};

// ---- full barrier (round-9 proven): every WG releases + acquires ----------
__device__ void gbar_full(u32* flags, u32* genp, u32 btf, u32 bt){
  __syncthreads();
  int wg = blockIdx.x, tid = threadIdx.x;
  if (wg == 0){
    if (tid > 0 && tid < NWG){
      while (__hip_atomic_fetch_add(&flags[tid], 0u, __ATOMIC_RELAXED, __HIP_MEMORY_SCOPE_AGENT) < btf)
        __builtin_amdgcn_s_sleep(2);
    }
    __syncthreads();
    if (tid == 0)
      __hip_atomic_fetch_add(genp, 1u, __ATOMIC_RELEASE, __HIP_MEMORY_SCOPE_AGENT);
  } else {
    if (tid == 0){
      __hip_atomic_fetch_add(&flags[wg], 1u, __ATOMIC_RELEASE, __HIP_MEMORY_SCOPE_AGENT);
      while (__hip_atomic_fetch_add(genp, 0u, __ATOMIC_RELAXED, __HIP_MEMORY_SCOPE_AGENT) < bt)
        __builtin_amdgcn_s_sleep(2);
    }
  }
  __builtin_amdgcn_fence(__ATOMIC_ACQUIRE, "agent");
  __syncthreads();
}

// ---- leader barrier: one RELEASE (wbl2) per XCD; acquire fence everywhere --
__device__ void gbar2(u32* larr, u32* lflags, u32* genp,
                      int myxcd, int isldr, int lidx, int nloc, int nldr,
                      u32 bt2, u32 bt){
  __syncthreads();
  const int wg = blockIdx.x, tid = threadIdx.x;
  if (tid == 0){
    asm volatile("s_waitcnt vmcnt(0)" ::: "memory");   // my stores at XCD L2
    __hip_atomic_fetch_add(&larr[myxcd], 1u, __ATOMIC_RELAXED, __HIP_MEMORY_SCOPE_AGENT);
    if (isldr){
      while (__hip_atomic_fetch_add(&larr[myxcd], 0u, __ATOMIC_RELAXED, __HIP_MEMORY_SCOPE_AGENT) < (u32)nloc * bt2)
        __builtin_amdgcn_s_sleep(1);
      // single XCD-wide writeback: flushes all local WGs' dirty L2 lines
      __hip_atomic_fetch_add(&lflags[lidx], 1u, __ATOMIC_RELEASE, __HIP_MEMORY_SCOPE_AGENT);
    }
  }
  if (wg == 0){
    if (tid >= 2 && tid < 2 + nldr){
      while (__hip_atomic_fetch_add(&lflags[tid-2], 0u, __ATOMIC_RELAXED, __HIP_MEMORY_SCOPE_AGENT) < bt2)
        __builtin_amdgcn_s_sleep(1);
    }
    __syncthreads();
    if (tid == 0)
      __hip_atomic_fetch_add(genp, 1u, __ATOMIC_RELAXED, __HIP_MEMORY_SCOPE_AGENT);
  }
  if (tid == 0){
    while (__hip_atomic_fetch_add(genp, 0u, __ATOMIC_RELAXED, __HIP_MEMORY_SCOPE_AGENT) < bt)
      __builtin_amdgcn_s_sleep(1);
  }
  __builtin_amdgcn_fence(__ATOMIC_ACQUIRE, "agent");
  __syncthreads();
}

// ---- generic 64x16 tile of  C = A @ B^T  (split-bf16 3-pass) --------------
__device__ __forceinline__ v4f tile_xwT(const u16* Ah, const u16* Al, size_t lda, int nks,
                                        const u16* Bh, const u16* Bl, size_t ldb,
                                        int row0, int brow0, v4f* red){
  int tid = threadIdx.x, w = tid >> 6, lane = tid & 63;
  v4f acc[4];
  #pragma unroll
  for (int i=0;i<4;i++) acc[i] = (v4f){0.f,0.f,0.f,0.f};
  for (int ks = w; ks < nks; ks += 4){
    int k0 = ks * 32;
    v8s bh = ldfrag(Bh, ldb, brow0, k0);
    v8s bl = ldfrag(Bl, ldb, brow0, k0);
    #pragma unroll
    for (int rt=0; rt<4; rt++){
      v8s a  = ldfrag(Ah, lda, row0 + rt*16, k0);
      v8s al = ldfrag(Al, lda, row0 + rt*16, k0);
      acc[rt] = MFMA_(a,  bh, acc[rt]);
      acc[rt] = MFMA_(al, bh, acc[rt]);
      acc[rt] = MFMA_(a,  bl, acc[rt]);
    }
  }
  __syncthreads();
  red[(0*4+w)*64+lane]=acc[0]; red[(1*4+w)*64+lane]=acc[1];
  red[(2*4+w)*64+lane]=acc[2]; red[(3*4+w)*64+lane]=acc[3];
  __syncthreads();
  v4f g = red[(w*4+0)*64+lane];
  g += red[(w*4+1)*64+lane]; g += red[(w*4+2)*64+lane]; g += red[(w*4+3)*64+lane];
  return g;
}

// ---- decoder GRU gate tile: acc types {0:r, 1:z, 2:n_i, 3:n_h} ------------
template<bool PAIR>
__device__ __forceinline__ void gru_tile(const u16* Axh, const u16* Axl, size_t ldx, int nkx,
                                         const u16* Ahh, const u16* Ahl, size_t ldh, int nkh,
                                         const u16* Wi,  const u16* Wil, size_t ldwi,
                                         const u16* Wh,  const u16* Whl, size_t ldwh,
                                         int row0, int col0, v4f* red, v4f* gate){
  int tid = threadIdx.x, w = tid >> 6, lane = tid & 63;
  v4f acc[4][4];
  #pragma unroll
  for (int i=0;i<4;i++){
    #pragma unroll
    for (int j=0;j<4;j++) acc[i][j] = (v4f){0.f,0.f,0.f,0.f};
  }
  for (int ks = w; ks < nkx; ks += 4){
    int k0 = ks * 32;
    v8s br = ldfrag(Wi, ldwi,        col0, k0);
    v8s bz = ldfrag(Wi, ldwi,  512 + col0, k0);
    v8s bn = ldfrag(Wi, ldwi, 1024 + col0, k0);
    v8s brl, bzl, bnl;
    if (PAIR){ brl = ldfrag(Wil, ldwi, col0, k0); bzl = ldfrag(Wil, ldwi, 512+col0, k0); bnl = ldfrag(Wil, ldwi, 1024+col0, k0); }
    #pragma unroll
    for (int rt=0; rt<4; rt++){
      v8s a = ldfrag(Axh, ldx, row0 + rt*16, k0);
      acc[rt][0] = MFMA_(a, br, acc[rt][0]);
      acc[rt][1] = MFMA_(a, bz, acc[rt][1]);
      acc[rt][2] = MFMA_(a, bn, acc[rt][2]);
      if (PAIR){
        v8s al = ldfrag(Axl, ldx, row0 + rt*16, k0);
        acc[rt][0] = MFMA_(al, br, acc[rt][0]); acc[rt][0] = MFMA_(a, brl, acc[rt][0]);
        acc[rt][1] = MFMA_(al, bz, acc[rt][1]); acc[rt][1] = MFMA_(a, bzl, acc[rt][1]);
        acc[rt][2] = MFMA_(al, bn, acc[rt][2]); acc[rt][2] = MFMA_(a, bnl, acc[rt][2]);
      }
    }
  }
  for (int ks = w; ks < nkh; ks += 4){
    int k0 = ks * 32;
    v8s br = ldfrag(Wh, ldwh,        col0, k0);
    v8s bz = ldfrag(Wh, ldwh,  512 + col0, k0);
    v8s bn = ldfrag(Wh, ldwh, 1024 + col0, k0);
    v8s brl, bzl, bnl;
    if (PAIR){ brl = ldfrag(Whl, ldwh, col0, k0); bzl = ldfrag(Whl, ldwh, 512+col0, k0); bnl = ldfrag(Whl, ldwh, 1024+col0, k0); }
    #pragma unroll
    for (int rt=0; rt<4; rt++){
      v8s a = ldfrag(Ahh, ldh, row0 + rt*16, k0);
      acc[rt][0] = MFMA_(a, br, acc[rt][0]);
      acc[rt][1] = MFMA_(a, bz, acc[rt][1]);
      acc[rt][3] = MFMA_(a, bn, acc[rt][3]);
      if (PAIR){
        v8s al = ldfrag(Ahl, ldh, row0 + rt*16, k0);
        acc[rt][0] = MFMA_(al, br, acc[rt][0]); acc[rt][0] = MFMA_(a, brl, acc[rt][0]);
        acc[rt][1] = MFMA_(al, bz, acc[rt][1]); acc[rt][1] = MFMA_(a, bzl, acc[rt][1]);
        acc[rt][3] = MFMA_(al, bn, acc[rt][3]); acc[rt][3] = MFMA_(a, bnl, acc[rt][3]);
      }
    }
  }
  #pragma unroll
  for (int ty=0; ty<4; ty++){
    __syncthreads();
    red[(0*4+w)*64+lane]=acc[0][ty]; red[(1*4+w)*64+lane]=acc[1][ty];
    red[(2*4+w)*64+lane]=acc[2][ty]; red[(3*4+w)*64+lane]=acc[3][ty];
    __syncthreads();
    v4f g = red[(w*4+0)*64+lane];
    g += red[(w*4+1)*64+lane]; g += red[(w*4+2)*64+lane]; g += red[(w*4+3)*64+lane];
    gate[ty] = g;
  }
}

__device__ __forceinline__ void gru_combine(const v4f* gate, const float* bih, const float* bhh,
                                            const u16* Hph, const u16* Hpl,
                                            u16* Hnh, u16* Hnl,
                                            int row0, int col0){
  int tid = threadIdx.x, w = tid >> 6, lane = tid & 63;
  int col  = col0 + (lane & 15);
  int rowb = row0 + w*16 + ((lane >> 4) << 2);
  float bir = bih[col], biz = bih[512+col], bin = bih[1024+col];
  float bhr = bhh[col], bhz = bhh[512+col], bhn = bhh[1024+col];
  #pragma unroll
  for (int e=0; e<4; e++){
    int row = rowb + e;
    float r = sigm(gate[0][e] + bir + bhr);
    float z = sigm(gate[1][e] + biz + bhz);
    float n = tanh_f(gate[2][e] + bin + r * (gate[3][e] + bhn));
    float hp = bf2f(Hph[(size_t)row*512 + col]) + bf2f(Hpl[(size_t)row*512 + col]);
    float hv = (1.f - z) * n + z * hp;
    splitstore(&Hnh[(size_t)row*512+col], &Hnl[(size_t)row*512+col], hv);
  }
}

// ---- pipelined encoder step: waves own 2 row-tiles x full K; no reduce -----
__device__ void enc_step2(const u16* Xb, size_t ldX, const u16* Hp, u16* Hn,
                          u16* encw, int t, const u16* wI, const u16* wH,
                          const float* bih, const float* bhh, int col0){
  const int tid = threadIdx.x, w = tid>>6, lane = tid&63;
  v4f aR[2], aZ[2], aNI[2], aNH[2];
  #pragma unroll
  for (int j=0;j<2;j++){ aR[j]=(v4f){0,0,0,0}; aZ[j]=(v4f){0,0,0,0}; aNI[j]=(v4f){0,0,0,0}; aNH[j]=(v4f){0,0,0,0}; }
  for (int kt=0; kt<16; ++kt){
    int k0 = kt*32;
    v8s bi0=ldfrag_w(wI,0,kt), bi1=ldfrag_w(wI,1,kt), bi2=ldfrag_w(wI,2,kt);
    v8s bh0=ldfrag_w(wH,0,kt), bh1=ldfrag_w(wH,1,kt), bh2=ldfrag_w(wH,2,kt);
    #pragma unroll
    for (int j=0;j<2;j++){
      int r0 = (w*2+j)*16;
      v8s ax = ldfrag(Xb, ldX, r0, k0);
      v8s ah = ldfrag(Hp, 512, r0, k0);
      aR[j]=MFMA_(ax,bi0,aR[j]); aZ[j]=MFMA_(ax,bi1,aZ[j]); aNI[j]=MFMA_(ax,bi2,aNI[j]);
      aR[j]=MFMA_(ah,bh0,aR[j]); aZ[j]=MFMA_(ah,bh1,aZ[j]); aNH[j]=MFMA_(ah,bh2,aNH[j]);
    }
  }
  int col = col0 + (lane&15);
  float bir=bih[col], biz=bih[512+col], bin=bih[1024+col];
  float bhr=bhh[col], bhz=bhh[512+col], bhn=bhh[1024+col];
  #pragma unroll
  for (int j=0;j<2;j++){
    int rowb = (w*2+j)*16 + ((lane>>4)<<2);
    #pragma unroll
    for (int e=0;e<4;e++){
      int row = rowb + e;
      float r = sigm(aR[j][e] + bir + bhr);
      float z = sigm(aZ[j][e] + biz + bhz);
      float n = tanh_f(aNI[j][e] + bin + r*(aNH[j][e] + bhn));
      float hp = bf2f(Hp[(size_t)row*512 + col]);
      float hv = (1.f-z)*n + z*hp;
      u16 h16 = f2bf(hv);
      Hn[(size_t)row*512 + col] = h16;
      if (encw) encw[((size_t)row*256 + t)*512 + col] = h16;
    }
  }
}

__device__ __forceinline__ float blk_max(float v, float* sred){
  #pragma unroll
  for (int off=32; off>0; off>>=1) v = fmaxf(v, __shfl_xor(v, off, 64));
  __syncthreads();
  if ((threadIdx.x & 63) == 0) sred[threadIdx.x >> 6] = v;
  __syncthreads();
  return fmaxf(fmaxf(sred[0], sred[1]), fmaxf(sred[2], sred[3]));
}
__device__ __forceinline__ float blk_sum(float v, float* sred){
  #pragma unroll
  for (int off=32; off>0; off>>=1) v += __shfl_xor(v, off, 64);
  __syncthreads();
  if ((threadIdx.x & 63) == 0) sred[threadIdx.x >> 6] = v;
  __syncthreads();
  return sred[0] + sred[1] + sred[2] + sred[3];
}

#define DECOUT_OFF 0
#define DECHID_OFF 1228800      // 128*32*300
#define ATTN_OFF   1359872      // + 2*128*512

__global__ void __launch_bounds__(TPB, 1) traffic_kernel(KArgs A){
  __shared__ union {
    struct { u16 wI[3*16*64*8]; u16 wH[3*16*64*8]; } enc;   // 48KB + 48KB
    struct { float awl[2][256]; } dec;
  } U;
  __shared__ v4f red[4*4*64];   // 16KB reduce scratch
  __shared__ float sred[4];
  __shared__ int sh_xcd, sh_slot, sh_lidx, sh_nloc, sh_nldr;
  const int tid = threadIdx.x;
  const int wg  = blockIdx.x;
  const size_t gtid = (size_t)wg * TPB + tid;
  const size_t P = (size_t)NWG * TPB;
  u32 bt = 0, bt2 = 0, btf = 0;

  // ================= Election: XCD id + leader slot ========================
  {
    u32 xcd;
    asm volatile("s_getreg_b32 %0, hwreg(HW_REG_XCC_ID)" : "=s"(xcd));
    if (tid == 0){
      int x = (int)(xcd & 63);
      sh_xcd = x;
      u32 slot = __hip_atomic_fetch_add(&A.ecnt[x], 1u, __ATOMIC_RELAXED, __HIP_MEMORY_SCOPE_AGENT);
      sh_slot = (int)slot;
      sh_lidx = (slot == 0u) ? (int)__hip_atomic_fetch_add(A.enldr, 1u, __ATOMIC_RELAXED, __HIP_MEMORY_SCOPE_AGENT) : -1;
    }
    __syncthreads();
  }

  // ================= Phase 0: conversion / padding / zeroing ===============
  for (size_t i=gtid; i<128UL*256*512; i+=P) A.xhi[i] = f2bf(A.x[i]);
  for (size_t i=gtid; i<1536UL*320; i+=P){
    size_t r=i/320, c=i%320;
    float v = (c<300)? A.dWih0_f[r*300+c] : 0.f;
    splitstore(&A.dWih0h[i], &A.dWih0l[i], v);
  }
  for (size_t i=gtid; i<1536UL*512; i+=P) splitstore(&A.dWih1h[i], &A.dWih1l[i], A.dWih1_f[i]);
  for (size_t i=gtid; i<2UL*1536*512; i+=P) splitstore(&A.dWhhh[i], &A.dWhhl[i], A.dWhh_f[i]);
  for (size_t i=gtid; i<256UL*512; i+=P){ size_t r=i>>9, c=i&511; splitstore(&A.Wwhh[i], &A.Wwhl[i], A.aWw_f[r*812+300+c]); }
  for (size_t i=gtid; i<256UL*320; i+=P){ size_t r=i/320, c=i%320; float v=(c<300)? A.aWw_f[r*812+c]:0.f; splitstore(&A.Wwxh[i], &A.Wwxl[i], v); }
  for (size_t i=gtid; i<304UL*512; i+=P){ size_t r=i>>9, c=i&511; float v=(r<300)? A.aCw_f[r*812+300+c]:0.f; splitstore(&A.Wchh[i], &A.Wchl[i], v); }
  for (size_t i=gtid; i<304UL*320; i+=P){ size_t r=i/320, c=i%320; float v=(r<300&&c<300)? A.aCw_f[r*812+c]:0.f; splitstore(&A.Wcxh[i], &A.Wcxl[i], v); }
  // o2w padded to 320x320 (split)
  for (size_t i=gtid; i<320UL*320; i+=P){ size_t r=i/320, c=i%320; float v=(r<300&&c<300)? A.o2w_f[r*300+c]:0.f; splitstore(&A.o2wh[i], &A.o2wl[i], v); }
  // o1w^T (512x320, split) for the W' GEMM
  for (size_t i=gtid; i<512UL*320; i+=P){
    size_t j=i/320, k=i%320;
    float v = (k<300)? A.o1w_f[k*512+j] : 0.f;
    splitstore(&A.o1Th[i], &A.o1Tl[i], v);
  }
  // b' = o2w@o1b + o2b
  for (size_t i=gtid; i<304; i+=P){
    float s = 0.f;
    if (i < 300){
      s = A.o2b[i];
      const float* wrow = A.o2w_f + i*300;
      for (int k=0;k<300;k++) s += wrow[k] * A.o1b[k];
    }
    A.bpr[i] = s;
  }
  for (size_t i=gtid; i<32UL*128*320; i+=P){
    size_t sb=i/320, c=i%320, s2=sb>>7, b=sb&127;
    float v = (c<300)? A.target[(b*33+s2)*300 + c] : 0.f;
    splitstore(&A.xth[i], &A.xtl[i], v);
  }
  for (size_t i=gtid; i<65536; i+=P){ A.h0hi[i]=0; A.h1hi[i]=0; }
  for (size_t i=gtid; i<128UL*320; i+=P){ A.xch[i]=0; A.xcl[i]=0; }
  ++bt; ++btf; gbar_full(A.flags, A.genp, btf, bt);

  // broadcast final election counts (stable now)
  if (tid == 0){
    sh_nloc = (int)__hip_atomic_fetch_add(&A.ecnt[sh_xcd], 0u, __ATOMIC_RELAXED, __HIP_MEMORY_SCOPE_AGENT);
    sh_nldr = (int)__hip_atomic_fetch_add(A.enldr, 0u, __ATOMIC_RELAXED, __HIP_MEMORY_SCOPE_AGENT);
  }
  __syncthreads();
  const int myxcd = sh_xcd, isldr = (sh_slot == 0), lidx = sh_lidx;
  const int nloc = sh_nloc, nldr = sh_nldr;

  // ================= Phase 0b: xt-side attn linears + W' ===================
  for (int tl = wg; tl < 1024; tl += NWG){        // preW: (32*128) x 256
    int rb = tl >> 4, cb = tl & 15;
    int row0 = rb*64, col0 = cb*16;
    v4f g = tile_xwT(A.xth, A.xtl, 320, 10, A.Wwxh, A.Wwxl, 320, row0, col0, red);
    int w = tid>>6, lane = tid&63;
    int col = col0 + (lane&15), rowb = row0 + w*16 + ((lane>>4)<<2);
    #pragma unroll
    for (int e=0;e<4;e++){ int row=rowb+e; A.preW[(size_t)row*256+col] = g[e] + A.aWb[col]; }
  }
  for (int tl = wg; tl < 1216; tl += NWG){        // preC: (32*128) x 304
    int rb = tl / 19, cb = tl % 19;
    int row0 = rb*64, col0 = cb*16;
    v4f g = tile_xwT(A.xth, A.xtl, 320, 10, A.Wcxh, A.Wcxl, 320, row0, col0, red);
    int w = tid>>6, lane = tid&63;
    int col = col0 + (lane&15), rowb = row0 + w*16 + ((lane>>4)<<2);
    #pragma unroll
    for (int e=0;e<4;e++){
      int row=rowb+e;
      float v = (col<300)? (g[e] + A.aCb[col]) : 0.f;
      A.preC[(size_t)row*320+col] = v;
    }
  }
  for (int tl = wg; tl < 160; tl += NWG){         // W' = o2w @ o1w  (320pad x 512)
    int rt = tl >> 5, ct = tl & 31;
    int row0 = rt*64, col0 = ct*16;
    v4f g = tile_xwT(A.o2wh, A.o2wl, 320, 10, A.o1Th, A.o1Tl, 320, row0, col0, red);
    int w = tid>>6, lane = tid&63;
    int col = col0 + (lane&15), rowb = row0 + w*16 + ((lane>>4)<<2);
    #pragma unroll
    for (int e=0;e<4;e++){
      int row = rowb+e;
      if (row < 304) splitstore(&A.Wph[(size_t)row*512+col], &A.Wpl[(size_t)row*512+col], g[e]);
    }
  }
  ++bt; ++btf; gbar_full(A.flags, A.genp, btf, bt);

  // ================= Encoder: 2 layers PIPELINED, 257 barriers =============
  {
    const int grp  = wg >> 5;            // 0: layer0 (WGs 0-31), 1: layer1
    const int col0 = (wg & 31) * 16;
    stage_wslice(A.eWih_f + (size_t)grp*1536*512, U.enc.wI, col0);
    stage_wslice(A.eWhh_f + (size_t)grp*1536*512, U.enc.wH, col0);
    __syncthreads();
    const float* bih = A.ebih + grp*1536;
    const float* bhh = A.ebhh + grp*1536;
    for (int k=0; k<=256; ++k){
      if (grp == 0){
        if (k < 256)
          enc_step2(A.xhi + (size_t)k*512, (size_t)256*512,
                    A.h0hi + (size_t)k*65536, A.h0hi + (size_t)(k+1)*65536,
                    nullptr, 0, U.enc.wI, U.enc.wH, bih, bhh, col0);
      } else {
        if (k >= 1){
          int t = k-1;
          enc_step2(A.h0hi + (size_t)k*65536, 512,
                    A.h1hi + (size_t)(t&1)*65536, A.h1hi + (size_t)((t+1)&1)*65536,
                    A.encout, t, U.enc.wI, U.enc.wH, bih, bhh, col0);
        }
      }
      ++bt; ++bt2;
      gbar2(A.larr, A.lflags, A.genp, myxcd, isldr, lidx, nloc, nldr, bt2, bt);
    }
  }

  // ================= Decoder init: h = enc_hidden ==========================
  for (size_t i=gtid; i<65536; i+=P){
    A.dh0h[i] = A.h0hi[(size_t)256*65536 + i]; A.dh0l[i] = 0;
    A.dh1h[i] = A.h1hi[i];                     A.dh1l[i] = 0;   // layer1 final in buf 0
  }
  ++bt; ++bt2;
  gbar2(A.larr, A.lflags, A.genp, myxcd, isldr, lidx, nloc, nldr, bt2, bt);

  // ================= Decoder: 32 steps, 5 barriers/step ====================
  for (int s=0; s<32; s++){
    const u16* h0ph = A.dh0h + (size_t)(s&1)*65536;
    const u16* h0pl = A.dh0l + (size_t)(s&1)*65536;
    u16* h0nh = A.dh0h + (size_t)((s+1)&1)*65536;
    u16* h0nl = A.dh0l + (size_t)((s+1)&1)*65536;
    const u16* h1ph = A.dh1h + (size_t)(s&1)*65536;
    const u16* h1pl = A.dh1l + (size_t)(s&1)*65536;
    u16* h1nh = A.dh1h + (size_t)((s+1)&1)*65536;
    u16* h1nl = A.dh1l + (size_t)((s+1)&1)*65536;

    // S1: logits = preW[s] + h1 @ Wwh^T      (128 x 256)
    if (wg < 32){
      int rb = wg >> 4, cb = wg & 15;
      int row0 = rb*64, col0 = cb*16;
      v4f g = tile_xwT(h1ph, h1pl, 512, 16, A.Wwhh, A.Wwhl, 512, row0, col0, red);
      const float* pre = A.preW + (size_t)s*128*256;
      int w = tid>>6, lane = tid&63;
      int col = col0 + (lane&15), rowb = row0 + w*16 + ((lane>>4)<<2);
      #pragma unroll
      for (int e=0;e<4;e++){ int row=rowb+e; A.logits[(size_t)row*256+col] = g[e] + pre[(size_t)row*256+col]; }
    }
    ++bt; ++bt2;
    gbar2(A.larr, A.lflags, A.genp, myxcd, isldr, lidx, nloc, nldr, bt2, bt);

    // S2+S3 fused: softmax (aw in LDS) + weighted context
    {
      int b0 = wg*2, b1 = b0+1;
      #pragma unroll
      for (int bi=0; bi<2; bi++){
        int b = wg*2 + bi;
        float v = A.logits[(size_t)b*256 + tid];
        float m = blk_max(v, sred);
        float e = __expf(v - m);
        float ssum = blk_sum(e, sred);
        float awv = e / ssum;
        U.dec.awl[bi][tid] = awv;
        A.out[ATTN_OFF + ((size_t)b*32 + s)*256 + tid] = awv;
      }
      __syncthreads();
      float a00=0.f,a01=0.f,a10=0.f,a11=0.f;
      const u16* e0 = A.encout + (size_t)b0*256*512;
      const u16* e1 = A.encout + (size_t)b1*256*512;
      for (int t2=0; t2<256; t2++){
        float w0 = U.dec.awl[0][t2], w1 = U.dec.awl[1][t2];
        a00 += w0 * bf2f(e0[(size_t)t2*512 + tid]);
        a01 += w0 * bf2f(e0[(size_t)t2*512 + 256 + tid]);
        a10 += w1 * bf2f(e1[(size_t)t2*512 + tid]);
        a11 += w1 * bf2f(e1[(size_t)t2*512 + 256 + tid]);
      }
      splitstore(&A.wcth[(size_t)b0*512+tid],     &A.wctl[(size_t)b0*512+tid],     a00);
      splitstore(&A.wcth[(size_t)b0*512+256+tid], &A.wctl[(size_t)b0*512+256+tid], a01);
      splitstore(&A.wcth[(size_t)b1*512+tid],     &A.wctl[(size_t)b1*512+tid],     a10);
      splitstore(&A.wcth[(size_t)b1*512+256+tid], &A.wctl[(size_t)b1*512+256+tid], a11);
    }
    ++bt; ++bt2;
    gbar2(A.larr, A.lflags, A.genp, myxcd, isldr, lidx, nloc, nldr, bt2, bt);

    // S4: xc = relu(preC[s] + wctx @ Wch^T)   (128 x 304, pads stay 0)
    if (wg < 38){
      int rb = wg / 19, cb = wg % 19;
      int row0 = rb*64, col0 = cb*16;
      v4f g = tile_xwT(A.wcth, A.wctl, 512, 16, A.Wchh, A.Wchl, 512, row0, col0, red);
      const float* pre = A.preC + (size_t)s*128*320;
      int w = tid>>6, lane = tid&63;
      int col = col0 + (lane&15), rowb = row0 + w*16 + ((lane>>4)<<2);
      #pragma unroll
      for (int e=0;e<4;e++){
        int row = rowb+e;
        float v = (col<300)? fmaxf(g[e] + pre[(size_t)row*320+col], 0.f) : 0.f;
        splitstore(&A.xch[(size_t)row*320+col], &A.xcl[(size_t)row*320+col], v);
      }
    }
    ++bt; ++bt2;
    gbar2(A.larr, A.lflags, A.genp, myxcd, isldr, lidx, nloc, nldr, bt2, bt);

    // S5: GRU layer 0: h0' = gru(xc, h0)
    {
      int rb = wg >> 5, cb = wg & 31;
      int row0 = rb*64, col0 = cb*16;
      v4f gate[4];
      gru_tile<true>(A.xch, A.xcl, 320, 10, h0ph, h0pl, 512, 16,
                     A.dWih0h, A.dWih0l, 320, A.dWhhh, A.dWhhl, 512, row0, col0, red, gate);
      gru_combine(gate, A.dbih, A.dbhh, h0ph, h0pl, h0nh, h0nl, row0, col0);
    }
    ++bt; ++bt2;
    gbar2(A.larr, A.lflags, A.genp, myxcd, isldr, lidx, nloc, nldr, bt2, bt);

    // S6: GRU layer 1: h1' = gru(h0', h1)
    {
      int rb = wg >> 5, cb = wg & 31;
      int row0 = rb*64, col0 = cb*16;
      v4f gate[4];
      gru_tile<true>(h0nh, h0nl, 512, 16, h1ph, h1pl, 512, 16,
                     A.dWih1h, A.dWih1l, 512,
                     A.dWhhh + (size_t)1536*512, A.dWhhl + (size_t)1536*512, 512,
                     row0, col0, red, gate);
      gru_combine(gate, A.dbih + 1536, A.dbhh + 1536, h1ph, h1pl, h1nh, h1nl, row0, col0);
    }
    ++bt; ++bt2;
    gbar2(A.larr, A.lflags, A.genp, myxcd, isldr, lidx, nloc, nldr, bt2, bt);

    // S8': dec_out[:,s,:] = h1' @ W'^T + b'   (fused S7+S8; no trailing bar)
    if (wg < 38){
      int rb = wg / 19, cb = wg % 19;
      int row0 = rb*64, col0 = cb*16;
      v4f g = tile_xwT(h1nh, h1nl, 512, 16, A.Wph, A.Wpl, 512, row0, col0, red);
      int w = tid>>6, lane = tid&63;
      int col = col0 + (lane&15), rowb = row0 + w*16 + ((lane>>4)<<2);
      #pragma unroll
      for (int e=0;e<4;e++){
        int row = rowb+e;
        if (col < 300) A.out[DECOUT_OFF + ((size_t)row*32 + s)*300 + col] = g[e] + A.bpr[col];
      }
    }
  }

  // ================= dec_hidden output (final h in buffer 0) ===============
  for (size_t i=gtid; i<65536; i+=P){
    A.out[DECHID_OFF + i]         = bf2f(A.dh0h[i]) + bf2f(A.dh0l[i]);
    A.out[DECHID_OFF + 65536 + i] = bf2f(A.dh1h[i]) + bf2f(A.dh1l[i]);
  }
}

// ===========================================================================
extern "C" void kernel_launch(void* const* d_in, const int* in_sizes, int n_in,
                              void* d_out, int out_size, void* d_ws, size_t ws_size,
                              hipStream_t stream){
  (void)in_sizes; (void)n_in; (void)out_size; (void)ws_size;
  KArgs A;
  A.x       = (const float*)d_in[0];  A.target = (const float*)d_in[1];
  A.eWih_f  = (const float*)d_in[2];  A.eWhh_f = (const float*)d_in[3];
  A.ebih    = (const float*)d_in[4];  A.ebhh   = (const float*)d_in[5];
  A.dWih0_f = (const float*)d_in[6];  A.dWih1_f= (const float*)d_in[7];
  A.dWhh_f  = (const float*)d_in[8];  A.dbih   = (const float*)d_in[9];
  A.dbhh    = (const float*)d_in[10];
  A.aWw_f   = (const float*)d_in[11]; A.aWb    = (const float*)d_in[12];
  A.aCw_f   = (const float*)d_in[13]; A.aCb    = (const float*)d_in[14];
  A.o1w_f   = (const float*)d_in[15]; A.o1b    = (const float*)d_in[16];
  A.o2w_f   = (const float*)d_in[17]; A.o2b    = (const float*)d_in[18];
  A.out = (float*)d_out;

  char* w = (char*)d_ws;
  size_t off = 0;
  auto alloc = [&](size_t bytes)->char*{
    char* p = w + off; off += (bytes + 255) & ~(size_t)255; return p;
  };
  char* barp = alloc(4096);
  A.flags  = (u32*)barp;               // [0..255]
  A.genp   = (u32*)(barp + 2048);
  A.larr   = (u32*)(barp + 2304);      // 64 u32
  A.lflags = (u32*)(barp + 2560);      // 64 u32
  A.ecnt   = (u32*)(barp + 2816);      // 64 u32
  A.enldr  = (u32*)(barp + 3072);
  A.xhi    = (u16*)alloc(128UL*256*512*2);
  A.h0hi   = (u16*)alloc(257UL*128*512*2);
  A.h1hi   = (u16*)alloc(2UL*128*512*2);
  A.encout = A.xhi;   // alias: layer0 reads xhi[t=k] while layer1 writes
                      // encout[t=k-1] -- trailing by one t-slice, disjoint
  A.dWih0h = (u16*)alloc(1536UL*320*2); A.dWih0l = (u16*)alloc(1536UL*320*2);
  A.dWih1h = (u16*)alloc(1536UL*512*2); A.dWih1l = (u16*)alloc(1536UL*512*2);
  A.dWhhh  = (u16*)alloc(2UL*1536*512*2); A.dWhhl = (u16*)alloc(2UL*1536*512*2);
  A.Wwhh   = (u16*)alloc(256UL*512*2);  A.Wwhl   = (u16*)alloc(256UL*512*2);
  A.Wwxh   = (u16*)alloc(256UL*320*2);  A.Wwxl   = (u16*)alloc(256UL*320*2);
  A.Wchh   = (u16*)alloc(304UL*512*2);  A.Wchl   = (u16*)alloc(304UL*512*2);
  A.Wcxh   = (u16*)alloc(304UL*320*2);  A.Wcxl   = (u16*)alloc(304UL*320*2);
  A.o2wh   = (u16*)alloc(320UL*320*2);  A.o2wl   = (u16*)alloc(320UL*320*2);
  A.o1Th   = (u16*)alloc(512UL*320*2);  A.o1Tl   = (u16*)alloc(512UL*320*2);
  A.Wph    = (u16*)alloc(304UL*512*2);  A.Wpl    = (u16*)alloc(304UL*512*2);
  A.bpr    = (float*)alloc(304UL*4);
  A.xth    = (u16*)alloc(32UL*128*320*2); A.xtl  = (u16*)alloc(32UL*128*320*2);
  A.preW   = (float*)alloc(32UL*128*256*4);
  A.preC   = (float*)alloc(32UL*128*320*4);
  A.dh0h   = (u16*)alloc(2UL*65536*2); A.dh0l = (u16*)alloc(2UL*65536*2);
  A.dh1h   = (u16*)alloc(2UL*65536*2); A.dh1l = (u16*)alloc(2UL*65536*2);
  A.logits = (float*)alloc(128UL*256*4);
  A.wcth   = (u16*)alloc(128UL*512*2); A.wctl = (u16*)alloc(128UL*512*2);
  A.xch    = (u16*)alloc(128UL*320*2); A.xcl  = (u16*)alloc(128UL*320*2);

  hipMemsetAsync(d_ws, 0, 4096, stream);   // reset barrier/election page each launch
  traffic_kernel<<<dim3(NWG), dim3(TPB), 0, stream>>>(A);
}

// Round 11
// 10395.940 us; speedup vs baseline: 6.8582x; 1.1015x over previous
//
#include <hip/hip_runtime.h>
#include <hip/hip_bf16.h>
#include <math.h>

// ---------------------------------------------------------------------------
// TrafficSeq2Seq round 11 = round-10 (proven, 11.45ms) with:
//  1. barrier polls via sc0/sc1 CP-bypass LOADS (no RMW serialization);
//     arrival stays a RELEASE RMW (single wb), exit keeps agent ACQUIRE fence
//  2. encoder on 128 WGs: 2 layers x 32 col-groups x 2 batch-halves --
//     per-WG global reads halve (64 rows), 2x CUs, bit-identical math
//  3. leader-election removed (measured ~0); S7+S8 W' fusion kept (proven)
// ---------------------------------------------------------------------------

#define NWG 128
#define TPB 256

typedef unsigned short u16;
typedef unsigned int   u32;
typedef short v8s __attribute__((ext_vector_type(8)));
typedef float v4f __attribute__((ext_vector_type(4)));

#define MFMA_(a,b,c) __builtin_amdgcn_mfma_f32_16x16x32_bf16((a),(b),(c),0,0,0)

__device__ __forceinline__ u16 f2bf(float f){
  unsigned u = __builtin_bit_cast(unsigned, f);
  unsigned r = u + 0x7FFFu + ((u >> 16) & 1u);
  return (u16)(r >> 16);
}
__device__ __forceinline__ float bf2f(u16 s){
  unsigned u = ((unsigned)s) << 16;
  return __builtin_bit_cast(float, u);
}
__device__ __forceinline__ void splitstore(u16* ph, u16* pl, float v){
  u16 h = f2bf(v); ph[0] = h; pl[0] = f2bf(v - bf2f(h));
}
__device__ __forceinline__ float sigm(float x){ return 1.f / (1.f + __expf(-x)); }
__device__ __forceinline__ float tanh_f(float x){
  float ax = fabsf(x);
  float t = __expf(-2.f * ax);
  float r = (1.f - t) / (1.f + t);
  return copysignf(r, x);
}

// fragment load: lane holds M[(r0+(lane&15))*ld + k0 + (lane>>4)*8 .. +8)
__device__ __forceinline__ v8s ldfrag(const u16* base, size_t ld, int r0, int k0){
  int lane = threadIdx.x & 63;
  const u16* p = base + (size_t)(r0 + (lane & 15)) * ld + (size_t)(k0 + ((lane >> 4) << 3));
  return *(const v8s*)p;
}

// ---- LDS weight slice: [3 gates][16 rows][64 chunks of 8], chunk ^= (row&7)
__device__ __forceinline__ v8s ldfrag_w(const u16* wlds, int gate, int kt){
  int lane = threadIdx.x & 63;
  int rr = lane & 15;
  int ch = (kt*4 + (lane >> 4)) ^ (rr & 7);
  return *(const v8s*)(wlds + (size_t)((gate*16 + rr)*64 + ch) * 8);
}
__device__ void stage_wslice(const float* Wf, u16* wlds, int col0){
  for (int idx = threadIdx.x; idx < 3*16*64; idx += TPB){
    int ch = idx & 63, rr = (idx >> 6) & 15, g = idx >> 10;
    const float* src = Wf + ((size_t)(g*512 + col0 + rr))*512 + ch*8;
    v4f f0 = *(const v4f*)src, f1 = *(const v4f*)(src + 4);
    v8s o;
    #pragma unroll
    for (int j=0;j<4;j++){ o[j] = (short)f2bf(f0[j]); o[4+j] = (short)f2bf(f1[j]); }
    *(v8s*)(wlds + (size_t)((g*16 + rr)*64 + (ch ^ (rr & 7))) * 8) = o;
  }
}

struct KArgs {
  // inputs (f32)
  const float *x, *target, *eWih_f, *eWhh_f, *ebih, *ebhh;
  const float *dWih0_f, *dWih1_f, *dWhh_f, *dbih, *dbhh;
  const float *aWw_f, *aWb, *aCw_f, *aCb, *o1w_f, *o1b, *o2w_f, *o2b;
  float* out;
  // barrier page
  u32 *flags, *genp;
  // bf16 weights / activations in ws
  u16 *xhi, *h0hi, *h1hi, *encout;
  u16 *dWih0h,*dWih0l,*dWih1h,*dWih1l,*dWhhh,*dWhhl;
  u16 *Wwhh,*Wwhl,*Wwxh,*Wwxl,*Wchh,*Wchl,*Wcxh,*Wcxl;
  u16 *o2wh,*o2wl,*o1Th,*o1Tl,*Wph,*Wpl;
  float *bpr;
  u16 *xth,*xtl;
  float *preW,*preC;
  u16 *dh0h,*dh0l,*dh1h,*dh1l;
  float *logits;
  u16 *wcth,*wctl,*xch,*xcl;
};

// ---- CP-bypass flag load: reads coherence-point value, no RMW, no inv -----
__device__ __forceinline__ u32 ldcp(const u32* p){
  u32 r;
  asm volatile("global_load_dword %0, %1, off sc0 sc1\n\ts_waitcnt vmcnt(0)"
               : "=&v"(r) : "v"(p) : "memory");
  return r;
}

// ---- grid barrier: RELEASE RMW arrival, sc-load polls, ACQUIRE fence exit --
__device__ void gbar(u32* flags, u32* genp, u32 target){
  __syncthreads();
  int wg = blockIdx.x, tid = threadIdx.x;
  if (wg == 0){
    if (tid > 0 && tid < NWG){
      while (ldcp(&flags[tid]) < target) __builtin_amdgcn_s_sleep(1);
    }
    __syncthreads();
    if (tid == 0)
      __hip_atomic_fetch_add(genp, 1u, __ATOMIC_RELEASE, __HIP_MEMORY_SCOPE_AGENT);
  } else {
    if (tid == 0){
      __hip_atomic_fetch_add(&flags[wg], 1u, __ATOMIC_RELEASE, __HIP_MEMORY_SCOPE_AGENT);
      while (ldcp(genp) < target) __builtin_amdgcn_s_sleep(1);
    }
  }
  __builtin_amdgcn_fence(__ATOMIC_ACQUIRE, "agent");
  __syncthreads();
}

// ---- generic 64x16 tile of  C = A @ B^T  (split-bf16 3-pass) --------------
__device__ __forceinline__ v4f tile_xwT(const u16* Ah, const u16* Al, size_t lda, int nks,
                                        const u16* Bh, const u16* Bl, size_t ldb,
                                        int row0, int brow0, v4f* red){
  int tid = threadIdx.x, w = tid >> 6, lane = tid & 63;
  v4f acc[4];
  #pragma unroll
  for (int i=0;i<4;i++) acc[i] = (v4f){0.f,0.f,0.f,0.f};
  for (int ks = w; ks < nks; ks += 4){
    int k0 = ks * 32;
    v8s bh = ldfrag(Bh, ldb, brow0, k0);
    v8s bl = ldfrag(Bl, ldb, brow0, k0);
    #pragma unroll
    for (int rt=0; rt<4; rt++){
      v8s a  = ldfrag(Ah, lda, row0 + rt*16, k0);
      v8s al = ldfrag(Al, lda, row0 + rt*16, k0);
      acc[rt] = MFMA_(a,  bh, acc[rt]);
      acc[rt] = MFMA_(al, bh, acc[rt]);
      acc[rt] = MFMA_(a,  bl, acc[rt]);
    }
  }
  __syncthreads();
  red[(0*4+w)*64+lane]=acc[0]; red[(1*4+w)*64+lane]=acc[1];
  red[(2*4+w)*64+lane]=acc[2]; red[(3*4+w)*64+lane]=acc[3];
  __syncthreads();
  v4f g = red[(w*4+0)*64+lane];
  g += red[(w*4+1)*64+lane]; g += red[(w*4+2)*64+lane]; g += red[(w*4+3)*64+lane];
  return g;
}

// ---- decoder GRU gate tile: acc types {0:r, 1:z, 2:n_i, 3:n_h} ------------
template<bool PAIR>
__device__ __forceinline__ void gru_tile(const u16* Axh, const u16* Axl, size_t ldx, int nkx,
                                         const u16* Ahh, const u16* Ahl, size_t ldh, int nkh,
                                         const u16* Wi,  const u16* Wil, size_t ldwi,
                                         const u16* Wh,  const u16* Whl, size_t ldwh,
                                         int row0, int col0, v4f* red, v4f* gate){
  int tid = threadIdx.x, w = tid >> 6, lane = tid & 63;
  v4f acc[4][4];
  #pragma unroll
  for (int i=0;i<4;i++){
    #pragma unroll
    for (int j=0;j<4;j++) acc[i][j] = (v4f){0.f,0.f,0.f,0.f};
  }
  for (int ks = w; ks < nkx; ks += 4){
    int k0 = ks * 32;
    v8s br = ldfrag(Wi, ldwi,        col0, k0);
    v8s bz = ldfrag(Wi, ldwi,  512 + col0, k0);
    v8s bn = ldfrag(Wi, ldwi, 1024 + col0, k0);
    v8s brl, bzl, bnl;
    if (PAIR){ brl = ldfrag(Wil, ldwi, col0, k0); bzl = ldfrag(Wil, ldwi, 512+col0, k0); bnl = ldfrag(Wil, ldwi, 1024+col0, k0); }
    #pragma unroll
    for (int rt=0; rt<4; rt++){
      v8s a = ldfrag(Axh, ldx, row0 + rt*16, k0);
      acc[rt][0] = MFMA_(a, br, acc[rt][0]);
      acc[rt][1] = MFMA_(a, bz, acc[rt][1]);
      acc[rt][2] = MFMA_(a, bn, acc[rt][2]);
      if (PAIR){
        v8s al = ldfrag(Axl, ldx, row0 + rt*16, k0);
        acc[rt][0] = MFMA_(al, br, acc[rt][0]); acc[rt][0] = MFMA_(a, brl, acc[rt][0]);
        acc[rt][1] = MFMA_(al, bz, acc[rt][1]); acc[rt][1] = MFMA_(a, bzl, acc[rt][1]);
        acc[rt][2] = MFMA_(al, bn, acc[rt][2]); acc[rt][2] = MFMA_(a, bnl, acc[rt][2]);
      }
    }
  }
  for (int ks = w; ks < nkh; ks += 4){
    int k0 = ks * 32;
    v8s br = ldfrag(Wh, ldwh,        col0, k0);
    v8s bz = ldfrag(Wh, ldwh,  512 + col0, k0);
    v8s bn = ldfrag(Wh, ldwh, 1024 + col0, k0);
    v8s brl, bzl, bnl;
    if (PAIR){ brl = ldfrag(Whl, ldwh, col0, k0); bzl = ldfrag(Whl, ldwh, 512+col0, k0); bnl = ldfrag(Whl, ldwh, 1024+col0, k0); }
    #pragma unroll
    for (int rt=0; rt<4; rt++){
      v8s a = ldfrag(Ahh, ldh, row0 + rt*16, k0);
      acc[rt][0] = MFMA_(a, br, acc[rt][0]);
      acc[rt][1] = MFMA_(a, bz, acc[rt][1]);
      acc[rt][3] = MFMA_(a, bn, acc[rt][3]);
      if (PAIR){
        v8s al = ldfrag(Ahl, ldh, row0 + rt*16, k0);
        acc[rt][0] = MFMA_(al, br, acc[rt][0]); acc[rt][0] = MFMA_(a, brl, acc[rt][0]);
        acc[rt][1] = MFMA_(al, bz, acc[rt][1]); acc[rt][1] = MFMA_(a, bzl, acc[rt][1]);
        acc[rt][3] = MFMA_(al, bn, acc[rt][3]); acc[rt][3] = MFMA_(a, bnl, acc[rt][3]);
      }
    }
  }
  #pragma unroll
  for (int ty=0; ty<4; ty++){
    __syncthreads();
    red[(0*4+w)*64+lane]=acc[0][ty]; red[(1*4+w)*64+lane]=acc[1][ty];
    red[(2*4+w)*64+lane]=acc[2][ty]; red[(3*4+w)*64+lane]=acc[3][ty];
    __syncthreads();
    v4f g = red[(w*4+0)*64+lane];
    g += red[(w*4+1)*64+lane]; g += red[(w*4+2)*64+lane]; g += red[(w*4+3)*64+lane];
    gate[ty] = g;
  }
}

__device__ __forceinline__ void gru_combine(const v4f* gate, const float* bih, const float* bhh,
                                            const u16* Hph, const u16* Hpl,
                                            u16* Hnh, u16* Hnl,
                                            int row0, int col0){
  int tid = threadIdx.x, w = tid >> 6, lane = tid & 63;
  int col  = col0 + (lane & 15);
  int rowb = row0 + w*16 + ((lane >> 4) << 2);
  float bir = bih[col], biz = bih[512+col], bin = bih[1024+col];
  float bhr = bhh[col], bhz = bhh[512+col], bhn = bhh[1024+col];
  #pragma unroll
  for (int e=0; e<4; e++){
    int row = rowb + e;
    float r = sigm(gate[0][e] + bir + bhr);
    float z = sigm(gate[1][e] + biz + bhz);
    float n = tanh_f(gate[2][e] + bin + r * (gate[3][e] + bhn));
    float hp = bf2f(Hph[(size_t)row*512 + col]) + bf2f(Hpl[(size_t)row*512 + col]);
    float hv = (1.f - z) * n + z * hp;
    splitstore(&Hnh[(size_t)row*512+col], &Hnl[(size_t)row*512+col], hv);
  }
}

// ---- encoder step, 64-row half: wave w owns rows row0 + w*16 .. +16 --------
__device__ void enc_step3(const u16* Xb, size_t ldX, const u16* Hp, u16* Hn,
                          u16* encw, int t, const u16* wI, const u16* wH,
                          const float* bih, const float* bhh, int col0, int row0){
  const int tid = threadIdx.x, w = tid>>6, lane = tid&63;
  v4f aR=(v4f){0,0,0,0}, aZ=aR, aNI=aR, aNH=aR;
  const int r0 = row0 + w*16;
  for (int kt=0; kt<16; ++kt){
    int k0 = kt*32;
    v8s bi0=ldfrag_w(wI,0,kt), bi1=ldfrag_w(wI,1,kt), bi2=ldfrag_w(wI,2,kt);
    v8s bh0=ldfrag_w(wH,0,kt), bh1=ldfrag_w(wH,1,kt), bh2=ldfrag_w(wH,2,kt);
    v8s ax = ldfrag(Xb, ldX, r0, k0);
    v8s ah = ldfrag(Hp, 512, r0, k0);
    aR=MFMA_(ax,bi0,aR); aZ=MFMA_(ax,bi1,aZ); aNI=MFMA_(ax,bi2,aNI);
    aR=MFMA_(ah,bh0,aR); aZ=MFMA_(ah,bh1,aZ); aNH=MFMA_(ah,bh2,aNH);
  }
  int col = col0 + (lane&15);
  float bir=bih[col], biz=bih[512+col], bin=bih[1024+col];
  float bhr=bhh[col], bhz=bhh[512+col], bhn=bhh[1024+col];
  int rowb = r0 + ((lane>>4)<<2);
  #pragma unroll
  for (int e=0;e<4;e++){
    int row = rowb + e;
    float r = sigm(aR[e] + bir + bhr);
    float z = sigm(aZ[e] + biz + bhz);
    float n = tanh_f(aNI[e] + bin + r*(aNH[e] + bhn));
    float hp = bf2f(Hp[(size_t)row*512 + col]);
    float hv = (1.f-z)*n + z*hp;
    u16 h16 = f2bf(hv);
    Hn[(size_t)row*512 + col] = h16;
    if (encw) encw[((size_t)row*256 + t)*512 + col] = h16;
  }
}

__device__ __forceinline__ float blk_max(float v, float* sred){
  #pragma unroll
  for (int off=32; off>0; off>>=1) v = fmaxf(v, __shfl_xor(v, off, 64));
  __syncthreads();
  if ((threadIdx.x & 63) == 0) sred[threadIdx.x >> 6] = v;
  __syncthreads();
  return fmaxf(fmaxf(sred[0], sred[1]), fmaxf(sred[2], sred[3]));
}
__device__ __forceinline__ float blk_sum(float v, float* sred){
  #pragma unroll
  for (int off=32; off>0; off>>=1) v += __shfl_xor(v, off, 64);
  __syncthreads();
  if ((threadIdx.x & 63) == 0) sred[threadIdx.x >> 6] = v;
  __syncthreads();
  return sred[0] + sred[1] + sred[2] + sred[3];
}

#define DECOUT_OFF 0
#define DECHID_OFF 1228800      // 128*32*300
#define ATTN_OFF   1359872      // + 2*128*512

__global__ void __launch_bounds__(TPB, 1) traffic_kernel(KArgs A){
  __shared__ union {
    struct { u16 wI[3*16*64*8]; u16 wH[3*16*64*8]; } enc;   // 48KB + 48KB
    struct { float awl[2][256]; } dec;
  } U;
  __shared__ v4f red[4*4*64];   // 16KB reduce scratch
  __shared__ float sred[4];
  const int tid = threadIdx.x;
  const int wg  = blockIdx.x;
  const size_t gtid = (size_t)wg * TPB + tid;
  const size_t P = (size_t)NWG * TPB;
  u32 bt = 0;

  // ================= Phase 0: conversion / padding / zeroing ===============
  for (size_t i=gtid; i<128UL*256*512; i+=P) A.xhi[i] = f2bf(A.x[i]);
  for (size_t i=gtid; i<1536UL*320; i+=P){
    size_t r=i/320, c=i%320;
    float v = (c<300)? A.dWih0_f[r*300+c] : 0.f;
    splitstore(&A.dWih0h[i], &A.dWih0l[i], v);
  }
  for (size_t i=gtid; i<1536UL*512; i+=P) splitstore(&A.dWih1h[i], &A.dWih1l[i], A.dWih1_f[i]);
  for (size_t i=gtid; i<2UL*1536*512; i+=P) splitstore(&A.dWhhh[i], &A.dWhhl[i], A.dWhh_f[i]);
  for (size_t i=gtid; i<256UL*512; i+=P){ size_t r=i>>9, c=i&511; splitstore(&A.Wwhh[i], &A.Wwhl[i], A.aWw_f[r*812+300+c]); }
  for (size_t i=gtid; i<256UL*320; i+=P){ size_t r=i/320, c=i%320; float v=(c<300)? A.aWw_f[r*812+c]:0.f; splitstore(&A.Wwxh[i], &A.Wwxl[i], v); }
  for (size_t i=gtid; i<304UL*512; i+=P){ size_t r=i>>9, c=i&511; float v=(r<300)? A.aCw_f[r*812+300+c]:0.f; splitstore(&A.Wchh[i], &A.Wchl[i], v); }
  for (size_t i=gtid; i<304UL*320; i+=P){ size_t r=i/320, c=i%320; float v=(r<300&&c<300)? A.aCw_f[r*812+c]:0.f; splitstore(&A.Wcxh[i], &A.Wcxl[i], v); }
  for (size_t i=gtid; i<320UL*320; i+=P){ size_t r=i/320, c=i%320; float v=(r<300&&c<300)? A.o2w_f[r*300+c]:0.f; splitstore(&A.o2wh[i], &A.o2wl[i], v); }
  for (size_t i=gtid; i<512UL*320; i+=P){
    size_t j=i/320, k=i%320;
    float v = (k<300)? A.o1w_f[k*512+j] : 0.f;
    splitstore(&A.o1Th[i], &A.o1Tl[i], v);
  }
  for (size_t i=gtid; i<304; i+=P){
    float s = 0.f;
    if (i < 300){
      s = A.o2b[i];
      const float* wrow = A.o2w_f + i*300;
      for (int k=0;k<300;k++) s += wrow[k] * A.o1b[k];
    }
    A.bpr[i] = s;
  }
  for (size_t i=gtid; i<32UL*128*320; i+=P){
    size_t sb=i/320, c=i%320, s2=sb>>7, b=sb&127;
    float v = (c<300)? A.target[(b*33+s2)*300 + c] : 0.f;
    splitstore(&A.xth[i], &A.xtl[i], v);
  }
  for (size_t i=gtid; i<65536; i+=P){ A.h0hi[i]=0; A.h1hi[i]=0; }
  for (size_t i=gtid; i<128UL*320; i+=P){ A.xch[i]=0; A.xcl[i]=0; }
  gbar(A.flags, A.genp, ++bt);

  // ================= Phase 0b: xt-side attn linears + W' ===================
  for (int tl = wg; tl < 1024; tl += NWG){        // preW: (32*128) x 256
    int rb = tl >> 4, cb = tl & 15;
    int row0 = rb*64, col0 = cb*16;
    v4f g = tile_xwT(A.xth, A.xtl, 320, 10, A.Wwxh, A.Wwxl, 320, row0, col0, red);
    int w = tid>>6, lane = tid&63;
    int col = col0 + (lane&15), rowb = row0 + w*16 + ((lane>>4)<<2);
    #pragma unroll
    for (int e=0;e<4;e++){ int row=rowb+e; A.preW[(size_t)row*256+col] = g[e] + A.aWb[col]; }
  }
  for (int tl = wg; tl < 1216; tl += NWG){        // preC: (32*128) x 304
    int rb = tl / 19, cb = tl % 19;
    int row0 = rb*64, col0 = cb*16;
    v4f g = tile_xwT(A.xth, A.xtl, 320, 10, A.Wcxh, A.Wcxl, 320, row0, col0, red);
    int w = tid>>6, lane = tid&63;
    int col = col0 + (lane&15), rowb = row0 + w*16 + ((lane>>4)<<2);
    #pragma unroll
    for (int e=0;e<4;e++){
      int row=rowb+e;
      float v = (col<300)? (g[e] + A.aCb[col]) : 0.f;
      A.preC[(size_t)row*320+col] = v;
    }
  }
  for (int tl = wg; tl < 160; tl += NWG){         // W' = o2w @ o1w  (320pad x 512)
    int rt = tl >> 5, ct = tl & 31;
    int row0 = rt*64, col0 = ct*16;
    v4f g = tile_xwT(A.o2wh, A.o2wl, 320, 10, A.o1Th, A.o1Tl, 320, row0, col0, red);
    int w = tid>>6, lane = tid&63;
    int col = col0 + (lane&15), rowb = row0 + w*16 + ((lane>>4)<<2);
    #pragma unroll
    for (int e=0;e<4;e++){
      int row = rowb+e;
      if (row < 304) splitstore(&A.Wph[(size_t)row*512+col], &A.Wpl[(size_t)row*512+col], g[e]);
    }
  }
  gbar(A.flags, A.genp, ++bt);

  // ===== Encoder: 2 layers x 32 colgroups x 2 batch-halves, pipelined ======
  {
    const int grp  = wg >> 6;                  // 0: layer0, 1: layer1
    const int sub  = wg & 63;
    const int col0 = (sub >> 1) * 16;
    const int row0 = (sub & 1) * 64;           // batch-half
    stage_wslice(A.eWih_f + (size_t)grp*1536*512, U.enc.wI, col0);
    stage_wslice(A.eWhh_f + (size_t)grp*1536*512, U.enc.wH, col0);
    __syncthreads();
    const float* bih = A.ebih + grp*1536;
    const float* bhh = A.ebhh + grp*1536;
    for (int k=0; k<=256; ++k){
      if (grp == 0){
        if (k < 256)
          enc_step3(A.xhi + (size_t)k*512, (size_t)256*512,
                    A.h0hi + (size_t)k*65536, A.h0hi + (size_t)(k+1)*65536,
                    nullptr, 0, U.enc.wI, U.enc.wH, bih, bhh, col0, row0);
      } else {
        if (k >= 1){
          int t = k-1;
          enc_step3(A.h0hi + (size_t)k*65536, 512,
                    A.h1hi + (size_t)(t&1)*65536, A.h1hi + (size_t)((t+1)&1)*65536,
                    A.encout, t, U.enc.wI, U.enc.wH, bih, bhh, col0, row0);
        }
      }
      gbar(A.flags, A.genp, ++bt);
    }
  }

  // ================= Decoder init: h = enc_hidden ==========================
  for (size_t i=gtid; i<65536; i+=P){
    A.dh0h[i] = A.h0hi[(size_t)256*65536 + i]; A.dh0l[i] = 0;
    A.dh1h[i] = A.h1hi[i];                     A.dh1l[i] = 0;   // layer1 final in buf 0
  }
  gbar(A.flags, A.genp, ++bt);

  // ================= Decoder: 32 steps, 5 barriers/step ====================
  for (int s=0; s<32; s++){
    const u16* h0ph = A.dh0h + (size_t)(s&1)*65536;
    const u16* h0pl = A.dh0l + (size_t)(s&1)*65536;
    u16* h0nh = A.dh0h + (size_t)((s+1)&1)*65536;
    u16* h0nl = A.dh0l + (size_t)((s+1)&1)*65536;
    const u16* h1ph = A.dh1h + (size_t)(s&1)*65536;
    const u16* h1pl = A.dh1l + (size_t)(s&1)*65536;
    u16* h1nh = A.dh1h + (size_t)((s+1)&1)*65536;
    u16* h1nl = A.dh1l + (size_t)((s+1)&1)*65536;

    // S1: logits = preW[s] + h1 @ Wwh^T      (128 x 256)
    if (wg < 32){
      int rb = wg >> 4, cb = wg & 15;
      int row0 = rb*64, col0 = cb*16;
      v4f g = tile_xwT(h1ph, h1pl, 512, 16, A.Wwhh, A.Wwhl, 512, row0, col0, red);
      const float* pre = A.preW + (size_t)s*128*256;
      int w = tid>>6, lane = tid&63;
      int col = col0 + (lane&15), rowb = row0 + w*16 + ((lane>>4)<<2);
      #pragma unroll
      for (int e=0;e<4;e++){ int row=rowb+e; A.logits[(size_t)row*256+col] = g[e] + pre[(size_t)row*256+col]; }
    }
    gbar(A.flags, A.genp, ++bt);

    // S2+S3 fused: softmax (aw in LDS) + weighted context
    if (wg < 64){
      int b0 = wg*2, b1 = b0+1;
      #pragma unroll
      for (int bi=0; bi<2; bi++){
        int b = wg*2 + bi;
        float v = A.logits[(size_t)b*256 + tid];
        float m = blk_max(v, sred);
        float e = __expf(v - m);
        float ssum = blk_sum(e, sred);
        float awv = e / ssum;
        U.dec.awl[bi][tid] = awv;
        A.out[ATTN_OFF + ((size_t)b*32 + s)*256 + tid] = awv;
      }
      __syncthreads();
      float a00=0.f,a01=0.f,a10=0.f,a11=0.f;
      const u16* e0 = A.encout + (size_t)b0*256*512;
      const u16* e1 = A.encout + (size_t)b1*256*512;
      for (int t2=0; t2<256; t2++){
        float w0 = U.dec.awl[0][t2], w1 = U.dec.awl[1][t2];
        a00 += w0 * bf2f(e0[(size_t)t2*512 + tid]);
        a01 += w0 * bf2f(e0[(size_t)t2*512 + 256 + tid]);
        a10 += w1 * bf2f(e1[(size_t)t2*512 + tid]);
        a11 += w1 * bf2f(e1[(size_t)t2*512 + 256 + tid]);
      }
      splitstore(&A.wcth[(size_t)b0*512+tid],     &A.wctl[(size_t)b0*512+tid],     a00);
      splitstore(&A.wcth[(size_t)b0*512+256+tid], &A.wctl[(size_t)b0*512+256+tid], a01);
      splitstore(&A.wcth[(size_t)b1*512+tid],     &A.wctl[(size_t)b1*512+tid],     a10);
      splitstore(&A.wcth[(size_t)b1*512+256+tid], &A.wctl[(size_t)b1*512+256+tid], a11);
    }
    gbar(A.flags, A.genp, ++bt);

    // S4: xc = relu(preC[s] + wctx @ Wch^T)   (128 x 304, pads stay 0)
    if (wg < 38){
      int rb = wg / 19, cb = wg % 19;
      int row0 = rb*64, col0 = cb*16;
      v4f g = tile_xwT(A.wcth, A.wctl, 512, 16, A.Wchh, A.Wchl, 512, row0, col0, red);
      const float* pre = A.preC + (size_t)s*128*320;
      int w = tid>>6, lane = tid&63;
      int col = col0 + (lane&15), rowb = row0 + w*16 + ((lane>>4)<<2);
      #pragma unroll
      for (int e=0;e<4;e++){
        int row = rowb+e;
        float v = (col<300)? fmaxf(g[e] + pre[(size_t)row*320+col], 0.f) : 0.f;
        splitstore(&A.xch[(size_t)row*320+col], &A.xcl[(size_t)row*320+col], v);
      }
    }
    gbar(A.flags, A.genp, ++bt);

    // S5: GRU layer 0: h0' = gru(xc, h0)
    if (wg < 64){
      int rb = wg >> 5, cb = wg & 31;
      int row0 = rb*64, col0 = cb*16;
      v4f gate[4];
      gru_tile<true>(A.xch, A.xcl, 320, 10, h0ph, h0pl, 512, 16,
                     A.dWih0h, A.dWih0l, 320, A.dWhhh, A.dWhhl, 512, row0, col0, red, gate);
      gru_combine(gate, A.dbih, A.dbhh, h0ph, h0pl, h0nh, h0nl, row0, col0);
    }
    gbar(A.flags, A.genp, ++bt);

    // S6: GRU layer 1: h1' = gru(h0', h1)
    if (wg < 64){
      int rb = wg >> 5, cb = wg & 31;
      int row0 = rb*64, col0 = cb*16;
      v4f gate[4];
      gru_tile<true>(h0nh, h0nl, 512, 16, h1ph, h1pl, 512, 16,
                     A.dWih1h, A.dWih1l, 512,
                     A.dWhhh + (size_t)1536*512, A.dWhhl + (size_t)1536*512, 512,
                     row0, col0, red, gate);
      gru_combine(gate, A.dbih + 1536, A.dbhh + 1536, h1ph, h1pl, h1nh, h1nl, row0, col0);
    }
    gbar(A.flags, A.genp, ++bt);

    // S8': dec_out[:,s,:] = h1' @ W'^T + b'   (fused S7+S8; no trailing bar)
    if (wg < 38){
      int rb = wg / 19, cb = wg % 19;
      int row0 = rb*64, col0 = cb*16;
      v4f g = tile_xwT(h1nh, h1nl, 512, 16, A.Wph, A.Wpl, 512, row0, col0, red);
      int w = tid>>6, lane = tid&63;
      int col = col0 + (lane&15), rowb = row0 + w*16 + ((lane>>4)<<2);
      #pragma unroll
      for (int e=0;e<4;e++){
        int row = rowb+e;
        if (col < 300) A.out[DECOUT_OFF + ((size_t)row*32 + s)*300 + col] = g[e] + A.bpr[col];
      }
    }
  }

  // ================= dec_hidden output (final h in buffer 0) ===============
  for (size_t i=gtid; i<65536; i+=P){
    A.out[DECHID_OFF + i]         = bf2f(A.dh0h[i]) + bf2f(A.dh0l[i]);
    A.out[DECHID_OFF + 65536 + i] = bf2f(A.dh1h[i]) + bf2f(A.dh1l[i]);
  }
}

// ===========================================================================
extern "C" void kernel_launch(void* const* d_in, const int* in_sizes, int n_in,
                              void* d_out, int out_size, void* d_ws, size_t ws_size,
                              hipStream_t stream){
  (void)in_sizes; (void)n_in; (void)out_size; (void)ws_size;
  KArgs A;
  A.x       = (const float*)d_in[0];  A.target = (const float*)d_in[1];
  A.eWih_f  = (const float*)d_in[2];  A.eWhh_f = (const float*)d_in[3];
  A.ebih    = (const float*)d_in[4];  A.ebhh   = (const float*)d_in[5];
  A.dWih0_f = (const float*)d_in[6];  A.dWih1_f= (const float*)d_in[7];
  A.dWhh_f  = (const float*)d_in[8];  A.dbih   = (const float*)d_in[9];
  A.dbhh    = (const float*)d_in[10];
  A.aWw_f   = (const float*)d_in[11]; A.aWb    = (const float*)d_in[12];
  A.aCw_f   = (const float*)d_in[13]; A.aCb    = (const float*)d_in[14];
  A.o1w_f   = (const float*)d_in[15]; A.o1b    = (const float*)d_in[16];
  A.o2w_f   = (const float*)d_in[17]; A.o2b    = (const float*)d_in[18];
  A.out = (float*)d_out;

  char* w = (char*)d_ws;
  size_t off = 0;
  auto alloc = [&](size_t bytes)->char*{
    char* p = w + off; off += (bytes + 255) & ~(size_t)255; return p;
  };
  char* barp = alloc(4096);
  A.flags  = (u32*)barp;               // [0..127]
  A.genp   = (u32*)(barp + 2048);
  A.xhi    = (u16*)alloc(128UL*256*512*2);
  A.h0hi   = (u16*)alloc(257UL*128*512*2);
  A.h1hi   = (u16*)alloc(2UL*128*512*2);
  A.encout = A.xhi;   // alias: layer0 reads xhi[t=k] while layer1 writes
                      // encout[t=k-1] -- trailing by one t-slice, disjoint
  A.dWih0h = (u16*)alloc(1536UL*320*2); A.dWih0l = (u16*)alloc(1536UL*320*2);
  A.dWih1h = (u16*)alloc(1536UL*512*2); A.dWih1l = (u16*)alloc(1536UL*512*2);
  A.dWhhh  = (u16*)alloc(2UL*1536*512*2); A.dWhhl = (u16*)alloc(2UL*1536*512*2);
  A.Wwhh   = (u16*)alloc(256UL*512*2);  A.Wwhl   = (u16*)alloc(256UL*512*2);
  A.Wwxh   = (u16*)alloc(256UL*320*2);  A.Wwxl   = (u16*)alloc(256UL*320*2);
  A.Wchh   = (u16*)alloc(304UL*512*2);  A.Wchl   = (u16*)alloc(304UL*512*2);
  A.Wcxh   = (u16*)alloc(304UL*320*2);  A.Wcxl   = (u16*)alloc(304UL*320*2);
  A.o2wh   = (u16*)alloc(320UL*320*2);  A.o2wl   = (u16*)alloc(320UL*320*2);
  A.o1Th   = (u16*)alloc(512UL*320*2);  A.o1Tl   = (u16*)alloc(512UL*320*2);
  A.Wph    = (u16*)alloc(304UL*512*2);  A.Wpl    = (u16*)alloc(304UL*512*2);
  A.bpr    = (float*)alloc(304UL*4);
  A.xth    = (u16*)alloc(32UL*128*320*2); A.xtl  = (u16*)alloc(32UL*128*320*2);
  A.preW   = (float*)alloc(32UL*128*256*4);
  A.preC   = (float*)alloc(32UL*128*320*4);
  A.dh0h   = (u16*)alloc(2UL*65536*2); A.dh0l = (u16*)alloc(2UL*65536*2);
  A.dh1h   = (u16*)alloc(2UL*65536*2); A.dh1l = (u16*)alloc(2UL*65536*2);
  A.logits = (float*)alloc(128UL*256*4);
  A.wcth   = (u16*)alloc(128UL*512*2); A.wctl = (u16*)alloc(128UL*512*2);
  A.xch    = (u16*)alloc(128UL*320*2); A.xcl  = (u16*)alloc(128UL*320*2);

  hipMemsetAsync(d_ws, 0, 4096, stream);   // reset barrier page each launch
  traffic_kernel<<<dim3(NWG), dim3(TPB), 0, stream>>>(A);
}

// Round 12
// 6692.629 us; speedup vs baseline: 10.6532x; 1.5533x over previous
//
#include <hip/hip_runtime.h>
#include <hip/hip_bf16.h>
#include <math.h>

// ---------------------------------------------------------------------------
// TrafficSeq2Seq round 12 = round-11 (proven, 10.4ms) with refill-traffic cuts:
//  1. XCD-affine work placement via election (vwg = xcd*16+slot; identity
//     fallback if dispatch isn't balanced 16/XCD) -- encoder classes become
//     (layer, batch-half, col) so each XCD refetches 1 half-operand pair
//  2. decoder S5 -> WGs 0-63 with dWhh-L0 col-slice pinned in LDS (staged
//     once, reusing the encoder's 96KB union); S6 -> WGs 64-127 with dWhh-L1
//  3. S2+S3 on 128 WGs (1 batch each), wave-chunked t2 accumulation (4x MLP)
// Sync structure/protocol unchanged from round 11.
// ---------------------------------------------------------------------------

#define NWG 128
#define TPB 256

typedef unsigned short u16;
typedef unsigned int   u32;
typedef short v8s __attribute__((ext_vector_type(8)));
typedef float v4f __attribute__((ext_vector_type(4)));

#define MFMA_(a,b,c) __builtin_amdgcn_mfma_f32_16x16x32_bf16((a),(b),(c),0,0,0)

__device__ __forceinline__ u16 f2bf(float f){
  unsigned u = __builtin_bit_cast(unsigned, f);
  unsigned r = u + 0x7FFFu + ((u >> 16) & 1u);
  return (u16)(r >> 16);
}
__device__ __forceinline__ float bf2f(u16 s){
  unsigned u = ((unsigned)s) << 16;
  return __builtin_bit_cast(float, u);
}
__device__ __forceinline__ void splitstore(u16* ph, u16* pl, float v){
  u16 h = f2bf(v); ph[0] = h; pl[0] = f2bf(v - bf2f(h));
}
__device__ __forceinline__ float sigm(float x){ return 1.f / (1.f + __expf(-x)); }
__device__ __forceinline__ float tanh_f(float x){
  float ax = fabsf(x);
  float t = __expf(-2.f * ax);
  float r = (1.f - t) / (1.f + t);
  return copysignf(r, x);
}

// fragment load: lane holds M[(r0+(lane&15))*ld + k0 + (lane>>4)*8 .. +8)
__device__ __forceinline__ v8s ldfrag(const u16* base, size_t ld, int r0, int k0){
  int lane = threadIdx.x & 63;
  const u16* p = base + (size_t)(r0 + (lane & 15)) * ld + (size_t)(k0 + ((lane >> 4) << 3));
  return *(const v8s*)p;
}

// ---- LDS weight slice: [3 gates][16 rows][64 chunks of 8], chunk ^= (row&7)
__device__ __forceinline__ v8s ldfrag_w(const u16* wlds, int gate, int kt){
  int lane = threadIdx.x & 63;
  int rr = lane & 15;
  int ch = (kt*4 + (lane >> 4)) ^ (rr & 7);
  return *(const v8s*)(wlds + (size_t)((gate*16 + rr)*64 + ch) * 8);
}
__device__ void stage_wslice(const float* Wf, u16* wlds, int col0){
  for (int idx = threadIdx.x; idx < 3*16*64; idx += TPB){
    int ch = idx & 63, rr = (idx >> 6) & 15, g = idx >> 10;
    const float* src = Wf + ((size_t)(g*512 + col0 + rr))*512 + ch*8;
    v4f f0 = *(const v4f*)src, f1 = *(const v4f*)(src + 4);
    v8s o;
    #pragma unroll
    for (int j=0;j<4;j++){ o[j] = (short)f2bf(f0[j]); o[4+j] = (short)f2bf(f1[j]); }
    *(v8s*)(wlds + (size_t)((g*16 + rr)*64 + (ch ^ (rr & 7))) * 8) = o;
  }
}
// stage split-bf16 global weight slice (hi+lo) into the same swizzled layout
__device__ void stage_wslice_u16(const u16* Wh, const u16* Wl, u16* dh, u16* dl, int col0){
  for (int idx = threadIdx.x; idx < 3*16*64; idx += TPB){
    int ch = idx & 63, rr = (idx >> 6) & 15, g = idx >> 10;
    size_t so = ((size_t)(g*512 + col0 + rr))*512 + ch*8;
    size_t o  = (size_t)((g*16 + rr)*64 + (ch ^ (rr & 7))) * 8;
    *(v8s*)(dh+o) = *(const v8s*)(Wh+so);
    *(v8s*)(dl+o) = *(const v8s*)(Wl+so);
  }
}

struct KArgs {
  // inputs (f32)
  const float *x, *target, *eWih_f, *eWhh_f, *ebih, *ebhh;
  const float *dWih0_f, *dWih1_f, *dWhh_f, *dbih, *dbhh;
  const float *aWw_f, *aWb, *aCw_f, *aCb, *o1w_f, *o1b, *o2w_f, *o2b;
  float* out;
  // barrier page
  u32 *flags, *genp, *ecnt;
  // bf16 weights / activations in ws
  u16 *xhi, *h0hi, *h1hi, *encout;
  u16 *dWih0h,*dWih0l,*dWih1h,*dWih1l,*dWhhh,*dWhhl;
  u16 *Wwhh,*Wwhl,*Wwxh,*Wwxl,*Wchh,*Wchl,*Wcxh,*Wcxl;
  u16 *o2wh,*o2wl,*o1Th,*o1Tl,*Wph,*Wpl;
  float *bpr;
  u16 *xth,*xtl;
  float *preW,*preC;
  u16 *dh0h,*dh0l,*dh1h,*dh1l;
  float *logits;
  u16 *wcth,*wctl,*xch,*xcl;
};

// ---- CP-bypass flag load: reads coherence-point value, no RMW, no inv -----
__device__ __forceinline__ u32 ldcp(const u32* p){
  u32 r;
  asm volatile("global_load_dword %0, %1, off sc0 sc1\n\ts_waitcnt vmcnt(0)"
               : "=&v"(r) : "v"(p) : "memory");
  return r;
}

// ---- grid barrier: RELEASE RMW arrival, sc-load polls, ACQUIRE fence exit --
__device__ void gbar(u32* flags, u32* genp, u32 target){
  __syncthreads();
  int wg = blockIdx.x, tid = threadIdx.x;
  if (wg == 0){
    if (tid > 0 && tid < NWG){
      while (ldcp(&flags[tid]) < target) __builtin_amdgcn_s_sleep(1);
    }
    __syncthreads();
    if (tid == 0)
      __hip_atomic_fetch_add(genp, 1u, __ATOMIC_RELEASE, __HIP_MEMORY_SCOPE_AGENT);
  } else {
    if (tid == 0){
      __hip_atomic_fetch_add(&flags[wg], 1u, __ATOMIC_RELEASE, __HIP_MEMORY_SCOPE_AGENT);
      while (ldcp(genp) < target) __builtin_amdgcn_s_sleep(1);
    }
  }
  __builtin_amdgcn_fence(__ATOMIC_ACQUIRE, "agent");
  __syncthreads();
}

// ---- generic 64x16 tile of  C = A @ B^T  (split-bf16 3-pass) --------------
__device__ __forceinline__ v4f tile_xwT(const u16* Ah, const u16* Al, size_t lda, int nks,
                                        const u16* Bh, const u16* Bl, size_t ldb,
                                        int row0, int brow0, v4f* red){
  int tid = threadIdx.x, w = tid >> 6, lane = tid & 63;
  v4f acc[4];
  #pragma unroll
  for (int i=0;i<4;i++) acc[i] = (v4f){0.f,0.f,0.f,0.f};
  for (int ks = w; ks < nks; ks += 4){
    int k0 = ks * 32;
    v8s bh = ldfrag(Bh, ldb, brow0, k0);
    v8s bl = ldfrag(Bl, ldb, brow0, k0);
    #pragma unroll
    for (int rt=0; rt<4; rt++){
      v8s a  = ldfrag(Ah, lda, row0 + rt*16, k0);
      v8s al = ldfrag(Al, lda, row0 + rt*16, k0);
      acc[rt] = MFMA_(a,  bh, acc[rt]);
      acc[rt] = MFMA_(al, bh, acc[rt]);
      acc[rt] = MFMA_(a,  bl, acc[rt]);
    }
  }
  __syncthreads();
  red[(0*4+w)*64+lane]=acc[0]; red[(1*4+w)*64+lane]=acc[1];
  red[(2*4+w)*64+lane]=acc[2]; red[(3*4+w)*64+lane]=acc[3];
  __syncthreads();
  v4f g = red[(w*4+0)*64+lane];
  g += red[(w*4+1)*64+lane]; g += red[(w*4+2)*64+lane]; g += red[(w*4+3)*64+lane];
  return g;
}

// ---- decoder GRU gate tile, Wh (hi+lo) PINNED in LDS ----------------------
__device__ __forceinline__ void gru_tile_pin(const u16* Axh, const u16* Axl, size_t ldx, int nkx,
                                             const u16* Ahh, const u16* Ahl,
                                             const u16* Wi,  const u16* Wil, size_t ldwi,
                                             const u16* whp, const u16* wlp,
                                             int row0, int col0, v4f* red, v4f* gate){
  int tid = threadIdx.x, w = tid >> 6, lane = tid & 63;
  v4f acc[4][4];
  #pragma unroll
  for (int i=0;i<4;i++){
    #pragma unroll
    for (int j=0;j<4;j++) acc[i][j] = (v4f){0.f,0.f,0.f,0.f};
  }
  for (int ks = w; ks < nkx; ks += 4){
    int k0 = ks * 32;
    v8s br = ldfrag(Wi, ldwi,        col0, k0);
    v8s bz = ldfrag(Wi, ldwi,  512 + col0, k0);
    v8s bn = ldfrag(Wi, ldwi, 1024 + col0, k0);
    v8s brl = ldfrag(Wil, ldwi, col0, k0);
    v8s bzl = ldfrag(Wil, ldwi, 512+col0, k0);
    v8s bnl = ldfrag(Wil, ldwi, 1024+col0, k0);
    #pragma unroll
    for (int rt=0; rt<4; rt++){
      v8s a  = ldfrag(Axh, ldx, row0 + rt*16, k0);
      v8s al = ldfrag(Axl, ldx, row0 + rt*16, k0);
      acc[rt][0] = MFMA_(a, br, acc[rt][0]); acc[rt][0] = MFMA_(al, br, acc[rt][0]); acc[rt][0] = MFMA_(a, brl, acc[rt][0]);
      acc[rt][1] = MFMA_(a, bz, acc[rt][1]); acc[rt][1] = MFMA_(al, bz, acc[rt][1]); acc[rt][1] = MFMA_(a, bzl, acc[rt][1]);
      acc[rt][2] = MFMA_(a, bn, acc[rt][2]); acc[rt][2] = MFMA_(al, bn, acc[rt][2]); acc[rt][2] = MFMA_(a, bnl, acc[rt][2]);
    }
  }
  for (int ks = w; ks < 16; ks += 4){
    int k0 = ks * 32;
    v8s br  = ldfrag_w(whp, 0, ks), bz  = ldfrag_w(whp, 1, ks), bn  = ldfrag_w(whp, 2, ks);
    v8s brl = ldfrag_w(wlp, 0, ks), bzl = ldfrag_w(wlp, 1, ks), bnl = ldfrag_w(wlp, 2, ks);
    #pragma unroll
    for (int rt=0; rt<4; rt++){
      v8s a  = ldfrag(Ahh, 512, row0 + rt*16, k0);
      v8s al = ldfrag(Ahl, 512, row0 + rt*16, k0);
      acc[rt][0] = MFMA_(a, br, acc[rt][0]); acc[rt][0] = MFMA_(al, br, acc[rt][0]); acc[rt][0] = MFMA_(a, brl, acc[rt][0]);
      acc[rt][1] = MFMA_(a, bz, acc[rt][1]); acc[rt][1] = MFMA_(al, bz, acc[rt][1]); acc[rt][1] = MFMA_(a, bzl, acc[rt][1]);
      acc[rt][3] = MFMA_(a, bn, acc[rt][3]); acc[rt][3] = MFMA_(al, bn, acc[rt][3]); acc[rt][3] = MFMA_(a, bnl, acc[rt][3]);
    }
  }
  #pragma unroll
  for (int ty=0; ty<4; ty++){
    __syncthreads();
    red[(0*4+w)*64+lane]=acc[0][ty]; red[(1*4+w)*64+lane]=acc[1][ty];
    red[(2*4+w)*64+lane]=acc[2][ty]; red[(3*4+w)*64+lane]=acc[3][ty];
    __syncthreads();
    v4f g = red[(w*4+0)*64+lane];
    g += red[(w*4+1)*64+lane]; g += red[(w*4+2)*64+lane]; g += red[(w*4+3)*64+lane];
    gate[ty] = g;
  }
}

__device__ __forceinline__ void gru_combine(const v4f* gate, const float* bih, const float* bhh,
                                            const u16* Hph, const u16* Hpl,
                                            u16* Hnh, u16* Hnl,
                                            int row0, int col0){
  int tid = threadIdx.x, w = tid >> 6, lane = tid & 63;
  int col  = col0 + (lane & 15);
  int rowb = row0 + w*16 + ((lane >> 4) << 2);
  float bir = bih[col], biz = bih[512+col], bin = bih[1024+col];
  float bhr = bhh[col], bhz = bhh[512+col], bhn = bhh[1024+col];
  #pragma unroll
  for (int e=0; e<4; e++){
    int row = rowb + e;
    float r = sigm(gate[0][e] + bir + bhr);
    float z = sigm(gate[1][e] + biz + bhz);
    float n = tanh_f(gate[2][e] + bin + r * (gate[3][e] + bhn));
    float hp = bf2f(Hph[(size_t)row*512 + col]) + bf2f(Hpl[(size_t)row*512 + col]);
    float hv = (1.f - z) * n + z * hp;
    splitstore(&Hnh[(size_t)row*512+col], &Hnl[(size_t)row*512+col], hv);
  }
}

// ---- encoder step, 64-row half: wave w owns rows row0 + w*16 .. +16 --------
__device__ void enc_step3(const u16* Xb, size_t ldX, const u16* Hp, u16* Hn,
                          u16* encw, int t, const u16* wI, const u16* wH,
                          const float* bih, const float* bhh, int col0, int row0){
  const int tid = threadIdx.x, w = tid>>6, lane = tid&63;
  v4f aR=(v4f){0,0,0,0}, aZ=aR, aNI=aR, aNH=aR;
  const int r0 = row0 + w*16;
  for (int kt=0; kt<16; ++kt){
    int k0 = kt*32;
    v8s bi0=ldfrag_w(wI,0,kt), bi1=ldfrag_w(wI,1,kt), bi2=ldfrag_w(wI,2,kt);
    v8s bh0=ldfrag_w(wH,0,kt), bh1=ldfrag_w(wH,1,kt), bh2=ldfrag_w(wH,2,kt);
    v8s ax = ldfrag(Xb, ldX, r0, k0);
    v8s ah = ldfrag(Hp, 512, r0, k0);
    aR=MFMA_(ax,bi0,aR); aZ=MFMA_(ax,bi1,aZ); aNI=MFMA_(ax,bi2,aNI);
    aR=MFMA_(ah,bh0,aR); aZ=MFMA_(ah,bh1,aZ); aNH=MFMA_(ah,bh2,aNH);
  }
  int col = col0 + (lane&15);
  float bir=bih[col], biz=bih[512+col], bin=bih[1024+col];
  float bhr=bhh[col], bhz=bhh[512+col], bhn=bhh[1024+col];
  int rowb = r0 + ((lane>>4)<<2);
  #pragma unroll
  for (int e=0;e<4;e++){
    int row = rowb + e;
    float r = sigm(aR[e] + bir + bhr);
    float z = sigm(aZ[e] + biz + bhz);
    float n = tanh_f(aNI[e] + bin + r*(aNH[e] + bhn));
    float hp = bf2f(Hp[(size_t)row*512 + col]);
    float hv = (1.f-z)*n + z*hp;
    u16 h16 = f2bf(hv);
    Hn[(size_t)row*512 + col] = h16;
    if (encw) encw[((size_t)row*256 + t)*512 + col] = h16;
  }
}

__device__ __forceinline__ float blk_max(float v, float* sred){
  #pragma unroll
  for (int off=32; off>0; off>>=1) v = fmaxf(v, __shfl_xor(v, off, 64));
  __syncthreads();
  if ((threadIdx.x & 63) == 0) sred[threadIdx.x >> 6] = v;
  __syncthreads();
  return fmaxf(fmaxf(sred[0], sred[1]), fmaxf(sred[2], sred[3]));
}
__device__ __forceinline__ float blk_sum(float v, float* sred){
  #pragma unroll
  for (int off=32; off>0; off>>=1) v += __shfl_xor(v, off, 64);
  __syncthreads();
  if ((threadIdx.x & 63) == 0) sred[threadIdx.x >> 6] = v;
  __syncthreads();
  return sred[0] + sred[1] + sred[2] + sred[3];
}

#define DECOUT_OFF 0
#define DECHID_OFF 1228800      // 128*32*300
#define ATTN_OFF   1359872      // + 2*128*512

__global__ void __launch_bounds__(TPB, 1) traffic_kernel(KArgs A){
  __shared__ struct { u16 wI[3*16*64*8]; u16 wH[3*16*64*8]; } WL;  // 96KB
  __shared__ v4f red[4*4*64];   // 16KB reduce scratch
  __shared__ float sred[4];
  __shared__ float awl2[256];   // 1KB (decoder softmax row)
  __shared__ int sh_xcd, sh_slot, sh_bal;
  const int tid = threadIdx.x;
  const int wg  = blockIdx.x;
  const size_t gtid = (size_t)wg * TPB + tid;
  const size_t P = (size_t)NWG * TPB;
  u32 bt = 0;

  // ================= Election: XCD id + slot ===============================
  {
    u32 xcd;
    asm volatile("s_getreg_b32 %0, hwreg(HW_REG_XCC_ID)" : "=s"(xcd));
    if (tid == 0){
      sh_xcd = (int)(xcd & 7);
      sh_slot = (int)__hip_atomic_fetch_add(&A.ecnt[sh_xcd], 1u, __ATOMIC_RELAXED, __HIP_MEMORY_SCOPE_AGENT);
    }
    __syncthreads();
  }

  // ================= Phase 0: conversion / padding / zeroing ===============
  for (size_t i=gtid; i<128UL*256*512; i+=P) A.xhi[i] = f2bf(A.x[i]);
  for (size_t i=gtid; i<1536UL*320; i+=P){
    size_t r=i/320, c=i%320;
    float v = (c<300)? A.dWih0_f[r*300+c] : 0.f;
    splitstore(&A.dWih0h[i], &A.dWih0l[i], v);
  }
  for (size_t i=gtid; i<1536UL*512; i+=P) splitstore(&A.dWih1h[i], &A.dWih1l[i], A.dWih1_f[i]);
  for (size_t i=gtid; i<2UL*1536*512; i+=P) splitstore(&A.dWhhh[i], &A.dWhhl[i], A.dWhh_f[i]);
  for (size_t i=gtid; i<256UL*512; i+=P){ size_t r=i>>9, c=i&511; splitstore(&A.Wwhh[i], &A.Wwhl[i], A.aWw_f[r*812+300+c]); }
  for (size_t i=gtid; i<256UL*320; i+=P){ size_t r=i/320, c=i%320; float v=(c<300)? A.aWw_f[r*812+c]:0.f; splitstore(&A.Wwxh[i], &A.Wwxl[i], v); }
  for (size_t i=gtid; i<304UL*512; i+=P){ size_t r=i>>9, c=i&511; float v=(r<300)? A.aCw_f[r*812+300+c]:0.f; splitstore(&A.Wchh[i], &A.Wchl[i], v); }
  for (size_t i=gtid; i<304UL*320; i+=P){ size_t r=i/320, c=i%320; float v=(r<300&&c<300)? A.aCw_f[r*812+c]:0.f; splitstore(&A.Wcxh[i], &A.Wcxl[i], v); }
  for (size_t i=gtid; i<320UL*320; i+=P){ size_t r=i/320, c=i%320; float v=(r<300&&c<300)? A.o2w_f[r*300+c]:0.f; splitstore(&A.o2wh[i], &A.o2wl[i], v); }
  for (size_t i=gtid; i<512UL*320; i+=P){
    size_t j=i/320, k=i%320;
    float v = (k<300)? A.o1w_f[k*512+j] : 0.f;
    splitstore(&A.o1Th[i], &A.o1Tl[i], v);
  }
  for (size_t i=gtid; i<304; i+=P){
    float s = 0.f;
    if (i < 300){
      s = A.o2b[i];
      const float* wrow = A.o2w_f + i*300;
      for (int k=0;k<300;k++) s += wrow[k] * A.o1b[k];
    }
    A.bpr[i] = s;
  }
  for (size_t i=gtid; i<32UL*128*320; i+=P){
    size_t sb=i/320, c=i%320, s2=sb>>7, b=sb&127;
    float v = (c<300)? A.target[(b*33+s2)*300 + c] : 0.f;
    splitstore(&A.xth[i], &A.xtl[i], v);
  }
  for (size_t i=gtid; i<65536; i+=P){ A.h0hi[i]=0; A.h1hi[i]=0; }
  for (size_t i=gtid; i<128UL*320; i+=P){ A.xch[i]=0; A.xcl[i]=0; }
  gbar(A.flags, A.genp, ++bt);

  // election result (final after B1); identity fallback if not 16/XCD
  if (tid == 0){
    int ok = 1;
    for (int x2=0; x2<8; x2++)
      ok &= (__hip_atomic_fetch_add(&A.ecnt[x2], 0u, __ATOMIC_RELAXED, __HIP_MEMORY_SCOPE_AGENT) == 16u);
    sh_bal = ok;
  }
  __syncthreads();
  const int vwg = sh_bal ? (sh_xcd*16 + sh_slot) : wg;

  // ================= Phase 0b: xt-side attn linears + W' ===================
  for (int tl = vwg; tl < 1024; tl += NWG){        // preW: (32*128) x 256
    int rb = tl >> 4, cb = tl & 15;
    int row0 = rb*64, col0 = cb*16;
    v4f g = tile_xwT(A.xth, A.xtl, 320, 10, A.Wwxh, A.Wwxl, 320, row0, col0, red);
    int w = tid>>6, lane = tid&63;
    int col = col0 + (lane&15), rowb = row0 + w*16 + ((lane>>4)<<2);
    #pragma unroll
    for (int e=0;e<4;e++){ int row=rowb+e; A.preW[(size_t)row*256+col] = g[e] + A.aWb[col]; }
  }
  for (int tl = vwg; tl < 1216; tl += NWG){        // preC: (32*128) x 304
    int rb = tl / 19, cb = tl % 19;
    int row0 = rb*64, col0 = cb*16;
    v4f g = tile_xwT(A.xth, A.xtl, 320, 10, A.Wcxh, A.Wcxl, 320, row0, col0, red);
    int w = tid>>6, lane = tid&63;
    int col = col0 + (lane&15), rowb = row0 + w*16 + ((lane>>4)<<2);
    #pragma unroll
    for (int e=0;e<4;e++){
      int row=rowb+e;
      float v = (col<300)? (g[e] + A.aCb[col]) : 0.f;
      A.preC[(size_t)row*320+col] = v;
    }
  }
  for (int tl = vwg; tl < 160; tl += NWG){         // W' = o2w @ o1w  (320pad x 512)
    int rt = tl >> 5, ct = tl & 31;
    int row0 = rt*64, col0 = ct*16;
    v4f g = tile_xwT(A.o2wh, A.o2wl, 320, 10, A.o1Th, A.o1Tl, 320, row0, col0, red);
    int w = tid>>6, lane = tid&63;
    int col = col0 + (lane&15), rowb = row0 + w*16 + ((lane>>4)<<2);
    #pragma unroll
    for (int e=0;e<4;e++){
      int row = rowb+e;
      if (row < 304) splitstore(&A.Wph[(size_t)row*512+col], &A.Wpl[(size_t)row*512+col], g[e]);
    }
  }
  gbar(A.flags, A.genp, ++bt);

  // ===== Encoder: XCD-affine classes (layer, batch-half, col), pipelined ===
  {
    const int grp  = vwg >> 6;                 // layer
    const int half = (vwg >> 5) & 1;           // batch half
    const int col0 = (vwg & 31) * 16;
    const int row0 = half * 64;
    stage_wslice(A.eWih_f + (size_t)grp*1536*512, WL.wI, col0);
    stage_wslice(A.eWhh_f + (size_t)grp*1536*512, WL.wH, col0);
    __syncthreads();
    const float* bih = A.ebih + grp*1536;
    const float* bhh = A.ebhh + grp*1536;
    for (int k=0; k<=256; ++k){
      if (grp == 0){
        if (k < 256)
          enc_step3(A.xhi + (size_t)k*512, (size_t)256*512,
                    A.h0hi + (size_t)k*65536, A.h0hi + (size_t)(k+1)*65536,
                    nullptr, 0, WL.wI, WL.wH, bih, bhh, col0, row0);
      } else {
        if (k >= 1){
          int t = k-1;
          enc_step3(A.h0hi + (size_t)k*65536, 512,
                    A.h1hi + (size_t)(t&1)*65536, A.h1hi + (size_t)((t+1)&1)*65536,
                    A.encout, t, WL.wI, WL.wH, bih, bhh, col0, row0);
        }
      }
      gbar(A.flags, A.genp, ++bt);
    }
  }

  // ================= Decoder init + pin decoder Whh slices in LDS ==========
  for (size_t i=gtid; i<65536; i+=P){
    A.dh0h[i] = A.h0hi[(size_t)256*65536 + i]; A.dh0l[i] = 0;
    A.dh1h[i] = A.h1hi[i];                     A.dh1l[i] = 0;   // layer1 final in buf 0
  }
  if (vwg < 64){
    int cb = vwg & 31;
    stage_wslice_u16(A.dWhhh, A.dWhhl, WL.wI, WL.wH, cb*16);
  } else {
    int cb = (vwg - 64) & 31;
    stage_wslice_u16(A.dWhhh + (size_t)1536*512, A.dWhhl + (size_t)1536*512, WL.wI, WL.wH, cb*16);
  }
  gbar(A.flags, A.genp, ++bt);

  // ================= Decoder: 32 steps, 5 barriers/step ====================
  for (int s=0; s<32; s++){
    const u16* h0ph = A.dh0h + (size_t)(s&1)*65536;
    const u16* h0pl = A.dh0l + (size_t)(s&1)*65536;
    u16* h0nh = A.dh0h + (size_t)((s+1)&1)*65536;
    u16* h0nl = A.dh0l + (size_t)((s+1)&1)*65536;
    const u16* h1ph = A.dh1h + (size_t)(s&1)*65536;
    const u16* h1pl = A.dh1l + (size_t)(s&1)*65536;
    u16* h1nh = A.dh1h + (size_t)((s+1)&1)*65536;
    u16* h1nl = A.dh1l + (size_t)((s+1)&1)*65536;

    // S1: logits = preW[s] + h1 @ Wwh^T      (128 x 256)
    if (vwg < 32){
      int rb = vwg >> 4, cb = vwg & 15;
      int row0 = rb*64, col0 = cb*16;
      v4f g = tile_xwT(h1ph, h1pl, 512, 16, A.Wwhh, A.Wwhl, 512, row0, col0, red);
      const float* pre = A.preW + (size_t)s*128*256;
      int w = tid>>6, lane = tid&63;
      int col = col0 + (lane&15), rowb = row0 + w*16 + ((lane>>4)<<2);
      #pragma unroll
      for (int e=0;e<4;e++){ int row=rowb+e; A.logits[(size_t)row*256+col] = g[e] + pre[(size_t)row*256+col]; }
    }
    gbar(A.flags, A.genp, ++bt);

    // S2+S3: softmax + context, ONE batch per WG, wave-chunked t2
    {
      int b = vwg;
      float v = A.logits[(size_t)b*256 + tid];
      float m = blk_max(v, sred);
      float e = __expf(v - m);
      float ssum = blk_sum(e, sred);
      float awv = e / ssum;
      awl2[tid] = awv;
      A.out[ATTN_OFF + ((size_t)b*32 + s)*256 + tid] = awv;
      __syncthreads();
      int w4 = tid >> 6, lane = tid & 63;
      const u16* ebase = A.encout + (size_t)b*256*512 + (size_t)(w4*64)*512 + lane*8;
      float acc8[8];
      #pragma unroll
      for (int q=0;q<8;q++) acc8[q]=0.f;
      for (int j=0;j<64;++j){
        float wv = awl2[w4*64+j];
        v8s ev = *(const v8s*)(ebase + (size_t)j*512);
        #pragma unroll
        for (int q=0;q<8;q++) acc8[q] += wv * bf2f((u16)ev[q]);
      }
      float* rr = (float*)red;
      #pragma unroll
      for (int q=0;q<8;q++) rr[(size_t)tid*8+q] = acc8[q];
      __syncthreads();
      #pragma unroll
      for (int cc=0; cc<2; ++cc){
        int col = tid*2+cc;
        float sum = 0.f;
        #pragma unroll
        for (int w2=0; w2<4; ++w2) sum += rr[(((size_t)w2*64 + (col>>3))<<3) + (col&7)];
        splitstore(&A.wcth[(size_t)b*512+col], &A.wctl[(size_t)b*512+col], sum);
      }
    }
    gbar(A.flags, A.genp, ++bt);

    // S4: xc = relu(preC[s] + wctx @ Wch^T)   (128 x 304, pads stay 0)
    if (vwg < 38){
      int rb = vwg / 19, cb = vwg % 19;
      int row0 = rb*64, col0 = cb*16;
      v4f g = tile_xwT(A.wcth, A.wctl, 512, 16, A.Wchh, A.Wchl, 512, row0, col0, red);
      const float* pre = A.preC + (size_t)s*128*320;
      int w = tid>>6, lane = tid&63;
      int col = col0 + (lane&15), rowb = row0 + w*16 + ((lane>>4)<<2);
      #pragma unroll
      for (int e=0;e<4;e++){
        int row = rowb+e;
        float v = (col<300)? fmaxf(g[e] + pre[(size_t)row*320+col], 0.f) : 0.f;
        splitstore(&A.xch[(size_t)row*320+col], &A.xcl[(size_t)row*320+col], v);
      }
    }
    gbar(A.flags, A.genp, ++bt);

    // S5: GRU layer 0: h0' = gru(xc, h0)  (Whh-L0 pinned; WGs 0-63)
    if (vwg < 64){
      int rb = vwg >> 5, cb = vwg & 31;
      int row0 = rb*64, col0 = cb*16;
      v4f gate[4];
      gru_tile_pin(A.xch, A.xcl, 320, 10, h0ph, h0pl,
                   A.dWih0h, A.dWih0l, 320, WL.wI, WL.wH, row0, col0, red, gate);
      gru_combine(gate, A.dbih, A.dbhh, h0ph, h0pl, h0nh, h0nl, row0, col0);
    }
    gbar(A.flags, A.genp, ++bt);

    // S6: GRU layer 1: h1' = gru(h0', h1)  (Whh-L1 pinned; WGs 64-127)
    if (vwg >= 64){
      int v2 = vwg - 64;
      int rb = v2 >> 5, cb = v2 & 31;
      int row0 = rb*64, col0 = cb*16;
      v4f gate[4];
      gru_tile_pin(h0nh, h0nl, 512, 16, h1ph, h1pl,
                   A.dWih1h, A.dWih1l, 512, WL.wI, WL.wH, row0, col0, red, gate);
      gru_combine(gate, A.dbih + 1536, A.dbhh + 1536, h1ph, h1pl, h1nh, h1nl, row0, col0);
    }
    gbar(A.flags, A.genp, ++bt);

    // S8': dec_out[:,s,:] = h1' @ W'^T + b'   (fused S7+S8; no trailing bar)
    if (vwg < 38){
      int rb = vwg / 19, cb = vwg % 19;
      int row0 = rb*64, col0 = cb*16;
      v4f g = tile_xwT(h1nh, h1nl, 512, 16, A.Wph, A.Wpl, 512, row0, col0, red);
      int w = tid>>6, lane = tid&63;
      int col = col0 + (lane&15), rowb = row0 + w*16 + ((lane>>4)<<2);
      #pragma unroll
      for (int e=0;e<4;e++){
        int row = rowb+e;
        if (col < 300) A.out[DECOUT_OFF + ((size_t)row*32 + s)*300 + col] = g[e] + A.bpr[col];
      }
    }
  }

  // ================= dec_hidden output (final h in buffer 0) ===============
  for (size_t i=gtid; i<65536; i+=P){
    A.out[DECHID_OFF + i]         = bf2f(A.dh0h[i]) + bf2f(A.dh0l[i]);
    A.out[DECHID_OFF + 65536 + i] = bf2f(A.dh1h[i]) + bf2f(A.dh1l[i]);
  }
}

// ===========================================================================
extern "C" void kernel_launch(void* const* d_in, const int* in_sizes, int n_in,
                              void* d_out, int out_size, void* d_ws, size_t ws_size,
                              hipStream_t stream){
  (void)in_sizes; (void)n_in; (void)out_size; (void)ws_size;
  KArgs A;
  A.x       = (const float*)d_in[0];  A.target = (const float*)d_in[1];
  A.eWih_f  = (const float*)d_in[2];  A.eWhh_f = (const float*)d_in[3];
  A.ebih    = (const float*)d_in[4];  A.ebhh   = (const float*)d_in[5];
  A.dWih0_f = (const float*)d_in[6];  A.dWih1_f= (const float*)d_in[7];
  A.dWhh_f  = (const float*)d_in[8];  A.dbih   = (const float*)d_in[9];
  A.dbhh    = (const float*)d_in[10];
  A.aWw_f   = (const float*)d_in[11]; A.aWb    = (const float*)d_in[12];
  A.aCw_f   = (const float*)d_in[13]; A.aCb    = (const float*)d_in[14];
  A.o1w_f   = (const float*)d_in[15]; A.o1b    = (const float*)d_in[16];
  A.o2w_f   = (const float*)d_in[17]; A.o2b    = (const float*)d_in[18];
  A.out = (float*)d_out;

  char* w = (char*)d_ws;
  size_t off = 0;
  auto alloc = [&](size_t bytes)->char*{
    char* p = w + off; off += (bytes + 255) & ~(size_t)255; return p;
  };
  char* barp = alloc(4096);
  A.flags  = (u32*)barp;               // [0..127]
  A.genp   = (u32*)(barp + 2048);
  A.ecnt   = (u32*)(barp + 2304);      // 8 u32 election counters
  A.xhi    = (u16*)alloc(128UL*256*512*2);
  A.h0hi   = (u16*)alloc(257UL*128*512*2);
  A.h1hi   = (u16*)alloc(2UL*128*512*2);
  A.encout = A.xhi;   // alias: layer0 reads xhi[t=k] while layer1 writes
                      // encout[t=k-1] -- trailing by one t-slice, disjoint
  A.dWih0h = (u16*)alloc(1536UL*320*2); A.dWih0l = (u16*)alloc(1536UL*320*2);
  A.dWih1h = (u16*)alloc(1536UL*512*2); A.dWih1l = (u16*)alloc(1536UL*512*2);
  A.dWhhh  = (u16*)alloc(2UL*1536*512*2); A.dWhhl = (u16*)alloc(2UL*1536*512*2);
  A.Wwhh   = (u16*)alloc(256UL*512*2);  A.Wwhl   = (u16*)alloc(256UL*512*2);
  A.Wwxh   = (u16*)alloc(256UL*320*2);  A.Wwxl   = (u16*)alloc(256UL*320*2);
  A.Wchh   = (u16*)alloc(304UL*512*2);  A.Wchl   = (u16*)alloc(304UL*512*2);
  A.Wcxh   = (u16*)alloc(304UL*320*2);  A.Wcxl   = (u16*)alloc(304UL*320*2);
  A.o2wh   = (u16*)alloc(320UL*320*2);  A.o2wl   = (u16*)alloc(320UL*320*2);
  A.o1Th   = (u16*)alloc(512UL*320*2);  A.o1Tl   = (u16*)alloc(512UL*320*2);
  A.Wph    = (u16*)alloc(304UL*512*2);  A.Wpl    = (u16*)alloc(304UL*512*2);
  A.bpr    = (float*)alloc(304UL*4);
  A.xth    = (u16*)alloc(32UL*128*320*2); A.xtl  = (u16*)alloc(32UL*128*320*2);
  A.preW   = (float*)alloc(32UL*128*256*4);
  A.preC   = (float*)alloc(32UL*128*320*4);
  A.dh0h   = (u16*)alloc(2UL*65536*2); A.dh0l = (u16*)alloc(2UL*65536*2);
  A.dh1h   = (u16*)alloc(2UL*65536*2); A.dh1l = (u16*)alloc(2UL*65536*2);
  A.logits = (float*)alloc(128UL*256*4);
  A.wcth   = (u16*)alloc(128UL*512*2); A.wctl = (u16*)alloc(128UL*512*2);
  A.xch    = (u16*)alloc(128UL*320*2); A.xcl  = (u16*)alloc(128UL*320*2);

  hipMemsetAsync(d_ws, 0, 4096, stream);   // reset barrier/election page each launch
  traffic_kernel<<<dim3(NWG), dim3(TPB), 0, stream>>>(A);
}